// Round 14
// baseline (1699.226 us; speedup 1.0000x reference)
//
#include <hip/hip_runtime.h>
#include <math.h>

#define DEVFN __device__ __forceinline__

constexpr int NB   = 16;     // batch
constexpr int NPTS = 8192;   // N points
constexpr int NG   = 128;    // groups
constexpr int NK   = 32;     // knn
constexpr int NC   = 384;    // model dim
constexpr int NH   = 6;      // heads
constexpr int NL   = 12;     // layers
constexpr int NHID = 1536;   // mlp hidden
constexpr int NDH  = 64;     // head dim
constexpr float LN_EPS = 1e-5f;

typedef __attribute__((ext_vector_type(8))) short short8v;
typedef __attribute__((ext_vector_type(4))) float f32x4;
typedef unsigned long long u64;

// fp32 ops without fma contraction, to track numpy's rounding in the
// index-selection stages (FPS / kNN / path ordering).
DEVFN float sq3(float x, float y, float z) {
  return __fadd_rn(__fadd_rn(__fmul_rn(x, x), __fmul_rn(y, y)), __fmul_rn(z, z));
}
DEVFN float dot3(float ax, float ay, float az, float bx, float by, float bz) {
  return __fadd_rn(__fadd_rn(__fmul_rn(ax, bx), __fmul_rn(ay, by)), __fmul_rn(az, bz));
}
DEVFN unsigned short f2bf(float f) {   // RTNE fp32 -> bf16
  unsigned u = __float_as_uint(f);
  return (unsigned short)((u + 0x7fffu + ((u >> 16) & 1u)) >> 16);
}
DEVFN float bf2f(unsigned short u) { return __uint_as_float(((unsigned)u) << 16); }

// ---------------- 1. farthest point sampling (one block per batch) ----------------
__global__ __launch_bounds__(512) void fps_kernel(const float* __restrict__ xyz,
                                                  int* __restrict__ cent) {
  extern __shared__ float dsm[];
  float* lx = dsm; float* ly = dsm + NPTS; float* lz = dsm + 2 * NPTS;
  __shared__ u64 swk[2][8];
  const int b = blockIdx.x, t = threadIdx.x;
  const float* X = xyz + (size_t)b * NPTS * 3;
  float px[16], py[16], pz[16], dd[16];
#pragma unroll
  for (int k = 0; k < 16; ++k) {
    const int i = t + k * 512;
    px[k] = X[i * 3 + 0]; py[k] = X[i * 3 + 1]; pz[k] = X[i * 3 + 2];
    lx[i] = px[k]; ly[i] = py[k]; lz[i] = pz[k];
    dd[k] = 1e10f;
  }
  __syncthreads();
  int far = 0;
  float fx = lx[0], fy = ly[0], fz = lz[0];
  for (int s = 0; s < NG; ++s) {
    if (t == 0) cent[b * NG + s] = far;
    float bv = -1.0f; int bi = 0;
#pragma unroll
    for (int k = 0; k < 16; ++k) {
      const float dx = __fsub_rn(px[k], fx);
      const float dy = __fsub_rn(py[k], fy);
      const float dz = __fsub_rn(pz[k], fz);
      const float d  = sq3(dx, dy, dz);
      const float nd = fminf(dd[k], d);
      dd[k] = nd;
      if (nd > bv) { bv = nd; bi = t + k * 512; }   // first occurrence = lowest i
    }
    u64 key = (((u64)__float_as_uint(bv)) << 32) | (unsigned)(8191 - bi);
#pragma unroll
    for (int m = 1; m < 64; m <<= 1) {
      const u64 o = __shfl_xor(key, m, 64);
      key = (o > key) ? o : key;
    }
    if ((t & 63) == 0) swk[s & 1][t >> 6] = key;
    __syncthreads();   // parity buffer: one barrier per step is race-free
    u64 fk = swk[s & 1][0];
#pragma unroll
    for (int w = 1; w < 8; ++w) fk = (swk[s & 1][w] > fk) ? swk[s & 1][w] : fk;
    far = 8191 - (int)(fk & 0xffffffffu);
    fx = lx[far]; fy = ly[far]; fz = lz[far];
  }
}

// ---------------- 2. kNN (one block per (b,g) center) ----------------
__global__ __launch_bounds__(256) void knn_kernel(const float* __restrict__ xyz,
                                                  const int* __restrict__ cent,
                                                  float* __restrict__ center,
                                                  int* __restrict__ knn) {
  __shared__ u64 swk[2][4];
  __shared__ float sc[3];
  const int bg = blockIdx.x, t = threadIdx.x;
  const int b = bg >> 7;
  const float* X = xyz + (size_t)b * NPTS * 3;
  if (t == 0) {
    const int ci = cent[bg];
    sc[0] = X[ci * 3 + 0]; sc[1] = X[ci * 3 + 1]; sc[2] = X[ci * 3 + 2];
    center[bg * 3 + 0] = sc[0]; center[bg * 3 + 1] = sc[1]; center[bg * 3 + 2] = sc[2];
  }
  __syncthreads();
  const float cx = sc[0], cy = sc[1], cz = sc[2];
  const float ra = sq3(cx, cy, cz);
  float d[32];
#pragma unroll
  for (int k = 0; k < 32; ++k) {
    const int i = t + k * 256;
    const float x = X[i * 3 + 0], y = X[i * 3 + 1], z = X[i * 3 + 2];
    const float rb = sq3(x, y, z);
    const float dt = dot3(cx, cy, cz, x, y, z);
    d[k] = fmaxf(__fsub_rn(__fadd_rn(ra, rb), __fmul_rn(2.0f, dt)), 0.0f);
  }
  float lv = 3.0e38f; int li = 0;
#pragma unroll
  for (int k = 0; k < 32; ++k) { if (d[k] < lv) { lv = d[k]; li = k; } }
  for (int k = 0; k < NK; ++k) {
    u64 key = (((u64)__float_as_uint(lv)) << 32) | (unsigned)(t + li * 256);
#pragma unroll
    for (int m = 1; m < 64; m <<= 1) {
      const u64 o = __shfl_xor(key, m, 64);
      key = (o < key) ? o : key;
    }
    if ((t & 63) == 0) swk[k & 1][t >> 6] = key;
    __syncthreads();
    u64 fk = swk[k & 1][0];
#pragma unroll
    for (int w = 1; w < 4; ++w) fk = (swk[k & 1][w] < fk) ? swk[k & 1][w] : fk;
    const int fi = (int)(fk & 0xffffffffu);
    if (t == 0) knn[(size_t)bg * NK + k] = fi;
    if ((fi & 255) == t) {
      const int kk = fi >> 8;
#pragma unroll
      for (int j = 0; j < 32; ++j) if (j == kk) d[j] = 3.0e38f;   // compile-time indices
      lv = 3.0e38f; li = 0;
#pragma unroll
      for (int j = 0; j < 32; ++j) { if (d[j] < lv) { lv = d[j]; li = j; } }
    }
  }
}

// ---------------- 3. greedy nearest path over centers (one block per batch) ----------------
__global__ __launch_bounds__(128) void order_kernel(const float* __restrict__ center,
                                                    int* __restrict__ order) {
  __shared__ float cx[NG], cy[NG], cz[NG];
  __shared__ u64 swk[2][2];
  const int b = blockIdx.x, t = threadIdx.x;
  cx[t] = center[((size_t)b * NG + t) * 3 + 0];
  cy[t] = center[((size_t)b * NG + t) * 3 + 1];
  cz[t] = center[((size_t)b * NG + t) * 3 + 2];
  bool vis = (t == 0);
  if (t == 0) order[b * NG] = 0;
  __syncthreads();
  int last = 0;
  for (int s = 1; s < NG; ++s) {
    float dv;
    const float lx = cx[last], ly = cy[last], lz = cz[last];
    if (vis) {
      dv = 3.0e38f;
    } else {
      const float ra = sq3(lx, ly, lz), rb = sq3(cx[t], cy[t], cz[t]);
      const float dd = __fsub_rn(__fadd_rn(ra, rb),
                                 __fmul_rn(2.0f, dot3(lx, ly, lz, cx[t], cy[t], cz[t])));
      dv = fmaxf(dd, 0.0f);
    }
    u64 key = (((u64)__float_as_uint(dv)) << 32) | (unsigned)t;
#pragma unroll
    for (int m = 1; m < 64; m <<= 1) {
      const u64 o = __shfl_xor(key, m, 64);
      key = (o < key) ? o : key;
    }
    if ((t & 63) == 0) swk[s & 1][t >> 6] = key;
    __syncthreads();
    const u64 fk = (swk[s & 1][1] < swk[s & 1][0]) ? swk[s & 1][1] : swk[s & 1][0];
    last = (int)(fk & 0xffffffffu);
    if (t == last) vis = true;
    if (t == 0) order[b * NG + s] = last;
  }
}

// ---------------- 4. gather ordered neighborhoods ----------------
__global__ void gather_neigh(const float* __restrict__ xyz, const int* __restrict__ knn,
                             const int* __restrict__ order, const float* __restrict__ center,
                             float* __restrict__ neigh, float* __restrict__ cord) {
  const int bg = blockIdx.x, t = threadIdx.x;  // 32 threads
  const int b = bg >> 7;
  const int src = order[bg];
  const int sbg = (b << 7) + src;
  const float c0 = center[sbg * 3 + 0], c1 = center[sbg * 3 + 1], c2 = center[sbg * 3 + 2];
  if (t < 3) cord[bg * 3 + t] = center[sbg * 3 + t];
  const int idx = knn[(size_t)sbg * NK + t];
  const float* P = xyz + ((size_t)b * NPTS + idx) * 3;
  float* o = neigh + ((size_t)bg * NK + t) * 3;
  o[0] = __fsub_rn(P[0], c0);
  o[1] = __fsub_rn(P[1], c1);
  o[2] = __fsub_rn(P[2], c2);
}

// ---------------- 5. encoder: BN1 statistics ----------------
__global__ __launch_bounds__(128) void bn1_stats(const float* __restrict__ neigh,
                                                 const float* __restrict__ w,
                                                 const float* __restrict__ bias,
                                                 float* __restrict__ psum,
                                                 float* __restrict__ psq) {
  const int c = threadIdx.x, blk = blockIdx.x;   // 256 blocks x 128 ch
  const float wx = w[c * 3 + 0], wy = w[c * 3 + 1], wz = w[c * 3 + 2], bb = bias[c];
  float s = 0.f, s2 = 0.f;
  const float* nr = neigh + (size_t)blk * 256 * 3;
  for (int r = 0; r < 256; ++r) {
    float y = fmaf(nr[r * 3 + 2], wz, fmaf(nr[r * 3 + 1], wy, fmaf(nr[r * 3 + 0], wx, bb)));
    s += y; s2 = fmaf(y, y, s2);
  }
  psum[c * 256 + blk] = s;
  psq[c * 256 + blk]  = s2;
}

// generic P-partial BN reduce: A = g*rsqrt(var+eps), B0 = b - mean*A  (M = 65536)
__global__ __launch_bounds__(256) void bn_reduce(const float* __restrict__ psum,
                                                 const float* __restrict__ psq,
                                                 const float* __restrict__ g,
                                                 const float* __restrict__ b,
                                                 float* __restrict__ A, float* __restrict__ B0,
                                                 int P) {
  __shared__ double rs[256], rq[256];
  const int c = blockIdx.x, t = threadIdx.x;
  double s = 0.0, q = 0.0;
  for (int i = t; i < P; i += 256) {
    s += (double)psum[(size_t)c * P + i];
    q += (double)psq[(size_t)c * P + i];
  }
  rs[t] = s; rq[t] = q;
  __syncthreads();
  for (int o = 128; o > 0; o >>= 1) {
    if (t < o) { rs[t] += rs[t + o]; rq[t] += rq[t + o]; }
    __syncthreads();
  }
  if (t == 0) {
    const double M = 65536.0;
    double m = rs[0] / M;
    double v = rq[0] / M - m * m;
    if (v < 0) v = 0;
    float a = g[c] * rsqrtf((float)v + LN_EPS);
    A[c] = a;
    B0[c] = b[c] - (float)m * a;
  }
}

// ---------------- 6. flat encoder stages ----------------
// f1 = relu(bn1(neigh @ ec1w^T)) -> bf16 [65536][128]
__global__ __launch_bounds__(256) void enc_f1(const float* __restrict__ neigh,
                                              const float* __restrict__ ec1w, const float* __restrict__ ec1b,
                                              const float* __restrict__ A1, const float* __restrict__ B01,
                                              unsigned short* __restrict__ f1bf) {
  __shared__ float ns[96];
  const int bg = blockIdx.x, t = threadIdx.x;
  if (t < 96) ns[t] = neigh[(size_t)bg * 96 + t];
  __syncthreads();
  for (int e = t; e < 32 * 128; e += 256) {
    const int r = e >> 7, c = e & 127;
    float y = fmaf(ns[r * 3 + 2], ec1w[c * 3 + 2],
             fmaf(ns[r * 3 + 1], ec1w[c * 3 + 1],
             fmaf(ns[r * 3 + 0], ec1w[c * 3 + 0], ec1b[c])));
    y = fmaxf(fmaf(y, A1[c], B01[c]), 0.f);
    f1bf[(size_t)bg * 4096 + e] = f2bf(y);
  }
}

// ---------------- 7. encoder A-stationary GEMM (stage 64 A-rows in LDS, sweep full N) ----
// wave tile 32x64 (acc[2][4]); N swept in 128-col chunks (2 waves cover 128 cols).
// EPI 0 (mm2): +bias, write C [N], per-group colmax -> gmaxOut (bf16)
// EPI 1 (mm3): +bias +sg[group], write C, column sum/sumsq partials (over bf16 values)
// EPI 2 (mm4): bn2-apply on A-load (relu(a*A2+B02) in bf16), no C, colmax+sc2b -> tokens
template <int K, int NTILE, int EPI>
__global__ __launch_bounds__(256) void enc_gemm(const unsigned short* __restrict__ A,
                                                const unsigned short* __restrict__ W,
                                                const float* __restrict__ bias,
                                                const float* __restrict__ sgbuf,
                                                const float* __restrict__ A2,
                                                const float* __restrict__ B02,
                                                unsigned short* __restrict__ C,
                                                unsigned short* __restrict__ gmaxOut,
                                                float* __restrict__ psum,
                                                float* __restrict__ psq,
                                                const float* __restrict__ sc2b,
                                                float* __restrict__ tokens) {
  constexpr int LDA = K + 8;   // shorts; +16B pad -> 2-way LDS bank aliasing (free)
  __shared__ unsigned short At[64 * LDA];
  const int blk = blockIdx.x, t = threadIdx.x;
  const int m0 = blk * 64;
  // ---- stage A (once) ----
  for (int idx = t; idx < 64 * (K / 8); idx += 256) {
    const int row = idx / (K / 8), off = idx % (K / 8);
    short8v v = *(const short8v*)(A + (size_t)(m0 + row) * K + off * 8);
    if (EPI == 2) {
      float a2v[8], b0v[8];
      *(float4*)(a2v)     = *(const float4*)(A2 + off * 8);
      *(float4*)(a2v + 4) = *(const float4*)(A2 + off * 8 + 4);
      *(float4*)(b0v)     = *(const float4*)(B02 + off * 8);
      *(float4*)(b0v + 4) = *(const float4*)(B02 + off * 8 + 4);
#pragma unroll
      for (int j = 0; j < 8; ++j)
        v[j] = (short)f2bf(fmaxf(fmaf(bf2f((unsigned short)v[j]), a2v[j], b0v[j]), 0.f));
    }
    *(short8v*)(At + row * LDA + off * 8) = v;
  }
  __syncthreads();
  const int lane = t & 63, wid = t >> 6;
  const int wr = wid >> 1, wc = wid & 1;
  const int lr = lane & 15, kg = lane >> 4;
  const int group = 2 * blk + wr;      // each wave's 32 rows = one group
  const unsigned short* a0 = At + (wr * 32 + lr) * LDA + kg * 8;
  const unsigned short* a1 = a0 + 16 * LDA;
  for (int nt = 0; nt < NTILE / 128; ++nt) {
    const int n0 = nt * 128 + wc * 64;
    f32x4 acc[2][4] = {};
#pragma unroll
    for (int k0 = 0; k0 < K; k0 += 32) {
      const short8v av0 = *(const short8v*)(a0 + k0);
      const short8v av1 = *(const short8v*)(a1 + k0);
#pragma unroll
      for (int j = 0; j < 4; ++j) {
        const short8v bv = *(const short8v*)(W + (size_t)(n0 + j * 16 + lr) * K + kg * 8 + k0);
        acc[0][j] = __builtin_amdgcn_mfma_f32_16x16x32_bf16(av0, bv, acc[0][j], 0, 0, 0);
        acc[1][j] = __builtin_amdgcn_mfma_f32_16x16x32_bf16(av1, bv, acc[1][j], 0, 0, 0);
      }
    }
    // ---- epilogue ----
#pragma unroll
    for (int j = 0; j < 4; ++j) {
      const int n = n0 + j * 16 + lr;
      float red0 = (EPI == 1) ? 0.f : -3.0e38f;   // sum or max
      float red1 = 0.f;                            // sumsq
      float base = 0.f;
      if (EPI == 0) base = bias[n];
      if (EPI == 1) base = bias[n] + sgbuf[(size_t)group * NTILE + n];
#pragma unroll
      for (int i = 0; i < 2; ++i) {
#pragma unroll
        for (int r = 0; r < 4; ++r) {
          const int m = m0 + wr * 32 + i * 16 + kg * 4 + r;
          const float v = acc[i][j][r] + base;
          if (EPI == 0) {
            C[(size_t)m * NTILE + n] = f2bf(v);
            red0 = fmaxf(red0, v);
          } else if (EPI == 1) {
            const unsigned short us = f2bf(v);
            C[(size_t)m * NTILE + n] = us;
            const float vv = bf2f(us);
            red0 += vv; red1 = fmaf(vv, vv, red1);
          } else {
            red0 = fmaxf(red0, v);
          }
        }
      }
      // reduce over kg (rows within the group): lanes lr, lr+16, lr+32, lr+48
      if (EPI == 1) {
        red0 += __shfl_xor(red0, 16, 64); red0 += __shfl_xor(red0, 32, 64);
        red1 += __shfl_xor(red1, 16, 64); red1 += __shfl_xor(red1, 32, 64);
        if (kg == 0) {
          psum[(size_t)n * 2048 + blk * 2 + wr] = red0;
          psq[(size_t)n * 2048 + blk * 2 + wr]  = red1;
        }
      } else {
        red0 = fmaxf(red0, __shfl_xor(red0, 16, 64));
        red0 = fmaxf(red0, __shfl_xor(red0, 32, 64));
        if (kg == 0) {
          if (EPI == 0) gmaxOut[(size_t)group * NTILE + n] = f2bf(red0);
          else          tokens[(size_t)group * NTILE + n] = red0 + sc2b[n];
        }
      }
    }
  }
}

// ---------------- 8. positional embedding + h init (merged) ----------------
__global__ void pos_hinit(const float* __restrict__ cord, const float* __restrict__ tokens,
                          const float* __restrict__ sos,
                          float* __restrict__ pos, float* __restrict__ h) {
  const int tok = blockIdx.x, t = threadIdx.x;   // 384 threads
  const int c = t >> 7;
  const int rem = t & 127;
  const int i = rem >> 1;
  const int isc = rem & 1;
  const float coord = cord[tok * 3 + c];
  const float ex = 2.0f * (float)i / 128.0f;
  const float inv = 1.0f / powf(10000.0f, ex);
  const float ang = coord * inv;
  pos[(size_t)tok * NC + t] = isc ? cosf(ang) : sinf(ang);
  const int b = tok >> 7, g = tok & 127;
  h[(size_t)tok * NC + t] = (g == 0) ? sos[t] : tokens[((size_t)b * NG + (g - 1)) * NC + t];
}

// ---------------- weight fp32 -> bf16 conversion (all segments, one kernel) ----------------
__global__ void cvt_all(const float* __restrict__ qkvw, const float* __restrict__ outw,
                        const float* __restrict__ m1w, const float* __restrict__ m2w,
                        const float* __restrict__ ec2w, const float* __restrict__ sc1w,
                        const float* __restrict__ sc2w,
                        unsigned short* __restrict__ wqkv, unsigned short* __restrict__ wout,
                        unsigned short* __restrict__ wm1, unsigned short* __restrict__ wm2,
                        unsigned short* __restrict__ ec2, unsigned short* __restrict__ w3a,
                        unsigned short* __restrict__ w3b, unsigned short* __restrict__ sc2) {
  constexpr int S0 = NL * 3 * NC * NC;          // 5308416
  constexpr int O0 = S0;
  constexpr int O1 = O0 + NL * NC * NC;         // +1769472
  constexpr int O2 = O1 + NL * NHID * NC;       // +7077888
  constexpr int O3 = O2 + NL * NC * NHID;       // +7077888
  constexpr int O4 = O3 + 256 * 128;
  constexpr int O5 = O4 + 512 * 512;
  constexpr int TOT = O5 + 384 * 512;
  for (int i = blockIdx.x * blockDim.x + threadIdx.x; i < TOT; i += gridDim.x * blockDim.x) {
    if (i < O0)      wqkv[i] = f2bf(qkvw[i]);
    else if (i < O1) wout[i - O0] = f2bf(outw[i - O0]);
    else if (i < O2) wm1[i - O1] = f2bf(m1w[i - O1]);
    else if (i < O3) wm2[i - O2] = f2bf(m2w[i - O2]);
    else if (i < O4) ec2[i - O3] = f2bf(ec2w[i - O3]);
    else if (i < O5) {
      const int ii = i - O4, c = ii >> 9, k = ii & 511;
      const unsigned short v = f2bf(sc1w[ii]);
      if (k < 256) w3a[c * 256 + k] = v;
      else         w3b[c * 256 + (k - 256)] = v;
    } else sc2[i - O5] = f2bf(sc2w[i - O5]);
  }
}

// ---------------- 9. layernorm (shuffle-reduce; optionally add first; y fp32 or bf16) ------
template <bool BF16OUT>
__global__ __launch_bounds__(128) void ln_kernel(const float* __restrict__ in,
                                                 const float* __restrict__ add,
                                                 const float* __restrict__ g,
                                                 const float* __restrict__ b,
                                                 void* __restrict__ y) {
  __shared__ float sm[4];
  const int row = blockIdx.x, t = threadIdx.x, w = t >> 6;
  const float* ip = in + (size_t)row * NC;
  float v0 = ip[t], v1 = ip[t + 128], v2 = ip[t + 256];
  if (add) {
    const float* ap = add + (size_t)row * NC;
    v0 += ap[t]; v1 += ap[t + 128]; v2 += ap[t + 256];
  }
  float s = v0 + v1 + v2;
#pragma unroll
  for (int m = 1; m < 64; m <<= 1) s += __shfl_xor(s, m, 64);
  if ((t & 63) == 0) sm[w] = s;
  __syncthreads();
  const float mean = (sm[0] + sm[1]) / (float)NC;
  const float d0 = v0 - mean, d1 = v1 - mean, d2 = v2 - mean;
  float sq = d0 * d0 + d1 * d1 + d2 * d2;
#pragma unroll
  for (int m = 1; m < 64; m <<= 1) sq += __shfl_xor(sq, m, 64);
  if ((t & 63) == 0) sm[2 + w] = sq;
  __syncthreads();
  const float rs = rsqrtf((sm[2] + sm[3]) / (float)NC + LN_EPS);
  const float y0 = d0 * rs * g[t] + b[t];
  const float y1 = d1 * rs * g[t + 128] + b[t + 128];
  const float y2 = d2 * rs * g[t + 256] + b[t + 256];
  if (BF16OUT) {
    unsigned short* yp = (unsigned short*)y + (size_t)row * NC;
    yp[t] = f2bf(y0); yp[t + 128] = f2bf(y1); yp[t + 256] = f2bf(y2);
  } else {
    float* yp = (float*)y + (size_t)row * NC;
    yp[t] = y0; yp[t + 128] = y1; yp[t + 256] = y2;
  }
}

// ---------------- 10. bf16 MFMA GEMM: C = act(A @ W^T + bias) (+res) ----------------
// RESMODE: 0=none, 1=+R[m*N+n], 3=+R[m*N+n]+R2[m*N+n]
template <int ACT, int RESMODE, bool OUT_BF, int K>
__global__ __launch_bounds__(256) void gemm_mfma(const unsigned short* __restrict__ A,
                                                 const unsigned short* __restrict__ W,
                                                 const float* __restrict__ bias,
                                                 const float* __restrict__ R,
                                                 const float* __restrict__ R2,
                                                 void* __restrict__ Cv,
                                                 int N) {
  const int t = threadIdx.x;
  const int lane = t & 63, wid = t >> 6;
  const int wr = wid >> 1, wc = wid & 1;
  const int m0 = blockIdx.y * 64 + wr * 32;
  const int n0 = blockIdx.x * 64 + wc * 32;
  const int lr = lane & 15, kg = lane >> 4;
  const unsigned short* a0p = A + (size_t)(m0 + lr) * K + kg * 8;
  const unsigned short* a1p = a0p + (size_t)16 * K;
  const unsigned short* b0p = W + (size_t)(n0 + lr) * K + kg * 8;
  const unsigned short* b1p = b0p + (size_t)16 * K;
  f32x4 acc00 = {0.f, 0.f, 0.f, 0.f}, acc01 = acc00, acc10 = acc00, acc11 = acc00;
#pragma unroll 4
  for (int k0 = 0; k0 < K; k0 += 32) {
    const short8v av0 = *(const short8v*)(a0p + k0);
    const short8v av1 = *(const short8v*)(a1p + k0);
    const short8v bv0 = *(const short8v*)(b0p + k0);
    const short8v bv1 = *(const short8v*)(b1p + k0);
    acc00 = __builtin_amdgcn_mfma_f32_16x16x32_bf16(av0, bv0, acc00, 0, 0, 0);
    acc01 = __builtin_amdgcn_mfma_f32_16x16x32_bf16(av0, bv1, acc01, 0, 0, 0);
    acc10 = __builtin_amdgcn_mfma_f32_16x16x32_bf16(av1, bv0, acc10, 0, 0, 0);
    acc11 = __builtin_amdgcn_mfma_f32_16x16x32_bf16(av1, bv1, acc11, 0, 0, 0);
  }
#pragma unroll
  for (int i = 0; i < 2; ++i) {
#pragma unroll
    for (int j = 0; j < 2; ++j) {
      const f32x4 a = (i == 0) ? (j == 0 ? acc00 : acc01) : (j == 0 ? acc10 : acc11);
      const int n = n0 + j * 16 + lr;
      const float bn = bias ? bias[n] : 0.f;
#pragma unroll
      for (int r = 0; r < 4; ++r) {
        const int m = m0 + i * 16 + kg * 4 + r;
        float v = a[r] + bn;
        if (ACT == 1) v = 0.5f * v * (1.0f + erff(v * 0.70710678118654752f));
        if (RESMODE == 1) v += R[(size_t)m * N + n];
        if (RESMODE == 3) v += R[(size_t)m * N + n] + R2[(size_t)m * N + n];
        if (OUT_BF) ((unsigned short*)Cv)[(size_t)m * N + n] = f2bf(v);
        else        ((float*)Cv)[(size_t)m * N + n] = v;
      }
    }
  }
}

// ---------------- 11. fused attention via MFMA: scores + softmax + PV ----------------
// one block per (b, h, 64-row half); 4 waves, wave w owns 16 q-rows.
__global__ __launch_bounds__(256) void attn_fused(const unsigned short* __restrict__ qkv,
                                                  unsigned short* __restrict__ obuf) {
  __shared__ __align__(16) unsigned short qs[64 * 72];    // Q [64][64] pad 8
  __shared__ __align__(16) unsigned short ks[128 * 72];   // K [128][64] pad 8
  __shared__ __align__(16) unsigned short vt[64 * 136];   // V^T [64][128] pad 8
  __shared__ __align__(16) unsigned short ps[64 * 136];   // P [64][128] pad 8
  const int blk = blockIdx.x, t = threadIdx.x;
  const int qt = blk & 1;
  const int h = (blk >> 1) % NH;
  const int b = blk / (2 * NH);
  const size_t qbase = ((size_t)(b * NG + qt * 64)) * (3 * NC) + h * NDH;
  const size_t kbase = ((size_t)(b * NG)) * (3 * NC) + NC + h * NDH;
  const size_t vbase = kbase + NC;
#pragma unroll
  for (int it = 0; it < 2; ++it) {   // Q: 512 8-short tasks
    const int idx = t + it * 256;
    const int r = idx >> 3, c0 = (idx & 7) * 8;
    *(short8v*)(qs + r * 72 + c0) = *(const short8v*)(qkv + qbase + (size_t)r * (3 * NC) + c0);
  }
#pragma unroll
  for (int it = 0; it < 4; ++it) {   // K: 1024 tasks
    const int idx = t + it * 256;
    const int r = idx >> 3, c0 = (idx & 7) * 8;
    *(short8v*)(ks + r * 72 + c0) = *(const short8v*)(qkv + kbase + (size_t)r * (3 * NC) + c0);
  }
#pragma unroll
  for (int it = 0; it < 4; ++it) {   // V transposed
    const int idx = t + it * 256;
    const int r = idx >> 3, c0 = (idx & 7) * 8;
    const short8v v = *(const short8v*)(qkv + vbase + (size_t)r * (3 * NC) + c0);
#pragma unroll
    for (int j = 0; j < 8; ++j) vt[(c0 + j) * 136 + r] = (unsigned short)v[j];
  }
  __syncthreads();
  const int lane = t & 63, w = t >> 6;
  const int lr = lane & 15, kg = lane >> 4;
  // ---- QK^T: wave w computes rows [w*16, w*16+16) x all 128 cols ----
  f32x4 sc[8] = {};
  {
    const short8v av0 = *(const short8v*)(qs + (w * 16 + lr) * 72 + kg * 8);
    const short8v av1 = *(const short8v*)(qs + (w * 16 + lr) * 72 + 32 + kg * 8);
#pragma unroll
    for (int j = 0; j < 8; ++j) {
      const short8v bv0 = *(const short8v*)(ks + (j * 16 + lr) * 72 + kg * 8);
      const short8v bv1 = *(const short8v*)(ks + (j * 16 + lr) * 72 + 32 + kg * 8);
      sc[j] = __builtin_amdgcn_mfma_f32_16x16x32_bf16(av0, bv0, sc[j], 0, 0, 0);
      sc[j] = __builtin_amdgcn_mfma_f32_16x16x32_bf16(av1, bv1, sc[j], 0, 0, 0);
    }
  }
  // ---- softmax (rows of this wave live in-wave: col=j*16+lr, row=kg*4+r) ----
#pragma unroll
  for (int r = 0; r < 4; ++r) {
    const int rowg = qt * 64 + w * 16 + kg * 4 + r;
    float pj[8];
    float mx = -3.0e38f;
#pragma unroll
    for (int j = 0; j < 8; ++j) {
      const int col = j * 16 + lr;
      const float s = (col <= rowg) ? sc[j][r] * 0.125f : -1e9f;
      pj[j] = s;
      mx = fmaxf(mx, s);
    }
#pragma unroll
    for (int m = 1; m < 16; m <<= 1) mx = fmaxf(mx, __shfl_xor(mx, m, 64));
    float sum = 0.f;
#pragma unroll
    for (int j = 0; j < 8; ++j) { pj[j] = expf(pj[j] - mx); sum += pj[j]; }
#pragma unroll
    for (int m = 1; m < 16; m <<= 1) sum += __shfl_xor(sum, m, 64);
#pragma unroll
    for (int j = 0; j < 8; ++j)
      ps[(w * 16 + kg * 4 + r) * 136 + j * 16 + lr] = f2bf(pj[j] / sum);
  }
  __syncthreads();
  // ---- PV: rows [w*16, w*16+16) x 64 dims, K=128 ----
  f32x4 oc[4] = {};
#pragma unroll
  for (int k = 0; k < 4; ++k) {
    const short8v av = *(const short8v*)(ps + (w * 16 + lr) * 136 + k * 32 + kg * 8);
#pragma unroll
    for (int dj = 0; dj < 4; ++dj) {
      const short8v bv = *(const short8v*)(vt + (dj * 16 + lr) * 136 + k * 32 + kg * 8);
      oc[dj] = __builtin_amdgcn_mfma_f32_16x16x32_bf16(av, bv, oc[dj], 0, 0, 0);
    }
  }
#pragma unroll
  for (int dj = 0; dj < 4; ++dj) {
#pragma unroll
    for (int r = 0; r < 4; ++r) {
      const int m = qt * 64 + w * 16 + kg * 4 + r;
      obuf[((size_t)(b * NG + m)) * NC + h * NDH + dj * 16 + lr] = f2bf(oc[dj][r]);
    }
  }
}

// ---------------- launch ----------------
extern "C" void kernel_launch(void* const* d_in, const int* in_sizes, int n_in,
                              void* d_out, int out_size, void* d_ws, size_t ws_size,
                              hipStream_t stream) {
  (void)in_sizes; (void)n_in; (void)out_size; (void)ws_size;
  const float* xyz  = (const float*)d_in[0];
  const float* ec1w = (const float*)d_in[1];
  const float* ec1b = (const float*)d_in[2];
  const float* bn1g = (const float*)d_in[3];
  const float* bn1b = (const float*)d_in[4];
  const float* ec2w = (const float*)d_in[5];
  const float* ec2b = (const float*)d_in[6];
  const float* sc1w = (const float*)d_in[7];
  const float* sc1b = (const float*)d_in[8];
  const float* bn2g = (const float*)d_in[9];
  const float* bn2b = (const float*)d_in[10];
  const float* sc2w = (const float*)d_in[11];
  const float* sc2b = (const float*)d_in[12];
  const float* sos  = (const float*)d_in[13];
  const float* ln1g = (const float*)d_in[14];
  const float* ln1b = (const float*)d_in[15];
  const float* qkvw = (const float*)d_in[16];
  const float* qkvb = (const float*)d_in[17];
  const float* outw = (const float*)d_in[18];
  const float* outb = (const float*)d_in[19];
  const float* ln2g = (const float*)d_in[20];
  const float* ln2b = (const float*)d_in[21];
  const float* m1w  = (const float*)d_in[22];
  const float* m1b  = (const float*)d_in[23];
  const float* m2w  = (const float*)d_in[24];
  const float* m2b  = (const float*)d_in[25];
  const float* lnfg = (const float*)d_in[26];
  const float* lnfb = (const float*)d_in[27];
  float* out = (float*)d_out;

  char* p = (char*)d_ws;
  auto carve = [&](size_t bytes) -> void* {
    void* q = (void*)p;
    p += (bytes + 255) & ~(size_t)255;
    return q;
  };
  int*   cent   = (int*)carve((size_t)NB * NG * 4);
  float* center = (float*)carve((size_t)NB * NG * 3 * 4);
  int*   knn    = (int*)carve((size_t)NB * NG * NK * 4);
  int*   order  = (int*)carve((size_t)NB * NG * 4);
  float* neigh  = (float*)carve((size_t)NB * NG * NK * 3 * 4);
  float* cord   = (float*)carve((size_t)NB * NG * 3 * 4);
  float* psum1  = (float*)carve((size_t)128 * 256 * 4);
  float* psq1   = (float*)carve((size_t)128 * 256 * 4);
  float* A1     = (float*)carve(128 * 4);
  float* B01    = (float*)carve(128 * 4);
  float* psum2  = (float*)carve((size_t)512 * 2048 * 4);
  float* psq2   = (float*)carve((size_t)512 * 2048 * 4);
  float* A2     = (float*)carve(512 * 4);
  float* B02    = (float*)carve(512 * 4);
  float* tokens = (float*)carve((size_t)NB * NG * NC * 4);
  float* posb   = (float*)carve((size_t)NB * NG * NC * 4);
  float* hbuf   = (float*)carve((size_t)NB * NG * NC * 4);
  unsigned short* ybf    = (unsigned short*)carve((size_t)NB * NG * NC * 2);
  unsigned short* qkv_bf = (unsigned short*)carve((size_t)NB * NG * 3 * NC * 2);
  unsigned short* obf    = (unsigned short*)carve((size_t)NB * NG * NC * 2);
  unsigned short* mh_bf  = (unsigned short*)carve((size_t)NB * NG * NHID * 2);
  unsigned short* wqkv_bf = (unsigned short*)carve((size_t)NL * 3 * NC * NC * 2);
  unsigned short* wout_bf = (unsigned short*)carve((size_t)NL * NC * NC * 2);
  unsigned short* wm1_bf  = (unsigned short*)carve((size_t)NL * NHID * NC * 2);
  unsigned short* wm2_bf  = (unsigned short*)carve((size_t)NL * NC * NHID * 2);
  // encoder bf16 weights
  unsigned short* ec2w_bf = (unsigned short*)carve((size_t)256 * 128 * 2);
  unsigned short* w3a_bf  = (unsigned short*)carve((size_t)512 * 256 * 2);
  unsigned short* w3b_bf  = (unsigned short*)carve((size_t)512 * 256 * 2);
  unsigned short* sc2w_bf = (unsigned short*)carve((size_t)384 * 512 * 2);
  // encoder activations (flat)
  unsigned short* f1bf   = (unsigned short*)carve((size_t)65536 * 128 * 2);  // 16.78 MB
  unsigned short* f2bf_a = (unsigned short*)carve((size_t)65536 * 256 * 2);  // 33.55 MB
  unsigned short* gmaxbf = (unsigned short*)carve((size_t)2048 * 256 * 2);
  float*          sgbuf  = (float*)carve((size_t)2048 * 512 * 4);
  unsigned short* s3bf   = (unsigned short*)carve((size_t)65536 * 512 * 2);  // 67.1 MB

  const int NTOK = NB * NG;  // 2048

  // weight conversion (deterministic, every call; one kernel)
  cvt_all<<<2048, 256, 0, stream>>>(qkvw, outw, m1w, m2w, ec2w, sc1w, sc2w,
                                    wqkv_bf, wout_bf, wm1_bf, wm2_bf,
                                    ec2w_bf, w3a_bf, w3b_bf, sc2w_bf);

  fps_kernel<<<NB, 512, 3 * NPTS * 4, stream>>>(xyz, cent);
  knn_kernel<<<NTOK, 256, 0, stream>>>(xyz, cent, center, knn);
  order_kernel<<<NB, 128, 0, stream>>>(center, order);
  gather_neigh<<<NTOK, 32, 0, stream>>>(xyz, knn, order, center, neigh, cord);

  // ---- encoder (flat MFMA pipeline, A-stationary, fused reductions) ----
  bn1_stats<<<256, 128, 0, stream>>>(neigh, ec1w, ec1b, psum1, psq1);
  bn_reduce<<<128, 256, 0, stream>>>(psum1, psq1, bn1g, bn1b, A1, B01, 256);
  enc_f1<<<NTOK, 256, 0, stream>>>(neigh, ec1w, ec1b, A1, B01, f1bf);
  enc_gemm<128, 256, 0><<<1024, 256, 0, stream>>>(
      f1bf, ec2w_bf, ec2b, nullptr, nullptr, nullptr,
      f2bf_a, gmaxbf, nullptr, nullptr, nullptr, nullptr);
  gemm_mfma<0, 0, false, 256><<<dim3(8, 32), 256, 0, stream>>>(
      gmaxbf, w3a_bf, nullptr, nullptr, nullptr, sgbuf, 512);
  enc_gemm<256, 512, 1><<<1024, 256, 0, stream>>>(
      f2bf_a, w3b_bf, sc1b, sgbuf, nullptr, nullptr,
      s3bf, nullptr, psum2, psq2, nullptr, nullptr);
  bn_reduce<<<512, 256, 0, stream>>>(psum2, psq2, bn2g, bn2b, A2, B02, 2048);
  enc_gemm<512, 384, 2><<<1024, 256, 0, stream>>>(
      s3bf, sc2w_bf, nullptr, nullptr, A2, B02,
      nullptr, nullptr, nullptr, nullptr, sc2b, tokens);

  pos_hinit<<<NTOK, NC, 0, stream>>>(cord, tokens, sos, posb, hbuf);

  for (int l = 0; l < NL; ++l) {
    ln_kernel<true><<<NTOK, 128, 0, stream>>>(hbuf, posb, ln1g + l * NC, ln1b + l * NC, ybf);
    gemm_mfma<0, 0, true, 384><<<dim3(18, 32), 256, 0, stream>>>(
        ybf, wqkv_bf + (size_t)l * 3 * NC * NC, qkvb + (size_t)l * 3 * NC, nullptr, nullptr,
        qkv_bf, 3 * NC);
    attn_fused<<<NB * NH * 2, 256, 0, stream>>>(qkv_bf, obf);
    gemm_mfma<0, 3, false, 384><<<dim3(6, 32), 256, 0, stream>>>(
        obf, wout_bf + (size_t)l * NC * NC, outb + (size_t)l * NC, hbuf, posb, hbuf, NC);
    ln_kernel<true><<<NTOK, 128, 0, stream>>>(hbuf, nullptr, ln2g + l * NC, ln2b + l * NC, ybf);
    gemm_mfma<1, 0, true, 384><<<dim3(24, 32), 256, 0, stream>>>(
        ybf, wm1_bf + (size_t)l * NHID * NC, m1b + (size_t)l * NHID, nullptr, nullptr,
        mh_bf, NHID);
    gemm_mfma<0, 1, false, 1536><<<dim3(6, 32), 256, 0, stream>>>(
        mh_bf, wm2_bf + (size_t)l * NC * NHID, m2b + (size_t)l * NC, hbuf, nullptr, hbuf, NC);
  }
  ln_kernel<false><<<NTOK, 128, 0, stream>>>(hbuf, nullptr, lnfg, lnfb, out);
}

// Round 15
// 1684.523 us; speedup vs baseline: 1.0087x; 1.0087x over previous
//
#include <hip/hip_runtime.h>
#include <math.h>

#define DEVFN __device__ __forceinline__

constexpr int NB   = 16;     // batch
constexpr int NPTS = 8192;   // N points
constexpr int NG   = 128;    // groups
constexpr int NK   = 32;     // knn
constexpr int NC   = 384;    // model dim
constexpr int NH   = 6;      // heads
constexpr int NL   = 12;     // layers
constexpr int NHID = 1536;   // mlp hidden
constexpr int NDH  = 64;     // head dim
constexpr float LN_EPS = 1e-5f;

typedef __attribute__((ext_vector_type(8))) short short8v;
typedef __attribute__((ext_vector_type(4))) float f32x4;
typedef unsigned long long u64;

// fp32 ops without fma contraction, to track numpy's rounding in the
// index-selection stages (FPS / kNN / path ordering).
DEVFN float sq3(float x, float y, float z) {
  return __fadd_rn(__fadd_rn(__fmul_rn(x, x), __fmul_rn(y, y)), __fmul_rn(z, z));
}
DEVFN float dot3(float ax, float ay, float az, float bx, float by, float bz) {
  return __fadd_rn(__fadd_rn(__fmul_rn(ax, bx), __fmul_rn(ay, by)), __fmul_rn(az, bz));
}
DEVFN unsigned short f2bf(float f) {   // RTNE fp32 -> bf16
  unsigned u = __float_as_uint(f);
  return (unsigned short)((u + 0x7fffu + ((u >> 16) & 1u)) >> 16);
}
DEVFN float bf2f(unsigned short u) { return __uint_as_float(((unsigned)u) << 16); }

// ---------------- 1. farthest point sampling (one block per batch) ----------------
__global__ __launch_bounds__(512) void fps_kernel(const float* __restrict__ xyz,
                                                  int* __restrict__ cent) {
  extern __shared__ float dsm[];
  float* lx = dsm; float* ly = dsm + NPTS; float* lz = dsm + 2 * NPTS;
  __shared__ u64 swk[2][8];
  const int b = blockIdx.x, t = threadIdx.x;
  const float* X = xyz + (size_t)b * NPTS * 3;
  float px[16], py[16], pz[16], dd[16];
#pragma unroll
  for (int k = 0; k < 16; ++k) {
    const int i = t + k * 512;
    px[k] = X[i * 3 + 0]; py[k] = X[i * 3 + 1]; pz[k] = X[i * 3 + 2];
    lx[i] = px[k]; ly[i] = py[k]; lz[i] = pz[k];
    dd[k] = 1e10f;
  }
  __syncthreads();
  int far = 0;
  float fx = lx[0], fy = ly[0], fz = lz[0];
  for (int s = 0; s < NG; ++s) {
    if (t == 0) cent[b * NG + s] = far;
    float bv = -1.0f; int bi = 0;
#pragma unroll
    for (int k = 0; k < 16; ++k) {
      const float dx = __fsub_rn(px[k], fx);
      const float dy = __fsub_rn(py[k], fy);
      const float dz = __fsub_rn(pz[k], fz);
      const float d  = sq3(dx, dy, dz);
      const float nd = fminf(dd[k], d);
      dd[k] = nd;
      if (nd > bv) { bv = nd; bi = t + k * 512; }   // first occurrence = lowest i
    }
    u64 key = (((u64)__float_as_uint(bv)) << 32) | (unsigned)(8191 - bi);
#pragma unroll
    for (int m = 1; m < 64; m <<= 1) {
      const u64 o = __shfl_xor(key, m, 64);
      key = (o > key) ? o : key;
    }
    if ((t & 63) == 0) swk[s & 1][t >> 6] = key;
    __syncthreads();   // parity buffer: one barrier per step is race-free
    u64 fk = swk[s & 1][0];
#pragma unroll
    for (int w = 1; w < 8; ++w) fk = (swk[s & 1][w] > fk) ? swk[s & 1][w] : fk;
    far = 8191 - (int)(fk & 0xffffffffu);
    fx = lx[far]; fy = ly[far]; fz = lz[far];
  }
}

// ---------------- 2. kNN (one block per (b,g) center) ----------------
__global__ __launch_bounds__(256) void knn_kernel(const float* __restrict__ xyz,
                                                  const int* __restrict__ cent,
                                                  float* __restrict__ center,
                                                  int* __restrict__ knn) {
  __shared__ u64 swk[2][4];
  __shared__ float sc[3];
  const int bg = blockIdx.x, t = threadIdx.x;
  const int b = bg >> 7;
  const float* X = xyz + (size_t)b * NPTS * 3;
  if (t == 0) {
    const int ci = cent[bg];
    sc[0] = X[ci * 3 + 0]; sc[1] = X[ci * 3 + 1]; sc[2] = X[ci * 3 + 2];
    center[bg * 3 + 0] = sc[0]; center[bg * 3 + 1] = sc[1]; center[bg * 3 + 2] = sc[2];
  }
  __syncthreads();
  const float cx = sc[0], cy = sc[1], cz = sc[2];
  const float ra = sq3(cx, cy, cz);
  float d[32];
#pragma unroll
  for (int k = 0; k < 32; ++k) {
    const int i = t + k * 256;
    const float x = X[i * 3 + 0], y = X[i * 3 + 1], z = X[i * 3 + 2];
    const float rb = sq3(x, y, z);
    const float dt = dot3(cx, cy, cz, x, y, z);
    d[k] = fmaxf(__fsub_rn(__fadd_rn(ra, rb), __fmul_rn(2.0f, dt)), 0.0f);
  }
  float lv = 3.0e38f; int li = 0;
#pragma unroll
  for (int k = 0; k < 32; ++k) { if (d[k] < lv) { lv = d[k]; li = k; } }
  for (int k = 0; k < NK; ++k) {
    u64 key = (((u64)__float_as_uint(lv)) << 32) | (unsigned)(t + li * 256);
#pragma unroll
    for (int m = 1; m < 64; m <<= 1) {
      const u64 o = __shfl_xor(key, m, 64);
      key = (o < key) ? o : key;
    }
    if ((t & 63) == 0) swk[k & 1][t >> 6] = key;
    __syncthreads();
    u64 fk = swk[k & 1][0];
#pragma unroll
    for (int w = 1; w < 4; ++w) fk = (swk[k & 1][w] < fk) ? swk[k & 1][w] : fk;
    const int fi = (int)(fk & 0xffffffffu);
    if (t == 0) knn[(size_t)bg * NK + k] = fi;
    if ((fi & 255) == t) {
      const int kk = fi >> 8;
#pragma unroll
      for (int j = 0; j < 32; ++j) if (j == kk) d[j] = 3.0e38f;   // compile-time indices
      lv = 3.0e38f; li = 0;
#pragma unroll
      for (int j = 0; j < 32; ++j) { if (d[j] < lv) { lv = d[j]; li = j; } }
    }
  }
}

// ---------------- 3. greedy nearest path over centers (one block per batch) ----------------
__global__ __launch_bounds__(128) void order_kernel(const float* __restrict__ center,
                                                    int* __restrict__ order) {
  __shared__ float cx[NG], cy[NG], cz[NG];
  __shared__ u64 swk[2][2];
  const int b = blockIdx.x, t = threadIdx.x;
  cx[t] = center[((size_t)b * NG + t) * 3 + 0];
  cy[t] = center[((size_t)b * NG + t) * 3 + 1];
  cz[t] = center[((size_t)b * NG + t) * 3 + 2];
  bool vis = (t == 0);
  if (t == 0) order[b * NG] = 0;
  __syncthreads();
  int last = 0;
  for (int s = 1; s < NG; ++s) {
    float dv;
    const float lx = cx[last], ly = cy[last], lz = cz[last];
    if (vis) {
      dv = 3.0e38f;
    } else {
      const float ra = sq3(lx, ly, lz), rb = sq3(cx[t], cy[t], cz[t]);
      const float dd = __fsub_rn(__fadd_rn(ra, rb),
                                 __fmul_rn(2.0f, dot3(lx, ly, lz, cx[t], cy[t], cz[t])));
      dv = fmaxf(dd, 0.0f);
    }
    u64 key = (((u64)__float_as_uint(dv)) << 32) | (unsigned)t;
#pragma unroll
    for (int m = 1; m < 64; m <<= 1) {
      const u64 o = __shfl_xor(key, m, 64);
      key = (o < key) ? o : key;
    }
    if ((t & 63) == 0) swk[s & 1][t >> 6] = key;
    __syncthreads();
    const u64 fk = (swk[s & 1][1] < swk[s & 1][0]) ? swk[s & 1][1] : swk[s & 1][0];
    last = (int)(fk & 0xffffffffu);
    if (t == last) vis = true;
    if (t == 0) order[b * NG + s] = last;
  }
}

// ---------------- 4. gather ordered neighborhoods ----------------
__global__ void gather_neigh(const float* __restrict__ xyz, const int* __restrict__ knn,
                             const int* __restrict__ order, const float* __restrict__ center,
                             float* __restrict__ neigh, float* __restrict__ cord) {
  const int bg = blockIdx.x, t = threadIdx.x;  // 32 threads
  const int b = bg >> 7;
  const int src = order[bg];
  const int sbg = (b << 7) + src;
  const float c0 = center[sbg * 3 + 0], c1 = center[sbg * 3 + 1], c2 = center[sbg * 3 + 2];
  if (t < 3) cord[bg * 3 + t] = center[sbg * 3 + t];
  const int idx = knn[(size_t)sbg * NK + t];
  const float* P = xyz + ((size_t)b * NPTS + idx) * 3;
  float* o = neigh + ((size_t)bg * NK + t) * 3;
  o[0] = __fsub_rn(P[0], c0);
  o[1] = __fsub_rn(P[1], c1);
  o[2] = __fsub_rn(P[2], c2);
}

// ---------------- 5. encoder: BN1 statistics ----------------
__global__ __launch_bounds__(128) void bn1_stats(const float* __restrict__ neigh,
                                                 const float* __restrict__ w,
                                                 const float* __restrict__ bias,
                                                 float* __restrict__ psum,
                                                 float* __restrict__ psq) {
  const int c = threadIdx.x, blk = blockIdx.x;   // 256 blocks x 128 ch
  const float wx = w[c * 3 + 0], wy = w[c * 3 + 1], wz = w[c * 3 + 2], bb = bias[c];
  float s = 0.f, s2 = 0.f;
  const float* nr = neigh + (size_t)blk * 256 * 3;
  for (int r = 0; r < 256; ++r) {
    float y = fmaf(nr[r * 3 + 2], wz, fmaf(nr[r * 3 + 1], wy, fmaf(nr[r * 3 + 0], wx, bb)));
    s += y; s2 = fmaf(y, y, s2);
  }
  psum[c * 256 + blk] = s;
  psq[c * 256 + blk]  = s2;
}

// generic P-partial BN reduce: A = g*rsqrt(var+eps), B0 = b - mean*A  (M = 65536)
__global__ __launch_bounds__(256) void bn_reduce(const float* __restrict__ psum,
                                                 const float* __restrict__ psq,
                                                 const float* __restrict__ g,
                                                 const float* __restrict__ b,
                                                 float* __restrict__ A, float* __restrict__ B0,
                                                 int P) {
  __shared__ double rs[256], rq[256];
  const int c = blockIdx.x, t = threadIdx.x;
  double s = 0.0, q = 0.0;
  for (int i = t; i < P; i += 256) {
    s += (double)psum[(size_t)c * P + i];
    q += (double)psq[(size_t)c * P + i];
  }
  rs[t] = s; rq[t] = q;
  __syncthreads();
  for (int o = 128; o > 0; o >>= 1) {
    if (t < o) { rs[t] += rs[t + o]; rq[t] += rq[t + o]; }
    __syncthreads();
  }
  if (t == 0) {
    const double M = 65536.0;
    double m = rs[0] / M;
    double v = rq[0] / M - m * m;
    if (v < 0) v = 0;
    float a = g[c] * rsqrtf((float)v + LN_EPS);
    A[c] = a;
    B0[c] = b[c] - (float)m * a;
  }
}

// ---------------- 6. flat encoder stages ----------------
// f1 = relu(bn1(neigh @ ec1w^T)) -> bf16 [65536][128]
__global__ __launch_bounds__(256) void enc_f1(const float* __restrict__ neigh,
                                              const float* __restrict__ ec1w, const float* __restrict__ ec1b,
                                              const float* __restrict__ A1, const float* __restrict__ B01,
                                              unsigned short* __restrict__ f1bf) {
  __shared__ float ns[96];
  const int bg = blockIdx.x, t = threadIdx.x;
  if (t < 96) ns[t] = neigh[(size_t)bg * 96 + t];
  __syncthreads();
  for (int e = t; e < 32 * 128; e += 256) {
    const int r = e >> 7, c = e & 127;
    float y = fmaf(ns[r * 3 + 2], ec1w[c * 3 + 2],
             fmaf(ns[r * 3 + 1], ec1w[c * 3 + 1],
             fmaf(ns[r * 3 + 0], ec1w[c * 3 + 0], ec1b[c])));
    y = fmaxf(fmaf(y, A1[c], B01[c]), 0.f);
    f1bf[(size_t)bg * 4096 + e] = f2bf(y);
  }
}

// ---------------- 7. encoder A-stationary GEMM (stage 64 A-rows in LDS, sweep full N) ----
// wave tile 32x64 (acc[2][4]); N swept in 128-col chunks (2 waves cover 128 cols).
// EPI 0 (mm2): +bias, write C [N], per-group colmax -> gmaxOut (bf16)
// EPI 1 (mm3): +bias +sg[group], write C, column sum/sumsq partials (over bf16 values)
// EPI 2 (mm4): bn2-apply on A-load (relu(a*A2+B02) in bf16), no C, colmax+sc2b -> tokens
template <int K, int NTILE, int EPI>
__global__ __launch_bounds__(256) void enc_gemm(const unsigned short* __restrict__ A,
                                                const unsigned short* __restrict__ W,
                                                const float* __restrict__ bias,
                                                const float* __restrict__ sgbuf,
                                                const float* __restrict__ A2,
                                                const float* __restrict__ B02,
                                                unsigned short* __restrict__ C,
                                                unsigned short* __restrict__ gmaxOut,
                                                float* __restrict__ psum,
                                                float* __restrict__ psq,
                                                const float* __restrict__ sc2b,
                                                float* __restrict__ tokens) {
  constexpr int LDA = K + 8;   // shorts; +16B pad -> 2-way LDS bank aliasing (free)
  __shared__ unsigned short At[64 * LDA];
  const int blk = blockIdx.x, t = threadIdx.x;
  const int m0 = blk * 64;
  // ---- stage A (once) ----
  for (int idx = t; idx < 64 * (K / 8); idx += 256) {
    const int row = idx / (K / 8), off = idx % (K / 8);
    short8v v = *(const short8v*)(A + (size_t)(m0 + row) * K + off * 8);
    if (EPI == 2) {
      float a2v[8], b0v[8];
      *(float4*)(a2v)     = *(const float4*)(A2 + off * 8);
      *(float4*)(a2v + 4) = *(const float4*)(A2 + off * 8 + 4);
      *(float4*)(b0v)     = *(const float4*)(B02 + off * 8);
      *(float4*)(b0v + 4) = *(const float4*)(B02 + off * 8 + 4);
#pragma unroll
      for (int j = 0; j < 8; ++j)
        v[j] = (short)f2bf(fmaxf(fmaf(bf2f((unsigned short)v[j]), a2v[j], b0v[j]), 0.f));
    }
    *(short8v*)(At + row * LDA + off * 8) = v;
  }
  __syncthreads();
  const int lane = t & 63, wid = t >> 6;
  const int wr = wid >> 1, wc = wid & 1;
  const int lr = lane & 15, kg = lane >> 4;
  const int group = 2 * blk + wr;      // each wave's 32 rows = one group
  const unsigned short* a0 = At + (wr * 32 + lr) * LDA + kg * 8;
  const unsigned short* a1 = a0 + 16 * LDA;
  for (int nt = 0; nt < NTILE / 128; ++nt) {
    const int n0 = nt * 128 + wc * 64;
    f32x4 acc[2][4] = {};
#pragma unroll
    for (int k0 = 0; k0 < K; k0 += 32) {
      const short8v av0 = *(const short8v*)(a0 + k0);
      const short8v av1 = *(const short8v*)(a1 + k0);
#pragma unroll
      for (int j = 0; j < 4; ++j) {
        const short8v bv = *(const short8v*)(W + (size_t)(n0 + j * 16 + lr) * K + kg * 8 + k0);
        acc[0][j] = __builtin_amdgcn_mfma_f32_16x16x32_bf16(av0, bv, acc[0][j], 0, 0, 0);
        acc[1][j] = __builtin_amdgcn_mfma_f32_16x16x32_bf16(av1, bv, acc[1][j], 0, 0, 0);
      }
    }
    // ---- epilogue ----
#pragma unroll
    for (int j = 0; j < 4; ++j) {
      const int n = n0 + j * 16 + lr;
      float red0 = (EPI == 1) ? 0.f : -3.0e38f;   // sum or max
      float red1 = 0.f;                            // sumsq
      float base = 0.f;
      if (EPI == 0) base = bias[n];
      if (EPI == 1) base = bias[n] + sgbuf[(size_t)group * NTILE + n];
#pragma unroll
      for (int i = 0; i < 2; ++i) {
#pragma unroll
        for (int r = 0; r < 4; ++r) {
          const int m = m0 + wr * 32 + i * 16 + kg * 4 + r;
          const float v = acc[i][j][r] + base;
          if (EPI == 0) {
            C[(size_t)m * NTILE + n] = f2bf(v);
            red0 = fmaxf(red0, v);
          } else if (EPI == 1) {
            const unsigned short us = f2bf(v);
            C[(size_t)m * NTILE + n] = us;
            const float vv = bf2f(us);
            red0 += vv; red1 = fmaf(vv, vv, red1);
          } else {
            red0 = fmaxf(red0, v);
          }
        }
      }
      // reduce over kg (rows within the group): lanes lr, lr+16, lr+32, lr+48
      if (EPI == 1) {
        red0 += __shfl_xor(red0, 16, 64); red0 += __shfl_xor(red0, 32, 64);
        red1 += __shfl_xor(red1, 16, 64); red1 += __shfl_xor(red1, 32, 64);
        if (kg == 0) {
          psum[(size_t)n * 2048 + blk * 2 + wr] = red0;
          psq[(size_t)n * 2048 + blk * 2 + wr]  = red1;
        }
      } else {
        red0 = fmaxf(red0, __shfl_xor(red0, 16, 64));
        red0 = fmaxf(red0, __shfl_xor(red0, 32, 64));
        if (kg == 0) {
          if (EPI == 0) gmaxOut[(size_t)group * NTILE + n] = f2bf(red0);
          else          tokens[(size_t)group * NTILE + n] = red0 + sc2b[n];
        }
      }
    }
  }
}

// ---------------- 8. positional embedding + h init (merged) ----------------
__global__ void pos_hinit(const float* __restrict__ cord, const float* __restrict__ tokens,
                          const float* __restrict__ sos,
                          float* __restrict__ pos, float* __restrict__ h) {
  const int tok = blockIdx.x, t = threadIdx.x;   // 384 threads
  const int c = t >> 7;
  const int rem = t & 127;
  const int i = rem >> 1;
  const int isc = rem & 1;
  const float coord = cord[tok * 3 + c];
  const float ex = 2.0f * (float)i / 128.0f;
  const float inv = 1.0f / powf(10000.0f, ex);
  const float ang = coord * inv;
  pos[(size_t)tok * NC + t] = isc ? cosf(ang) : sinf(ang);
  const int b = tok >> 7, g = tok & 127;
  h[(size_t)tok * NC + t] = (g == 0) ? sos[t] : tokens[((size_t)b * NG + (g - 1)) * NC + t];
}

// ---------------- weight fp32 -> bf16 conversion (all segments, one kernel) ----------------
__global__ void cvt_all(const float* __restrict__ qkvw, const float* __restrict__ outw,
                        const float* __restrict__ m1w, const float* __restrict__ m2w,
                        const float* __restrict__ ec2w, const float* __restrict__ sc1w,
                        const float* __restrict__ sc2w,
                        unsigned short* __restrict__ wqkv, unsigned short* __restrict__ wout,
                        unsigned short* __restrict__ wm1, unsigned short* __restrict__ wm2,
                        unsigned short* __restrict__ ec2, unsigned short* __restrict__ w3a,
                        unsigned short* __restrict__ w3b, unsigned short* __restrict__ sc2) {
  constexpr int S0 = NL * 3 * NC * NC;          // 5308416
  constexpr int O0 = S0;
  constexpr int O1 = O0 + NL * NC * NC;         // +1769472
  constexpr int O2 = O1 + NL * NHID * NC;       // +7077888
  constexpr int O3 = O2 + NL * NC * NHID;       // +7077888
  constexpr int O4 = O3 + 256 * 128;
  constexpr int O5 = O4 + 512 * 512;
  constexpr int TOT = O5 + 384 * 512;
  for (int i = blockIdx.x * blockDim.x + threadIdx.x; i < TOT; i += gridDim.x * blockDim.x) {
    if (i < O0)      wqkv[i] = f2bf(qkvw[i]);
    else if (i < O1) wout[i - O0] = f2bf(outw[i - O0]);
    else if (i < O2) wm1[i - O1] = f2bf(m1w[i - O1]);
    else if (i < O3) wm2[i - O2] = f2bf(m2w[i - O2]);
    else if (i < O4) ec2[i - O3] = f2bf(ec2w[i - O3]);
    else if (i < O5) {
      const int ii = i - O4, c = ii >> 9, k = ii & 511;
      const unsigned short v = f2bf(sc1w[ii]);
      if (k < 256) w3a[c * 256 + k] = v;
      else         w3b[c * 256 + (k - 256)] = v;
    } else sc2[i - O5] = f2bf(sc2w[i - O5]);
  }
}

// ---------------- 9. layernorm (shuffle-reduce; optionally add first; y fp32 or bf16) ------
template <bool BF16OUT>
__global__ __launch_bounds__(128) void ln_kernel(const float* __restrict__ in,
                                                 const float* __restrict__ add,
                                                 const float* __restrict__ g,
                                                 const float* __restrict__ b,
                                                 void* __restrict__ y) {
  __shared__ float sm[4];
  const int row = blockIdx.x, t = threadIdx.x, w = t >> 6;
  const float* ip = in + (size_t)row * NC;
  float v0 = ip[t], v1 = ip[t + 128], v2 = ip[t + 256];
  if (add) {
    const float* ap = add + (size_t)row * NC;
    v0 += ap[t]; v1 += ap[t + 128]; v2 += ap[t + 256];
  }
  float s = v0 + v1 + v2;
#pragma unroll
  for (int m = 1; m < 64; m <<= 1) s += __shfl_xor(s, m, 64);
  if ((t & 63) == 0) sm[w] = s;
  __syncthreads();
  const float mean = (sm[0] + sm[1]) / (float)NC;
  const float d0 = v0 - mean, d1 = v1 - mean, d2 = v2 - mean;
  float sq = d0 * d0 + d1 * d1 + d2 * d2;
#pragma unroll
  for (int m = 1; m < 64; m <<= 1) sq += __shfl_xor(sq, m, 64);
  if ((t & 63) == 0) sm[2 + w] = sq;
  __syncthreads();
  const float rs = rsqrtf((sm[2] + sm[3]) / (float)NC + LN_EPS);
  const float y0 = d0 * rs * g[t] + b[t];
  const float y1 = d1 * rs * g[t + 128] + b[t + 128];
  const float y2 = d2 * rs * g[t + 256] + b[t + 256];
  if (BF16OUT) {
    unsigned short* yp = (unsigned short*)y + (size_t)row * NC;
    yp[t] = f2bf(y0); yp[t + 128] = f2bf(y1); yp[t + 256] = f2bf(y2);
  } else {
    float* yp = (float*)y + (size_t)row * NC;
    yp[t] = y0; yp[t + 128] = y1; yp[t + 256] = y2;
  }
}

// ---------------- 10. bf16 MFMA GEMM: C = act(A @ W^T + bias) (+res) ----------------
// RESMODE: 0=none, 1=+R[m*N+n], 3=+R[m*N+n]+R2[m*N+n]
template <int ACT, int RESMODE, bool OUT_BF, int K>
__global__ __launch_bounds__(256) void gemm_mfma(const unsigned short* __restrict__ A,
                                                 const unsigned short* __restrict__ W,
                                                 const float* __restrict__ bias,
                                                 const float* __restrict__ R,
                                                 const float* __restrict__ R2,
                                                 void* __restrict__ Cv,
                                                 int N) {
  const int t = threadIdx.x;
  const int lane = t & 63, wid = t >> 6;
  const int wr = wid >> 1, wc = wid & 1;
  const int m0 = blockIdx.y * 64 + wr * 32;
  const int n0 = blockIdx.x * 64 + wc * 32;
  const int lr = lane & 15, kg = lane >> 4;
  const unsigned short* a0p = A + (size_t)(m0 + lr) * K + kg * 8;
  const unsigned short* a1p = a0p + (size_t)16 * K;
  const unsigned short* b0p = W + (size_t)(n0 + lr) * K + kg * 8;
  const unsigned short* b1p = b0p + (size_t)16 * K;
  f32x4 acc00 = {0.f, 0.f, 0.f, 0.f}, acc01 = acc00, acc10 = acc00, acc11 = acc00;
#pragma unroll 4
  for (int k0 = 0; k0 < K; k0 += 32) {
    const short8v av0 = *(const short8v*)(a0p + k0);
    const short8v av1 = *(const short8v*)(a1p + k0);
    const short8v bv0 = *(const short8v*)(b0p + k0);
    const short8v bv1 = *(const short8v*)(b1p + k0);
    acc00 = __builtin_amdgcn_mfma_f32_16x16x32_bf16(av0, bv0, acc00, 0, 0, 0);
    acc01 = __builtin_amdgcn_mfma_f32_16x16x32_bf16(av0, bv1, acc01, 0, 0, 0);
    acc10 = __builtin_amdgcn_mfma_f32_16x16x32_bf16(av1, bv0, acc10, 0, 0, 0);
    acc11 = __builtin_amdgcn_mfma_f32_16x16x32_bf16(av1, bv1, acc11, 0, 0, 0);
  }
#pragma unroll
  for (int i = 0; i < 2; ++i) {
#pragma unroll
    for (int j = 0; j < 2; ++j) {
      const f32x4 a = (i == 0) ? (j == 0 ? acc00 : acc01) : (j == 0 ? acc10 : acc11);
      const int n = n0 + j * 16 + lr;
      const float bn = bias ? bias[n] : 0.f;
#pragma unroll
      for (int r = 0; r < 4; ++r) {
        const int m = m0 + i * 16 + kg * 4 + r;
        float v = a[r] + bn;
        if (ACT == 1) v = 0.5f * v * (1.0f + erff(v * 0.70710678118654752f));
        if (RESMODE == 1) v += R[(size_t)m * N + n];
        if (RESMODE == 3) v += R[(size_t)m * N + n] + R2[(size_t)m * N + n];
        if (OUT_BF) ((unsigned short*)Cv)[(size_t)m * N + n] = f2bf(v);
        else        ((float*)Cv)[(size_t)m * N + n] = v;
      }
    }
  }
}

// ---------------- 11. fused attention via MFMA: scores + softmax + PV ----------------
// one block per (b, h, 64-row half); 4 waves, wave w owns 16 q-rows.
__global__ __launch_bounds__(256) void attn_fused(const unsigned short* __restrict__ qkv,
                                                  unsigned short* __restrict__ obuf) {
  __shared__ __align__(16) unsigned short qs[64 * 72];    // Q [64][64] pad 8
  __shared__ __align__(16) unsigned short ks[128 * 72];   // K [128][64] pad 8
  __shared__ __align__(16) unsigned short vt[64 * 136];   // V^T [64][128] pad 8
  __shared__ __align__(16) unsigned short ps[64 * 136];   // P [64][128] pad 8
  const int blk = blockIdx.x, t = threadIdx.x;
  const int qt = blk & 1;
  const int h = (blk >> 1) % NH;
  const int b = blk / (2 * NH);
  const size_t qbase = ((size_t)(b * NG + qt * 64)) * (3 * NC) + h * NDH;
  const size_t kbase = ((size_t)(b * NG)) * (3 * NC) + NC + h * NDH;
  const size_t vbase = kbase + NC;
#pragma unroll
  for (int it = 0; it < 2; ++it) {   // Q: 512 8-short tasks
    const int idx = t + it * 256;
    const int r = idx >> 3, c0 = (idx & 7) * 8;
    *(short8v*)(qs + r * 72 + c0) = *(const short8v*)(qkv + qbase + (size_t)r * (3 * NC) + c0);
  }
#pragma unroll
  for (int it = 0; it < 4; ++it) {   // K: 1024 tasks
    const int idx = t + it * 256;
    const int r = idx >> 3, c0 = (idx & 7) * 8;
    *(short8v*)(ks + r * 72 + c0) = *(const short8v*)(qkv + kbase + (size_t)r * (3 * NC) + c0);
  }
#pragma unroll
  for (int it = 0; it < 4; ++it) {   // V transposed
    const int idx = t + it * 256;
    const int r = idx >> 3, c0 = (idx & 7) * 8;
    const short8v v = *(const short8v*)(qkv + vbase + (size_t)r * (3 * NC) + c0);
#pragma unroll
    for (int j = 0; j < 8; ++j) vt[(c0 + j) * 136 + r] = (unsigned short)v[j];
  }
  __syncthreads();
  const int lane = t & 63, w = t >> 6;
  const int lr = lane & 15, kg = lane >> 4;
  // ---- QK^T: wave w computes rows [w*16, w*16+16) x all 128 cols ----
  f32x4 sc[8] = {};
  {
    const short8v av0 = *(const short8v*)(qs + (w * 16 + lr) * 72 + kg * 8);
    const short8v av1 = *(const short8v*)(qs + (w * 16 + lr) * 72 + 32 + kg * 8);
#pragma unroll
    for (int j = 0; j < 8; ++j) {
      const short8v bv0 = *(const short8v*)(ks + (j * 16 + lr) * 72 + kg * 8);
      const short8v bv1 = *(const short8v*)(ks + (j * 16 + lr) * 72 + 32 + kg * 8);
      sc[j] = __builtin_amdgcn_mfma_f32_16x16x32_bf16(av0, bv0, sc[j], 0, 0, 0);
      sc[j] = __builtin_amdgcn_mfma_f32_16x16x32_bf16(av1, bv1, sc[j], 0, 0, 0);
    }
  }
  // ---- softmax (rows of this wave live in-wave: col=j*16+lr, row=kg*4+r) ----
#pragma unroll
  for (int r = 0; r < 4; ++r) {
    const int rowg = qt * 64 + w * 16 + kg * 4 + r;
    float pj[8];
    float mx = -3.0e38f;
#pragma unroll
    for (int j = 0; j < 8; ++j) {
      const int col = j * 16 + lr;
      const float s = (col <= rowg) ? sc[j][r] * 0.125f : -1e9f;
      pj[j] = s;
      mx = fmaxf(mx, s);
    }
#pragma unroll
    for (int m = 1; m < 16; m <<= 1) mx = fmaxf(mx, __shfl_xor(mx, m, 64));
    float sum = 0.f;
#pragma unroll
    for (int j = 0; j < 8; ++j) { pj[j] = expf(pj[j] - mx); sum += pj[j]; }
#pragma unroll
    for (int m = 1; m < 16; m <<= 1) sum += __shfl_xor(sum, m, 64);
#pragma unroll
    for (int j = 0; j < 8; ++j)
      ps[(w * 16 + kg * 4 + r) * 136 + j * 16 + lr] = f2bf(pj[j] / sum);
  }
  __syncthreads();
  // ---- PV: rows [w*16, w*16+16) x 64 dims, K=128 ----
  f32x4 oc[4] = {};
#pragma unroll
  for (int k = 0; k < 4; ++k) {
    const short8v av = *(const short8v*)(ps + (w * 16 + lr) * 136 + k * 32 + kg * 8);
#pragma unroll
    for (int dj = 0; dj < 4; ++dj) {
      const short8v bv = *(const short8v*)(vt + (dj * 16 + lr) * 136 + k * 32 + kg * 8);
      oc[dj] = __builtin_amdgcn_mfma_f32_16x16x32_bf16(av, bv, oc[dj], 0, 0, 0);
    }
  }
#pragma unroll
  for (int dj = 0; dj < 4; ++dj) {
#pragma unroll
    for (int r = 0; r < 4; ++r) {
      const int m = qt * 64 + w * 16 + kg * 4 + r;
      obuf[((size_t)(b * NG + m)) * NC + h * NDH + dj * 16 + lr] = f2bf(oc[dj][r]);
    }
  }
}

// ---------------- launch ----------------
extern "C" void kernel_launch(void* const* d_in, const int* in_sizes, int n_in,
                              void* d_out, int out_size, void* d_ws, size_t ws_size,
                              hipStream_t stream) {
  (void)in_sizes; (void)n_in; (void)out_size; (void)ws_size;
  const float* xyz  = (const float*)d_in[0];
  const float* ec1w = (const float*)d_in[1];
  const float* ec1b = (const float*)d_in[2];
  const float* bn1g = (const float*)d_in[3];
  const float* bn1b = (const float*)d_in[4];
  const float* ec2w = (const float*)d_in[5];
  const float* ec2b = (const float*)d_in[6];
  const float* sc1w = (const float*)d_in[7];
  const float* sc1b = (const float*)d_in[8];
  const float* bn2g = (const float*)d_in[9];
  const float* bn2b = (const float*)d_in[10];
  const float* sc2w = (const float*)d_in[11];
  const float* sc2b = (const float*)d_in[12];
  const float* sos  = (const float*)d_in[13];
  const float* ln1g = (const float*)d_in[14];
  const float* ln1b = (const float*)d_in[15];
  const float* qkvw = (const float*)d_in[16];
  const float* qkvb = (const float*)d_in[17];
  const float* outw = (const float*)d_in[18];
  const float* outb = (const float*)d_in[19];
  const float* ln2g = (const float*)d_in[20];
  const float* ln2b = (const float*)d_in[21];
  const float* m1w  = (const float*)d_in[22];
  const float* m1b  = (const float*)d_in[23];
  const float* m2w  = (const float*)d_in[24];
  const float* m2b  = (const float*)d_in[25];
  const float* lnfg = (const float*)d_in[26];
  const float* lnfb = (const float*)d_in[27];
  float* out = (float*)d_out;

  char* p = (char*)d_ws;
  auto carve = [&](size_t bytes) -> void* {
    void* q = (void*)p;
    p += (bytes + 255) & ~(size_t)255;
    return q;
  };
  int*   cent   = (int*)carve((size_t)NB * NG * 4);
  float* center = (float*)carve((size_t)NB * NG * 3 * 4);
  int*   knn    = (int*)carve((size_t)NB * NG * NK * 4);
  int*   order  = (int*)carve((size_t)NB * NG * 4);
  float* neigh  = (float*)carve((size_t)NB * NG * NK * 3 * 4);
  float* cord   = (float*)carve((size_t)NB * NG * 3 * 4);
  float* psum1  = (float*)carve((size_t)128 * 256 * 4);
  float* psq1   = (float*)carve((size_t)128 * 256 * 4);
  float* A1     = (float*)carve(128 * 4);
  float* B01    = (float*)carve(128 * 4);
  float* psum2  = (float*)carve((size_t)512 * 2048 * 4);
  float* psq2   = (float*)carve((size_t)512 * 2048 * 4);
  float* A2     = (float*)carve(512 * 4);
  float* B02    = (float*)carve(512 * 4);
  float* tokens = (float*)carve((size_t)NB * NG * NC * 4);
  float* posb   = (float*)carve((size_t)NB * NG * NC * 4);
  float* hbuf   = (float*)carve((size_t)NB * NG * NC * 4);
  unsigned short* ybf    = (unsigned short*)carve((size_t)NB * NG * NC * 2);
  unsigned short* qkv_bf = (unsigned short*)carve((size_t)NB * NG * 3 * NC * 2);
  unsigned short* obf    = (unsigned short*)carve((size_t)NB * NG * NC * 2);
  unsigned short* mh_bf  = (unsigned short*)carve((size_t)NB * NG * NHID * 2);
  unsigned short* wqkv_bf = (unsigned short*)carve((size_t)NL * 3 * NC * NC * 2);
  unsigned short* wout_bf = (unsigned short*)carve((size_t)NL * NC * NC * 2);
  unsigned short* wm1_bf  = (unsigned short*)carve((size_t)NL * NHID * NC * 2);
  unsigned short* wm2_bf  = (unsigned short*)carve((size_t)NL * NC * NHID * 2);
  // encoder bf16 weights
  unsigned short* ec2w_bf = (unsigned short*)carve((size_t)256 * 128 * 2);
  unsigned short* w3a_bf  = (unsigned short*)carve((size_t)512 * 256 * 2);
  unsigned short* w3b_bf  = (unsigned short*)carve((size_t)512 * 256 * 2);
  unsigned short* sc2w_bf = (unsigned short*)carve((size_t)384 * 512 * 2);
  // encoder activations (flat)
  unsigned short* f1bf   = (unsigned short*)carve((size_t)65536 * 128 * 2);  // 16.78 MB
  unsigned short* f2bf_a = (unsigned short*)carve((size_t)65536 * 256 * 2);  // 33.55 MB
  unsigned short* gmaxbf = (unsigned short*)carve((size_t)2048 * 256 * 2);
  float*          sgbuf  = (float*)carve((size_t)2048 * 512 * 4);
  unsigned short* s3bf   = (unsigned short*)carve((size_t)65536 * 512 * 2);  // 67.1 MB

  const int NTOK = NB * NG;  // 2048

  // weight conversion (deterministic, every call; one kernel)
  cvt_all<<<2048, 256, 0, stream>>>(qkvw, outw, m1w, m2w, ec2w, sc1w, sc2w,
                                    wqkv_bf, wout_bf, wm1_bf, wm2_bf,
                                    ec2w_bf, w3a_bf, w3b_bf, sc2w_bf);

  fps_kernel<<<NB, 512, 3 * NPTS * 4, stream>>>(xyz, cent);
  knn_kernel<<<NTOK, 256, 0, stream>>>(xyz, cent, center, knn);
  order_kernel<<<NB, 128, 0, stream>>>(center, order);
  gather_neigh<<<NTOK, 32, 0, stream>>>(xyz, knn, order, center, neigh, cord);

  // ---- encoder (flat MFMA pipeline, A-stationary, fused reductions) ----
  bn1_stats<<<256, 128, 0, stream>>>(neigh, ec1w, ec1b, psum1, psq1);
  bn_reduce<<<128, 256, 0, stream>>>(psum1, psq1, bn1g, bn1b, A1, B01, 256);
  enc_f1<<<NTOK, 256, 0, stream>>>(neigh, ec1w, ec1b, A1, B01, f1bf);
  enc_gemm<128, 256, 0><<<1024, 256, 0, stream>>>(
      f1bf, ec2w_bf, ec2b, nullptr, nullptr, nullptr,
      f2bf_a, gmaxbf, nullptr, nullptr, nullptr, nullptr);
  gemm_mfma<0, 0, false, 256><<<dim3(8, 32), 256, 0, stream>>>(
      gmaxbf, w3a_bf, nullptr, nullptr, nullptr, sgbuf, 512);
  enc_gemm<256, 512, 1><<<1024, 256, 0, stream>>>(
      f2bf_a, w3b_bf, sc1b, sgbuf, nullptr, nullptr,
      s3bf, nullptr, psum2, psq2, nullptr, nullptr);
  bn_reduce<<<512, 256, 0, stream>>>(psum2, psq2, bn2g, bn2b, A2, B02, 2048);
  enc_gemm<512, 384, 2><<<1024, 256, 0, stream>>>(
      s3bf, sc2w_bf, nullptr, nullptr, A2, B02,
      nullptr, nullptr, nullptr, nullptr, sc2b, tokens);

  pos_hinit<<<NTOK, NC, 0, stream>>>(cord, tokens, sos, posb, hbuf);

  for (int l = 0; l < NL; ++l) {
    ln_kernel<true><<<NTOK, 128, 0, stream>>>(hbuf, posb, ln1g + l * NC, ln1b + l * NC, ybf);
    gemm_mfma<0, 0, true, 384><<<dim3(18, 32), 256, 0, stream>>>(
        ybf, wqkv_bf + (size_t)l * 3 * NC * NC, qkvb + (size_t)l * 3 * NC, nullptr, nullptr,
        qkv_bf, 3 * NC);
    attn_fused<<<NB * NH * 2, 256, 0, stream>>>(qkv_bf, obf);
    gemm_mfma<0, 3, false, 384><<<dim3(6, 32), 256, 0, stream>>>(
        obf, wout_bf + (size_t)l * NC * NC, outb + (size_t)l * NC, hbuf, posb, hbuf, NC);
    ln_kernel<true><<<NTOK, 128, 0, stream>>>(hbuf, nullptr, ln2g + l * NC, ln2b + l * NC, ybf);
    gemm_mfma<1, 0, true, 384><<<dim3(24, 32), 256, 0, stream>>>(
        ybf, wm1_bf + (size_t)l * NHID * NC, m1b + (size_t)l * NHID, nullptr, nullptr,
        mh_bf, NHID);
    gemm_mfma<0, 1, false, 1536><<<dim3(6, 32), 256, 0, stream>>>(
        mh_bf, wm2_bf + (size_t)l * NC * NHID, m2b + (size_t)l * NC, hbuf, nullptr, hbuf, NC);
  }
  ln_kernel<false><<<NTOK, 128, 0, stream>>>(hbuf, nullptr, lnfg, lnfb, out);
}

// Round 16
// 1643.350 us; speedup vs baseline: 1.0340x; 1.0251x over previous
//
#include <hip/hip_runtime.h>
#include <math.h>

#define DEVFN __device__ __forceinline__

constexpr int NB   = 16;     // batch
constexpr int NPTS = 8192;   // N points
constexpr int NG   = 128;    // groups
constexpr int NK   = 32;     // knn
constexpr int NC   = 384;    // model dim
constexpr int NH   = 6;      // heads
constexpr int NL   = 12;     // layers
constexpr int NHID = 1536;   // mlp hidden
constexpr int NDH  = 64;     // head dim
constexpr float LN_EPS = 1e-5f;

typedef __attribute__((ext_vector_type(8))) short short8v;
typedef __attribute__((ext_vector_type(4))) float f32x4;
typedef unsigned long long u64;

// fp32 ops without fma contraction, to track numpy's rounding in the
// index-selection stages (FPS / kNN / path ordering).
DEVFN float sq3(float x, float y, float z) {
  return __fadd_rn(__fadd_rn(__fmul_rn(x, x), __fmul_rn(y, y)), __fmul_rn(z, z));
}
DEVFN float dot3(float ax, float ay, float az, float bx, float by, float bz) {
  return __fadd_rn(__fadd_rn(__fmul_rn(ax, bx), __fmul_rn(ay, by)), __fmul_rn(az, bz));
}
DEVFN unsigned short f2bf(float f) {   // RTNE fp32 -> bf16
  unsigned u = __float_as_uint(f);
  return (unsigned short)((u + 0x7fffu + ((u >> 16) & 1u)) >> 16);
}
DEVFN float bf2f(unsigned short u) { return __uint_as_float(((unsigned)u) << 16); }

// ---------------- 1. farthest point sampling (one block per batch) ----------------
__global__ __launch_bounds__(512) void fps_kernel(const float* __restrict__ xyz,
                                                  int* __restrict__ cent) {
  extern __shared__ float dsm[];
  float* lx = dsm; float* ly = dsm + NPTS; float* lz = dsm + 2 * NPTS;
  __shared__ u64 swk[2][8];
  const int b = blockIdx.x, t = threadIdx.x;
  const float* X = xyz + (size_t)b * NPTS * 3;
  float px[16], py[16], pz[16], dd[16];
#pragma unroll
  for (int k = 0; k < 16; ++k) {
    const int i = t + k * 512;
    px[k] = X[i * 3 + 0]; py[k] = X[i * 3 + 1]; pz[k] = X[i * 3 + 2];
    lx[i] = px[k]; ly[i] = py[k]; lz[i] = pz[k];
    dd[k] = 1e10f;
  }
  __syncthreads();
  int far = 0;
  float fx = lx[0], fy = ly[0], fz = lz[0];
  for (int s = 0; s < NG; ++s) {
    if (t == 0) cent[b * NG + s] = far;
    float bv = -1.0f; int bi = 0;
#pragma unroll
    for (int k = 0; k < 16; ++k) {
      const float dx = __fsub_rn(px[k], fx);
      const float dy = __fsub_rn(py[k], fy);
      const float dz = __fsub_rn(pz[k], fz);
      const float d  = sq3(dx, dy, dz);
      const float nd = fminf(dd[k], d);
      dd[k] = nd;
      if (nd > bv) { bv = nd; bi = t + k * 512; }   // first occurrence = lowest i
    }
    u64 key = (((u64)__float_as_uint(bv)) << 32) | (unsigned)(8191 - bi);
#pragma unroll
    for (int m = 1; m < 64; m <<= 1) {
      const u64 o = __shfl_xor(key, m, 64);
      key = (o > key) ? o : key;
    }
    if ((t & 63) == 0) swk[s & 1][t >> 6] = key;
    __syncthreads();   // parity buffer: one barrier per step is race-free
    u64 fk = swk[s & 1][0];
#pragma unroll
    for (int w = 1; w < 8; ++w) fk = (swk[s & 1][w] > fk) ? swk[s & 1][w] : fk;
    far = 8191 - (int)(fk & 0xffffffffu);
    fx = lx[far]; fy = ly[far]; fz = lz[far];
  }
}

// ---------------- 2. kNN (one block per (b,g) center) ----------------
__global__ __launch_bounds__(256) void knn_kernel(const float* __restrict__ xyz,
                                                  const int* __restrict__ cent,
                                                  float* __restrict__ center,
                                                  int* __restrict__ knn) {
  __shared__ u64 swk[2][4];
  __shared__ float sc[3];
  const int bg = blockIdx.x, t = threadIdx.x;
  const int b = bg >> 7;
  const float* X = xyz + (size_t)b * NPTS * 3;
  if (t == 0) {
    const int ci = cent[bg];
    sc[0] = X[ci * 3 + 0]; sc[1] = X[ci * 3 + 1]; sc[2] = X[ci * 3 + 2];
    center[bg * 3 + 0] = sc[0]; center[bg * 3 + 1] = sc[1]; center[bg * 3 + 2] = sc[2];
  }
  __syncthreads();
  const float cx = sc[0], cy = sc[1], cz = sc[2];
  const float ra = sq3(cx, cy, cz);
  float d[32];
#pragma unroll
  for (int k = 0; k < 32; ++k) {
    const int i = t + k * 256;
    const float x = X[i * 3 + 0], y = X[i * 3 + 1], z = X[i * 3 + 2];
    const float rb = sq3(x, y, z);
    const float dt = dot3(cx, cy, cz, x, y, z);
    d[k] = fmaxf(__fsub_rn(__fadd_rn(ra, rb), __fmul_rn(2.0f, dt)), 0.0f);
  }
  float lv = 3.0e38f; int li = 0;
#pragma unroll
  for (int k = 0; k < 32; ++k) { if (d[k] < lv) { lv = d[k]; li = k; } }
  for (int k = 0; k < NK; ++k) {
    u64 key = (((u64)__float_as_uint(lv)) << 32) | (unsigned)(t + li * 256);
#pragma unroll
    for (int m = 1; m < 64; m <<= 1) {
      const u64 o = __shfl_xor(key, m, 64);
      key = (o < key) ? o : key;
    }
    if ((t & 63) == 0) swk[k & 1][t >> 6] = key;
    __syncthreads();
    u64 fk = swk[k & 1][0];
#pragma unroll
    for (int w = 1; w < 4; ++w) fk = (swk[k & 1][w] < fk) ? swk[k & 1][w] : fk;
    const int fi = (int)(fk & 0xffffffffu);
    if (t == 0) knn[(size_t)bg * NK + k] = fi;
    if ((fi & 255) == t) {
      const int kk = fi >> 8;
#pragma unroll
      for (int j = 0; j < 32; ++j) if (j == kk) d[j] = 3.0e38f;   // compile-time indices
      lv = 3.0e38f; li = 0;
#pragma unroll
      for (int j = 0; j < 32; ++j) { if (d[j] < lv) { lv = d[j]; li = j; } }
    }
  }
}

// ---------------- 3. greedy nearest path over centers (one block per batch) ----------------
__global__ __launch_bounds__(128) void order_kernel(const float* __restrict__ center,
                                                    int* __restrict__ order) {
  __shared__ float cx[NG], cy[NG], cz[NG];
  __shared__ u64 swk[2][2];
  const int b = blockIdx.x, t = threadIdx.x;
  cx[t] = center[((size_t)b * NG + t) * 3 + 0];
  cy[t] = center[((size_t)b * NG + t) * 3 + 1];
  cz[t] = center[((size_t)b * NG + t) * 3 + 2];
  bool vis = (t == 0);
  if (t == 0) order[b * NG] = 0;
  __syncthreads();
  int last = 0;
  for (int s = 1; s < NG; ++s) {
    float dv;
    const float lx = cx[last], ly = cy[last], lz = cz[last];
    if (vis) {
      dv = 3.0e38f;
    } else {
      const float ra = sq3(lx, ly, lz), rb = sq3(cx[t], cy[t], cz[t]);
      const float dd = __fsub_rn(__fadd_rn(ra, rb),
                                 __fmul_rn(2.0f, dot3(lx, ly, lz, cx[t], cy[t], cz[t])));
      dv = fmaxf(dd, 0.0f);
    }
    u64 key = (((u64)__float_as_uint(dv)) << 32) | (unsigned)t;
#pragma unroll
    for (int m = 1; m < 64; m <<= 1) {
      const u64 o = __shfl_xor(key, m, 64);
      key = (o < key) ? o : key;
    }
    if ((t & 63) == 0) swk[s & 1][t >> 6] = key;
    __syncthreads();
    const u64 fk = (swk[s & 1][1] < swk[s & 1][0]) ? swk[s & 1][1] : swk[s & 1][0];
    last = (int)(fk & 0xffffffffu);
    if (t == last) vis = true;
    if (t == 0) order[b * NG + s] = last;
  }
}

// ---------------- 4. gather ordered neighborhoods ----------------
__global__ void gather_neigh(const float* __restrict__ xyz, const int* __restrict__ knn,
                             const int* __restrict__ order, const float* __restrict__ center,
                             float* __restrict__ neigh, float* __restrict__ cord) {
  const int bg = blockIdx.x, t = threadIdx.x;  // 32 threads
  const int b = bg >> 7;
  const int src = order[bg];
  const int sbg = (b << 7) + src;
  const float c0 = center[sbg * 3 + 0], c1 = center[sbg * 3 + 1], c2 = center[sbg * 3 + 2];
  if (t < 3) cord[bg * 3 + t] = center[sbg * 3 + t];
  const int idx = knn[(size_t)sbg * NK + t];
  const float* P = xyz + ((size_t)b * NPTS + idx) * 3;
  float* o = neigh + ((size_t)bg * NK + t) * 3;
  o[0] = __fsub_rn(P[0], c0);
  o[1] = __fsub_rn(P[1], c1);
  o[2] = __fsub_rn(P[2], c2);
}

// ---------------- 5. encoder: BN1 statistics ----------------
__global__ __launch_bounds__(128) void bn1_stats(const float* __restrict__ neigh,
                                                 const float* __restrict__ w,
                                                 const float* __restrict__ bias,
                                                 float* __restrict__ psum,
                                                 float* __restrict__ psq) {
  const int c = threadIdx.x, blk = blockIdx.x;   // 256 blocks x 128 ch
  const float wx = w[c * 3 + 0], wy = w[c * 3 + 1], wz = w[c * 3 + 2], bb = bias[c];
  float s = 0.f, s2 = 0.f;
  const float* nr = neigh + (size_t)blk * 256 * 3;
  for (int r = 0; r < 256; ++r) {
    float y = fmaf(nr[r * 3 + 2], wz, fmaf(nr[r * 3 + 1], wy, fmaf(nr[r * 3 + 0], wx, bb)));
    s += y; s2 = fmaf(y, y, s2);
  }
  psum[c * 256 + blk] = s;
  psq[c * 256 + blk]  = s2;
}

// generic P-partial BN reduce: A = g*rsqrt(var+eps), B0 = b - mean*A  (M = 65536)
__global__ __launch_bounds__(256) void bn_reduce(const float* __restrict__ psum,
                                                 const float* __restrict__ psq,
                                                 const float* __restrict__ g,
                                                 const float* __restrict__ b,
                                                 float* __restrict__ A, float* __restrict__ B0,
                                                 int P) {
  __shared__ double rs[256], rq[256];
  const int c = blockIdx.x, t = threadIdx.x;
  double s = 0.0, q = 0.0;
  for (int i = t; i < P; i += 256) {
    s += (double)psum[(size_t)c * P + i];
    q += (double)psq[(size_t)c * P + i];
  }
  rs[t] = s; rq[t] = q;
  __syncthreads();
  for (int o = 128; o > 0; o >>= 1) {
    if (t < o) { rs[t] += rs[t + o]; rq[t] += rq[t + o]; }
    __syncthreads();
  }
  if (t == 0) {
    const double M = 65536.0;
    double m = rs[0] / M;
    double v = rq[0] / M - m * m;
    if (v < 0) v = 0;
    float a = g[c] * rsqrtf((float)v + LN_EPS);
    A[c] = a;
    B0[c] = b[c] - (float)m * a;
  }
}

// ---------------- 6. flat encoder stages ----------------
// f1 = relu(bn1(neigh @ ec1w^T)) -> bf16 [65536][128]
__global__ __launch_bounds__(256) void enc_f1(const float* __restrict__ neigh,
                                              const float* __restrict__ ec1w, const float* __restrict__ ec1b,
                                              const float* __restrict__ A1, const float* __restrict__ B01,
                                              unsigned short* __restrict__ f1bf) {
  __shared__ float ns[96];
  const int bg = blockIdx.x, t = threadIdx.x;
  if (t < 96) ns[t] = neigh[(size_t)bg * 96 + t];
  __syncthreads();
  for (int e = t; e < 32 * 128; e += 256) {
    const int r = e >> 7, c = e & 127;
    float y = fmaf(ns[r * 3 + 2], ec1w[c * 3 + 2],
             fmaf(ns[r * 3 + 1], ec1w[c * 3 + 1],
             fmaf(ns[r * 3 + 0], ec1w[c * 3 + 0], ec1b[c])));
    y = fmaxf(fmaf(y, A1[c], B01[c]), 0.f);
    f1bf[(size_t)bg * 4096 + e] = f2bf(y);
  }
}

// ---------------- 7. encoder A-stationary GEMM (stage 64 A-rows in LDS, sweep full N) ----
// wave tile 32x64 (acc[2][4]); N swept in 128-col chunks (2 waves cover 128 cols).
// EPI 0 (mm2): +bias, write C [N], per-group colmax -> gmaxOut (bf16)
// EPI 1 (mm3): +bias +sg[group], write C, column sum/sumsq partials (over bf16 values)
// EPI 2 (mm4): bn2-apply on A-load (relu(a*A2+B02) in bf16), no C, colmax+sc2b -> tokens
template <int K, int NTILE, int EPI>
__global__ __launch_bounds__(256) void enc_gemm(const unsigned short* __restrict__ A,
                                                const unsigned short* __restrict__ W,
                                                const float* __restrict__ bias,
                                                const float* __restrict__ sgbuf,
                                                const float* __restrict__ A2,
                                                const float* __restrict__ B02,
                                                unsigned short* __restrict__ C,
                                                unsigned short* __restrict__ gmaxOut,
                                                float* __restrict__ psum,
                                                float* __restrict__ psq,
                                                const float* __restrict__ sc2b,
                                                float* __restrict__ tokens) {
  constexpr int LDA = K + 8;   // shorts; +16B pad -> 2-way LDS bank aliasing (free)
  __shared__ unsigned short At[64 * LDA];
  const int blk = blockIdx.x, t = threadIdx.x;
  const int m0 = blk * 64;
  // ---- stage A (once) ----
  for (int idx = t; idx < 64 * (K / 8); idx += 256) {
    const int row = idx / (K / 8), off = idx % (K / 8);
    short8v v = *(const short8v*)(A + (size_t)(m0 + row) * K + off * 8);
    if (EPI == 2) {
      float a2v[8], b0v[8];
      *(float4*)(a2v)     = *(const float4*)(A2 + off * 8);
      *(float4*)(a2v + 4) = *(const float4*)(A2 + off * 8 + 4);
      *(float4*)(b0v)     = *(const float4*)(B02 + off * 8);
      *(float4*)(b0v + 4) = *(const float4*)(B02 + off * 8 + 4);
#pragma unroll
      for (int j = 0; j < 8; ++j)
        v[j] = (short)f2bf(fmaxf(fmaf(bf2f((unsigned short)v[j]), a2v[j], b0v[j]), 0.f));
    }
    *(short8v*)(At + row * LDA + off * 8) = v;
  }
  __syncthreads();
  const int lane = t & 63, wid = t >> 6;
  const int wr = wid >> 1, wc = wid & 1;
  const int lr = lane & 15, kg = lane >> 4;
  const int group = 2 * blk + wr;      // each wave's 32 rows = one group
  const unsigned short* a0 = At + (wr * 32 + lr) * LDA + kg * 8;
  const unsigned short* a1 = a0 + 16 * LDA;
  for (int nt = 0; nt < NTILE / 128; ++nt) {
    const int n0 = nt * 128 + wc * 64;
    f32x4 acc[2][4] = {};
#pragma unroll
    for (int k0 = 0; k0 < K; k0 += 32) {
      const short8v av0 = *(const short8v*)(a0 + k0);
      const short8v av1 = *(const short8v*)(a1 + k0);
#pragma unroll
      for (int j = 0; j < 4; ++j) {
        const short8v bv = *(const short8v*)(W + (size_t)(n0 + j * 16 + lr) * K + kg * 8 + k0);
        acc[0][j] = __builtin_amdgcn_mfma_f32_16x16x32_bf16(av0, bv, acc[0][j], 0, 0, 0);
        acc[1][j] = __builtin_amdgcn_mfma_f32_16x16x32_bf16(av1, bv, acc[1][j], 0, 0, 0);
      }
    }
    // ---- epilogue ----
#pragma unroll
    for (int j = 0; j < 4; ++j) {
      const int n = n0 + j * 16 + lr;
      float red0 = (EPI == 1) ? 0.f : -3.0e38f;   // sum or max
      float red1 = 0.f;                            // sumsq
      float base = 0.f;
      if (EPI == 0) base = bias[n];
      if (EPI == 1) base = bias[n] + sgbuf[(size_t)group * NTILE + n];
#pragma unroll
      for (int i = 0; i < 2; ++i) {
#pragma unroll
        for (int r = 0; r < 4; ++r) {
          const int m = m0 + wr * 32 + i * 16 + kg * 4 + r;
          const float v = acc[i][j][r] + base;
          if (EPI == 0) {
            C[(size_t)m * NTILE + n] = f2bf(v);
            red0 = fmaxf(red0, v);
          } else if (EPI == 1) {
            const unsigned short us = f2bf(v);
            C[(size_t)m * NTILE + n] = us;
            const float vv = bf2f(us);
            red0 += vv; red1 = fmaf(vv, vv, red1);
          } else {
            red0 = fmaxf(red0, v);
          }
        }
      }
      // reduce over kg (rows within the group): lanes lr, lr+16, lr+32, lr+48
      if (EPI == 1) {
        red0 += __shfl_xor(red0, 16, 64); red0 += __shfl_xor(red0, 32, 64);
        red1 += __shfl_xor(red1, 16, 64); red1 += __shfl_xor(red1, 32, 64);
        if (kg == 0) {
          psum[(size_t)n * 2048 + blk * 2 + wr] = red0;
          psq[(size_t)n * 2048 + blk * 2 + wr]  = red1;
        }
      } else {
        red0 = fmaxf(red0, __shfl_xor(red0, 16, 64));
        red0 = fmaxf(red0, __shfl_xor(red0, 32, 64));
        if (kg == 0) {
          if (EPI == 0) gmaxOut[(size_t)group * NTILE + n] = f2bf(red0);
          else          tokens[(size_t)group * NTILE + n] = red0 + sc2b[n];
        }
      }
    }
  }
}

// ---------------- 8. positional embedding + h init (merged) ----------------
__global__ void pos_hinit(const float* __restrict__ cord, const float* __restrict__ tokens,
                          const float* __restrict__ sos,
                          float* __restrict__ pos, float* __restrict__ h) {
  const int tok = blockIdx.x, t = threadIdx.x;   // 384 threads
  const int c = t >> 7;
  const int rem = t & 127;
  const int i = rem >> 1;
  const int isc = rem & 1;
  const float coord = cord[tok * 3 + c];
  const float ex = 2.0f * (float)i / 128.0f;
  const float inv = 1.0f / powf(10000.0f, ex);
  const float ang = coord * inv;
  pos[(size_t)tok * NC + t] = isc ? cosf(ang) : sinf(ang);
  const int b = tok >> 7, g = tok & 127;
  h[(size_t)tok * NC + t] = (g == 0) ? sos[t] : tokens[((size_t)b * NG + (g - 1)) * NC + t];
}

// ---------------- weight fp32 -> bf16 conversion (all segments, one kernel) ----------------
__global__ void cvt_all(const float* __restrict__ qkvw, const float* __restrict__ outw,
                        const float* __restrict__ m1w, const float* __restrict__ m2w,
                        const float* __restrict__ ec2w, const float* __restrict__ sc1w,
                        const float* __restrict__ sc2w,
                        unsigned short* __restrict__ wqkv, unsigned short* __restrict__ wout,
                        unsigned short* __restrict__ wm1, unsigned short* __restrict__ wm2,
                        unsigned short* __restrict__ ec2, unsigned short* __restrict__ w3a,
                        unsigned short* __restrict__ w3b, unsigned short* __restrict__ sc2) {
  constexpr int S0 = NL * 3 * NC * NC;          // 5308416
  constexpr int O0 = S0;
  constexpr int O1 = O0 + NL * NC * NC;         // +1769472
  constexpr int O2 = O1 + NL * NHID * NC;       // +7077888
  constexpr int O3 = O2 + NL * NC * NHID;       // +7077888
  constexpr int O4 = O3 + 256 * 128;
  constexpr int O5 = O4 + 512 * 512;
  constexpr int TOT = O5 + 384 * 512;
  for (int i = blockIdx.x * blockDim.x + threadIdx.x; i < TOT; i += gridDim.x * blockDim.x) {
    if (i < O0)      wqkv[i] = f2bf(qkvw[i]);
    else if (i < O1) wout[i - O0] = f2bf(outw[i - O0]);
    else if (i < O2) wm1[i - O1] = f2bf(m1w[i - O1]);
    else if (i < O3) wm2[i - O2] = f2bf(m2w[i - O2]);
    else if (i < O4) ec2[i - O3] = f2bf(ec2w[i - O3]);
    else if (i < O5) {
      const int ii = i - O4, c = ii >> 9, k = ii & 511;
      const unsigned short v = f2bf(sc1w[ii]);
      if (k < 256) w3a[c * 256 + k] = v;
      else         w3b[c * 256 + (k - 256)] = v;
    } else sc2[i - O5] = f2bf(sc2w[i - O5]);
  }
}

// ---------------- 9. layernorm (shuffle-reduce; optionally add first; y fp32 or bf16) ------
template <bool BF16OUT>
__global__ __launch_bounds__(128) void ln_kernel(const float* __restrict__ in,
                                                 const float* __restrict__ add,
                                                 const float* __restrict__ g,
                                                 const float* __restrict__ b,
                                                 void* __restrict__ y,
                                                 float* __restrict__ xout) {
  __shared__ float sm[4];
  const int row = blockIdx.x, t = threadIdx.x, w = t >> 6;
  const float* ip = in + (size_t)row * NC;
  float v0 = ip[t], v1 = ip[t + 128], v2 = ip[t + 256];
  if (add) {
    const float* ap = add + (size_t)row * NC;
    v0 += ap[t]; v1 += ap[t + 128]; v2 += ap[t + 256];
  }
  float s = v0 + v1 + v2;
#pragma unroll
  for (int m = 1; m < 64; m <<= 1) s += __shfl_xor(s, m, 64);
  if ((t & 63) == 0) sm[w] = s;
  __syncthreads();
  const float mean = (sm[0] + sm[1]) / (float)NC;
  const float d0 = v0 - mean, d1 = v1 - mean, d2 = v2 - mean;
  float sq = d0 * d0 + d1 * d1 + d2 * d2;
#pragma unroll
  for (int m = 1; m < 64; m <<= 1) sq += __shfl_xor(sq, m, 64);
  if ((t & 63) == 0) sm[2 + w] = sq;
  __syncthreads();
  const float rs = rsqrtf((sm[2] + sm[3]) / (float)NC + LN_EPS);
  const float y0 = d0 * rs * g[t] + b[t];
  const float y1 = d1 * rs * g[t + 128] + b[t + 128];
  const float y2 = d2 * rs * g[t + 256] + b[t + 256];
  if (BF16OUT) {
    unsigned short* yp = (unsigned short*)y + (size_t)row * NC;
    yp[t] = f2bf(y0); yp[t + 128] = f2bf(y1); yp[t + 256] = f2bf(y2);
  } else {
    float* yp = (float*)y + (size_t)row * NC;
    yp[t] = y0; yp[t + 128] = y1; yp[t + 256] = y2;
  }
  if (xout) {
    float* xp = xout + (size_t)row * NC;
    xp[t] = v0; xp[t + 128] = v1; xp[t + 256] = v2;
  }
}

// ---------------- 10. bf16 MFMA GEMM: C = act(A @ W^T + bias) (+res) ----------------
// RESMODE: 0=none, 1=+R[m*N+n]
template <int ACT, int RESMODE, bool OUT_BF, int K>
__global__ __launch_bounds__(256) void gemm_mfma(const unsigned short* __restrict__ A,
                                                 const unsigned short* __restrict__ W,
                                                 const float* __restrict__ bias,
                                                 const float* __restrict__ R,
                                                 void* __restrict__ Cv,
                                                 int N) {
  const int t = threadIdx.x;
  const int lane = t & 63, wid = t >> 6;
  const int wr = wid >> 1, wc = wid & 1;
  const int m0 = blockIdx.y * 64 + wr * 32;
  const int n0 = blockIdx.x * 64 + wc * 32;
  const int lr = lane & 15, kg = lane >> 4;
  const unsigned short* a0p = A + (size_t)(m0 + lr) * K + kg * 8;
  const unsigned short* a1p = a0p + (size_t)16 * K;
  const unsigned short* b0p = W + (size_t)(n0 + lr) * K + kg * 8;
  const unsigned short* b1p = b0p + (size_t)16 * K;
  f32x4 acc00 = {0.f, 0.f, 0.f, 0.f}, acc01 = acc00, acc10 = acc00, acc11 = acc00;
#pragma unroll 2
  for (int k0 = 0; k0 < K; k0 += 32) {
    const short8v av0 = *(const short8v*)(a0p + k0);
    const short8v av1 = *(const short8v*)(a1p + k0);
    const short8v bv0 = *(const short8v*)(b0p + k0);
    const short8v bv1 = *(const short8v*)(b1p + k0);
    acc00 = __builtin_amdgcn_mfma_f32_16x16x32_bf16(av0, bv0, acc00, 0, 0, 0);
    acc01 = __builtin_amdgcn_mfma_f32_16x16x32_bf16(av0, bv1, acc01, 0, 0, 0);
    acc10 = __builtin_amdgcn_mfma_f32_16x16x32_bf16(av1, bv0, acc10, 0, 0, 0);
    acc11 = __builtin_amdgcn_mfma_f32_16x16x32_bf16(av1, bv1, acc11, 0, 0, 0);
  }
#pragma unroll
  for (int i = 0; i < 2; ++i) {
#pragma unroll
    for (int j = 0; j < 2; ++j) {
      const f32x4 a = (i == 0) ? (j == 0 ? acc00 : acc01) : (j == 0 ? acc10 : acc11);
      const int n = n0 + j * 16 + lr;
      const float bn = bias ? bias[n] : 0.f;
#pragma unroll
      for (int r = 0; r < 4; ++r) {
        const int m = m0 + i * 16 + kg * 4 + r;
        float v = a[r] + bn;
        if (ACT == 1) v = 0.5f * v * (1.0f + erff(v * 0.70710678118654752f));
        if (RESMODE == 1) v += R[(size_t)m * N + n];
        if (OUT_BF) ((unsigned short*)Cv)[(size_t)m * N + n] = f2bf(v);
        else        ((float*)Cv)[(size_t)m * N + n] = v;
      }
    }
  }
}

// ---------------- 11. fused attention via MFMA: scores + softmax + PV ----------------
// one block per (b, h, 64-row half); 4 waves, wave w owns 16 q-rows.
__global__ __launch_bounds__(256) void attn_fused(const unsigned short* __restrict__ qkv,
                                                  unsigned short* __restrict__ obuf) {
  __shared__ __align__(16) unsigned short qs[64 * 72];    // Q [64][64] pad 8
  __shared__ __align__(16) unsigned short ks[128 * 72];   // K [128][64] pad 8
  __shared__ __align__(16) unsigned short vt[64 * 136];   // V^T [64][128] pad 8
  __shared__ __align__(16) unsigned short ps[64 * 136];   // P [64][128] pad 8
  const int blk = blockIdx.x, t = threadIdx.x;
  const int qt = blk & 1;
  const int h = (blk >> 1) % NH;
  const int b = blk / (2 * NH);
  const size_t qbase = ((size_t)(b * NG + qt * 64)) * (3 * NC) + h * NDH;
  const size_t kbase = ((size_t)(b * NG)) * (3 * NC) + NC + h * NDH;
  const size_t vbase = kbase + NC;
#pragma unroll
  for (int it = 0; it < 2; ++it) {   // Q: 512 8-short tasks
    const int idx = t + it * 256;
    const int r = idx >> 3, c0 = (idx & 7) * 8;
    *(short8v*)(qs + r * 72 + c0) = *(const short8v*)(qkv + qbase + (size_t)r * (3 * NC) + c0);
  }
#pragma unroll
  for (int it = 0; it < 4; ++it) {   // K: 1024 tasks
    const int idx = t + it * 256;
    const int r = idx >> 3, c0 = (idx & 7) * 8;
    *(short8v*)(ks + r * 72 + c0) = *(const short8v*)(qkv + kbase + (size_t)r * (3 * NC) + c0);
  }
#pragma unroll
  for (int it = 0; it < 4; ++it) {   // V transposed
    const int idx = t + it * 256;
    const int r = idx >> 3, c0 = (idx & 7) * 8;
    const short8v v = *(const short8v*)(qkv + vbase + (size_t)r * (3 * NC) + c0);
#pragma unroll
    for (int j = 0; j < 8; ++j) vt[(c0 + j) * 136 + r] = (unsigned short)v[j];
  }
  __syncthreads();
  const int lane = t & 63, w = t >> 6;
  const int lr = lane & 15, kg = lane >> 4;
  // ---- QK^T: wave w computes rows [w*16, w*16+16) x all 128 cols ----
  f32x4 sc[8] = {};
  {
    const short8v av0 = *(const short8v*)(qs + (w * 16 + lr) * 72 + kg * 8);
    const short8v av1 = *(const short8v*)(qs + (w * 16 + lr) * 72 + 32 + kg * 8);
#pragma unroll
    for (int j = 0; j < 8; ++j) {
      const short8v bv0 = *(const short8v*)(ks + (j * 16 + lr) * 72 + kg * 8);
      const short8v bv1 = *(const short8v*)(ks + (j * 16 + lr) * 72 + 32 + kg * 8);
      sc[j] = __builtin_amdgcn_mfma_f32_16x16x32_bf16(av0, bv0, sc[j], 0, 0, 0);
      sc[j] = __builtin_amdgcn_mfma_f32_16x16x32_bf16(av1, bv1, sc[j], 0, 0, 0);
    }
  }
  // ---- softmax (rows of this wave live in-wave: col=j*16+lr, row=kg*4+r) ----
#pragma unroll
  for (int r = 0; r < 4; ++r) {
    const int rowg = qt * 64 + w * 16 + kg * 4 + r;
    float pj[8];
    float mx = -3.0e38f;
#pragma unroll
    for (int j = 0; j < 8; ++j) {
      const int col = j * 16 + lr;
      const float s = (col <= rowg) ? sc[j][r] * 0.125f : -1e9f;
      pj[j] = s;
      mx = fmaxf(mx, s);
    }
#pragma unroll
    for (int m = 1; m < 16; m <<= 1) mx = fmaxf(mx, __shfl_xor(mx, m, 64));
    float sum = 0.f;
#pragma unroll
    for (int j = 0; j < 8; ++j) { pj[j] = expf(pj[j] - mx); sum += pj[j]; }
#pragma unroll
    for (int m = 1; m < 16; m <<= 1) sum += __shfl_xor(sum, m, 64);
#pragma unroll
    for (int j = 0; j < 8; ++j)
      ps[(w * 16 + kg * 4 + r) * 136 + j * 16 + lr] = f2bf(pj[j] / sum);
  }
  __syncthreads();
  // ---- PV: rows [w*16, w*16+16) x 64 dims, K=128 ----
  f32x4 oc[4] = {};
#pragma unroll
  for (int k = 0; k < 4; ++k) {
    const short8v av = *(const short8v*)(ps + (w * 16 + lr) * 136 + k * 32 + kg * 8);
#pragma unroll
    for (int dj = 0; dj < 4; ++dj) {
      const short8v bv = *(const short8v*)(vt + (dj * 16 + lr) * 136 + k * 32 + kg * 8);
      oc[dj] = __builtin_amdgcn_mfma_f32_16x16x32_bf16(av, bv, oc[dj], 0, 0, 0);
    }
  }
#pragma unroll
  for (int dj = 0; dj < 4; ++dj) {
#pragma unroll
    for (int r = 0; r < 4; ++r) {
      const int m = qt * 64 + w * 16 + kg * 4 + r;
      obuf[((size_t)(b * NG + m)) * NC + h * NDH + dj * 16 + lr] = f2bf(oc[dj][r]);
    }
  }
}

// ---------------- launch ----------------
extern "C" void kernel_launch(void* const* d_in, const int* in_sizes, int n_in,
                              void* d_out, int out_size, void* d_ws, size_t ws_size,
                              hipStream_t stream) {
  (void)in_sizes; (void)n_in; (void)out_size; (void)ws_size;
  const float* xyz  = (const float*)d_in[0];
  const float* ec1w = (const float*)d_in[1];
  const float* ec1b = (const float*)d_in[2];
  const float* bn1g = (const float*)d_in[3];
  const float* bn1b = (const float*)d_in[4];
  const float* ec2w = (const float*)d_in[5];
  const float* ec2b = (const float*)d_in[6];
  const float* sc1w = (const float*)d_in[7];
  const float* sc1b = (const float*)d_in[8];
  const float* bn2g = (const float*)d_in[9];
  const float* bn2b = (const float*)d_in[10];
  const float* sc2w = (const float*)d_in[11];
  const float* sc2b = (const float*)d_in[12];
  const float* sos  = (const float*)d_in[13];
  const float* ln1g = (const float*)d_in[14];
  const float* ln1b = (const float*)d_in[15];
  const float* qkvw = (const float*)d_in[16];
  const float* qkvb = (const float*)d_in[17];
  const float* outw = (const float*)d_in[18];
  const float* outb = (const float*)d_in[19];
  const float* ln2g = (const float*)d_in[20];
  const float* ln2b = (const float*)d_in[21];
  const float* m1w  = (const float*)d_in[22];
  const float* m1b  = (const float*)d_in[23];
  const float* m2w  = (const float*)d_in[24];
  const float* m2b  = (const float*)d_in[25];
  const float* lnfg = (const float*)d_in[26];
  const float* lnfb = (const float*)d_in[27];
  float* out = (float*)d_out;

  char* p = (char*)d_ws;
  auto carve = [&](size_t bytes) -> void* {
    void* q = (void*)p;
    p += (bytes + 255) & ~(size_t)255;
    return q;
  };
  int*   cent   = (int*)carve((size_t)NB * NG * 4);
  float* center = (float*)carve((size_t)NB * NG * 3 * 4);
  int*   knn    = (int*)carve((size_t)NB * NG * NK * 4);
  int*   order  = (int*)carve((size_t)NB * NG * 4);
  float* neigh  = (float*)carve((size_t)NB * NG * NK * 3 * 4);
  float* cord   = (float*)carve((size_t)NB * NG * 3 * 4);
  float* psum1  = (float*)carve((size_t)128 * 256 * 4);
  float* psq1   = (float*)carve((size_t)128 * 256 * 4);
  float* A1     = (float*)carve(128 * 4);
  float* B01    = (float*)carve(128 * 4);
  float* psum2  = (float*)carve((size_t)512 * 2048 * 4);
  float* psq2   = (float*)carve((size_t)512 * 2048 * 4);
  float* A2     = (float*)carve(512 * 4);
  float* B02    = (float*)carve(512 * 4);
  float* tokens = (float*)carve((size_t)NB * NG * NC * 4);
  float* posb   = (float*)carve((size_t)NB * NG * NC * 4);
  float* hbuf   = (float*)carve((size_t)NB * NG * NC * 4);
  float* xbuf   = (float*)carve((size_t)NB * NG * NC * 4);
  unsigned short* ybf    = (unsigned short*)carve((size_t)NB * NG * NC * 2);
  unsigned short* qkv_bf = (unsigned short*)carve((size_t)NB * NG * 3 * NC * 2);
  unsigned short* obf    = (unsigned short*)carve((size_t)NB * NG * NC * 2);
  unsigned short* mh_bf  = (unsigned short*)carve((size_t)NB * NG * NHID * 2);
  unsigned short* wqkv_bf = (unsigned short*)carve((size_t)NL * 3 * NC * NC * 2);
  unsigned short* wout_bf = (unsigned short*)carve((size_t)NL * NC * NC * 2);
  unsigned short* wm1_bf  = (unsigned short*)carve((size_t)NL * NHID * NC * 2);
  unsigned short* wm2_bf  = (unsigned short*)carve((size_t)NL * NC * NHID * 2);
  // encoder bf16 weights
  unsigned short* ec2w_bf = (unsigned short*)carve((size_t)256 * 128 * 2);
  unsigned short* w3a_bf  = (unsigned short*)carve((size_t)512 * 256 * 2);
  unsigned short* w3b_bf  = (unsigned short*)carve((size_t)512 * 256 * 2);
  unsigned short* sc2w_bf = (unsigned short*)carve((size_t)384 * 512 * 2);
  // encoder activations (flat)
  unsigned short* f1bf   = (unsigned short*)carve((size_t)65536 * 128 * 2);  // 16.78 MB
  unsigned short* f2bf_a = (unsigned short*)carve((size_t)65536 * 256 * 2);  // 33.55 MB
  unsigned short* gmaxbf = (unsigned short*)carve((size_t)2048 * 256 * 2);
  float*          sgbuf  = (float*)carve((size_t)2048 * 512 * 4);
  unsigned short* s3bf   = (unsigned short*)carve((size_t)65536 * 512 * 2);  // 67.1 MB

  const int NTOK = NB * NG;  // 2048

  // weight conversion (deterministic, every call; one kernel)
  cvt_all<<<2048, 256, 0, stream>>>(qkvw, outw, m1w, m2w, ec2w, sc1w, sc2w,
                                    wqkv_bf, wout_bf, wm1_bf, wm2_bf,
                                    ec2w_bf, w3a_bf, w3b_bf, sc2w_bf);

  fps_kernel<<<NB, 512, 3 * NPTS * 4, stream>>>(xyz, cent);
  knn_kernel<<<NTOK, 256, 0, stream>>>(xyz, cent, center, knn);
  order_kernel<<<NB, 128, 0, stream>>>(center, order);
  gather_neigh<<<NTOK, 32, 0, stream>>>(xyz, knn, order, center, neigh, cord);

  // ---- encoder (flat MFMA pipeline, A-stationary, fused reductions) ----
  bn1_stats<<<256, 128, 0, stream>>>(neigh, ec1w, ec1b, psum1, psq1);
  bn_reduce<<<128, 256, 0, stream>>>(psum1, psq1, bn1g, bn1b, A1, B01, 256);
  enc_f1<<<NTOK, 256, 0, stream>>>(neigh, ec1w, ec1b, A1, B01, f1bf);
  enc_gemm<128, 256, 0><<<1024, 256, 0, stream>>>(
      f1bf, ec2w_bf, ec2b, nullptr, nullptr, nullptr,
      f2bf_a, gmaxbf, nullptr, nullptr, nullptr, nullptr);
  gemm_mfma<0, 0, false, 256><<<dim3(8, 32), 256, 0, stream>>>(
      gmaxbf, w3a_bf, nullptr, nullptr, sgbuf, 512);
  enc_gemm<256, 512, 1><<<1024, 256, 0, stream>>>(
      f2bf_a, w3b_bf, sc1b, sgbuf, nullptr, nullptr,
      s3bf, nullptr, psum2, psq2, nullptr, nullptr);
  bn_reduce<<<512, 256, 0, stream>>>(psum2, psq2, bn2g, bn2b, A2, B02, 2048);
  enc_gemm<512, 384, 2><<<1024, 256, 0, stream>>>(
      s3bf, sc2w_bf, nullptr, nullptr, A2, B02,
      nullptr, nullptr, nullptr, nullptr, sc2b, tokens);

  pos_hinit<<<NTOK, NC, 0, stream>>>(cord, tokens, sos, posb, hbuf);

  for (int l = 0; l < NL; ++l) {
    ln_kernel<true><<<NTOK, 128, 0, stream>>>(hbuf, posb, ln1g + l * NC, ln1b + l * NC, ybf, xbuf);
    gemm_mfma<0, 0, true, 384><<<dim3(18, 32), 256, 0, stream>>>(
        ybf, wqkv_bf + (size_t)l * 3 * NC * NC, qkvb + (size_t)l * 3 * NC, nullptr, qkv_bf,
        3 * NC);
    attn_fused<<<NB * NH * 2, 256, 0, stream>>>(qkv_bf, obf);
    gemm_mfma<0, 1, false, 384><<<dim3(6, 32), 256, 0, stream>>>(
        obf, wout_bf + (size_t)l * NC * NC, outb + (size_t)l * NC, xbuf, hbuf, NC);
    ln_kernel<true><<<NTOK, 128, 0, stream>>>(hbuf, nullptr, ln2g + l * NC, ln2b + l * NC, ybf, nullptr);
    gemm_mfma<1, 0, true, 384><<<dim3(24, 32), 256, 0, stream>>>(
        ybf, wm1_bf + (size_t)l * NHID * NC, m1b + (size_t)l * NHID, nullptr, mh_bf, NHID);
    gemm_mfma<0, 1, false, 1536><<<dim3(6, 32), 256, 0, stream>>>(
        mh_bf, wm2_bf + (size_t)l * NC * NHID, m2b + (size_t)l * NC, hbuf, hbuf, NC);
  }
  ln_kernel<false><<<NTOK, 128, 0, stream>>>(hbuf, nullptr, lnfg, lnfb, out, nullptr);
}

// Round 17
// 1633.917 us; speedup vs baseline: 1.0400x; 1.0058x over previous
//
#include <hip/hip_runtime.h>
#include <math.h>

#define DEVFN __device__ __forceinline__

constexpr int NB   = 16;     // batch
constexpr int NPTS = 8192;   // N points
constexpr int NG   = 128;    // groups
constexpr int NK   = 32;     // knn
constexpr int NC   = 384;    // model dim
constexpr int NH   = 6;      // heads
constexpr int NL   = 12;     // layers
constexpr int NHID = 1536;   // mlp hidden
constexpr int NDH  = 64;     // head dim
constexpr float LN_EPS = 1e-5f;

typedef __attribute__((ext_vector_type(8))) short short8v;
typedef __attribute__((ext_vector_type(4))) float f32x4;
typedef unsigned long long u64;

// fp32 ops without fma contraction, to track numpy's rounding in the
// index-selection stages (FPS / kNN / path ordering).
DEVFN float sq3(float x, float y, float z) {
  return __fadd_rn(__fadd_rn(__fmul_rn(x, x), __fmul_rn(y, y)), __fmul_rn(z, z));
}
DEVFN float dot3(float ax, float ay, float az, float bx, float by, float bz) {
  return __fadd_rn(__fadd_rn(__fmul_rn(ax, bx), __fmul_rn(ay, by)), __fmul_rn(az, bz));
}
DEVFN unsigned short f2bf(float f) {   // RTNE fp32 -> bf16
  unsigned u = __float_as_uint(f);
  return (unsigned short)((u + 0x7fffu + ((u >> 16) & 1u)) >> 16);
}
DEVFN float bf2f(unsigned short u) { return __uint_as_float(((unsigned)u) << 16); }

// ---------------- 1. farthest point sampling (one block per batch) ----------------
__global__ __launch_bounds__(512) void fps_kernel(const float* __restrict__ xyz,
                                                  int* __restrict__ cent) {
  extern __shared__ float dsm[];
  float* lx = dsm; float* ly = dsm + NPTS; float* lz = dsm + 2 * NPTS;
  __shared__ u64 swk[2][8];
  const int b = blockIdx.x, t = threadIdx.x;
  const float* X = xyz + (size_t)b * NPTS * 3;
  float px[16], py[16], pz[16], dd[16];
#pragma unroll
  for (int k = 0; k < 16; ++k) {
    const int i = t + k * 512;
    px[k] = X[i * 3 + 0]; py[k] = X[i * 3 + 1]; pz[k] = X[i * 3 + 2];
    lx[i] = px[k]; ly[i] = py[k]; lz[i] = pz[k];
    dd[k] = 1e10f;
  }
  __syncthreads();
  int far = 0;
  float fx = lx[0], fy = ly[0], fz = lz[0];
  for (int s = 0; s < NG; ++s) {
    if (t == 0) cent[b * NG + s] = far;
    float bv = -1.0f; int bi = 0;
#pragma unroll
    for (int k = 0; k < 16; ++k) {
      const float dx = __fsub_rn(px[k], fx);
      const float dy = __fsub_rn(py[k], fy);
      const float dz = __fsub_rn(pz[k], fz);
      const float d  = sq3(dx, dy, dz);
      const float nd = fminf(dd[k], d);
      dd[k] = nd;
      if (nd > bv) { bv = nd; bi = t + k * 512; }   // first occurrence = lowest i
    }
    u64 key = (((u64)__float_as_uint(bv)) << 32) | (unsigned)(8191 - bi);
#pragma unroll
    for (int m = 1; m < 64; m <<= 1) {
      const u64 o = __shfl_xor(key, m, 64);
      key = (o > key) ? o : key;
    }
    if ((t & 63) == 0) swk[s & 1][t >> 6] = key;
    __syncthreads();   // parity buffer: one barrier per step is race-free
    u64 fk = swk[s & 1][0];
#pragma unroll
    for (int w = 1; w < 8; ++w) fk = (swk[s & 1][w] > fk) ? swk[s & 1][w] : fk;
    far = 8191 - (int)(fk & 0xffffffffu);
    fx = lx[far]; fy = ly[far]; fz = lz[far];
  }
}

// ---------------- 2. kNN (one block per (b,g) center) ----------------
__global__ __launch_bounds__(256) void knn_kernel(const float* __restrict__ xyz,
                                                  const int* __restrict__ cent,
                                                  float* __restrict__ center,
                                                  int* __restrict__ knn) {
  __shared__ u64 swk[2][4];
  __shared__ float sc[3];
  const int bg = blockIdx.x, t = threadIdx.x;
  const int b = bg >> 7;
  const float* X = xyz + (size_t)b * NPTS * 3;
  if (t == 0) {
    const int ci = cent[bg];
    sc[0] = X[ci * 3 + 0]; sc[1] = X[ci * 3 + 1]; sc[2] = X[ci * 3 + 2];
    center[bg * 3 + 0] = sc[0]; center[bg * 3 + 1] = sc[1]; center[bg * 3 + 2] = sc[2];
  }
  __syncthreads();
  const float cx = sc[0], cy = sc[1], cz = sc[2];
  const float ra = sq3(cx, cy, cz);
  float d[32];
#pragma unroll
  for (int k = 0; k < 32; ++k) {
    const int i = t + k * 256;
    const float x = X[i * 3 + 0], y = X[i * 3 + 1], z = X[i * 3 + 2];
    const float rb = sq3(x, y, z);
    const float dt = dot3(cx, cy, cz, x, y, z);
    d[k] = fmaxf(__fsub_rn(__fadd_rn(ra, rb), __fmul_rn(2.0f, dt)), 0.0f);
  }
  float lv = 3.0e38f; int li = 0;
#pragma unroll
  for (int k = 0; k < 32; ++k) { if (d[k] < lv) { lv = d[k]; li = k; } }
  for (int k = 0; k < NK; ++k) {
    u64 key = (((u64)__float_as_uint(lv)) << 32) | (unsigned)(t + li * 256);
#pragma unroll
    for (int m = 1; m < 64; m <<= 1) {
      const u64 o = __shfl_xor(key, m, 64);
      key = (o < key) ? o : key;
    }
    if ((t & 63) == 0) swk[k & 1][t >> 6] = key;
    __syncthreads();
    u64 fk = swk[k & 1][0];
#pragma unroll
    for (int w = 1; w < 4; ++w) fk = (swk[k & 1][w] < fk) ? swk[k & 1][w] : fk;
    const int fi = (int)(fk & 0xffffffffu);
    if (t == 0) knn[(size_t)bg * NK + k] = fi;
    if ((fi & 255) == t) {
      const int kk = fi >> 8;
#pragma unroll
      for (int j = 0; j < 32; ++j) if (j == kk) d[j] = 3.0e38f;   // compile-time indices
      lv = 3.0e38f; li = 0;
#pragma unroll
      for (int j = 0; j < 32; ++j) { if (d[j] < lv) { lv = d[j]; li = j; } }
    }
  }
}

// ---------------- 3. greedy nearest path over centers (one block per batch) ----------------
__global__ __launch_bounds__(128) void order_kernel(const float* __restrict__ center,
                                                    int* __restrict__ order) {
  __shared__ float cx[NG], cy[NG], cz[NG];
  __shared__ u64 swk[2][2];
  const int b = blockIdx.x, t = threadIdx.x;
  cx[t] = center[((size_t)b * NG + t) * 3 + 0];
  cy[t] = center[((size_t)b * NG + t) * 3 + 1];
  cz[t] = center[((size_t)b * NG + t) * 3 + 2];
  bool vis = (t == 0);
  if (t == 0) order[b * NG] = 0;
  __syncthreads();
  int last = 0;
  for (int s = 1; s < NG; ++s) {
    float dv;
    const float lx = cx[last], ly = cy[last], lz = cz[last];
    if (vis) {
      dv = 3.0e38f;
    } else {
      const float ra = sq3(lx, ly, lz), rb = sq3(cx[t], cy[t], cz[t]);
      const float dd = __fsub_rn(__fadd_rn(ra, rb),
                                 __fmul_rn(2.0f, dot3(lx, ly, lz, cx[t], cy[t], cz[t])));
      dv = fmaxf(dd, 0.0f);
    }
    u64 key = (((u64)__float_as_uint(dv)) << 32) | (unsigned)t;
#pragma unroll
    for (int m = 1; m < 64; m <<= 1) {
      const u64 o = __shfl_xor(key, m, 64);
      key = (o < key) ? o : key;
    }
    if ((t & 63) == 0) swk[s & 1][t >> 6] = key;
    __syncthreads();
    const u64 fk = (swk[s & 1][1] < swk[s & 1][0]) ? swk[s & 1][1] : swk[s & 1][0];
    last = (int)(fk & 0xffffffffu);
    if (t == last) vis = true;
    if (t == 0) order[b * NG + s] = last;
  }
}

// ---------------- 4. gather ordered neighborhoods ----------------
__global__ void gather_neigh(const float* __restrict__ xyz, const int* __restrict__ knn,
                             const int* __restrict__ order, const float* __restrict__ center,
                             float* __restrict__ neigh, float* __restrict__ cord) {
  const int bg = blockIdx.x, t = threadIdx.x;  // 32 threads
  const int b = bg >> 7;
  const int src = order[bg];
  const int sbg = (b << 7) + src;
  const float c0 = center[sbg * 3 + 0], c1 = center[sbg * 3 + 1], c2 = center[sbg * 3 + 2];
  if (t < 3) cord[bg * 3 + t] = center[sbg * 3 + t];
  const int idx = knn[(size_t)sbg * NK + t];
  const float* P = xyz + ((size_t)b * NPTS + idx) * 3;
  float* o = neigh + ((size_t)bg * NK + t) * 3;
  o[0] = __fsub_rn(P[0], c0);
  o[1] = __fsub_rn(P[1], c1);
  o[2] = __fsub_rn(P[2], c2);
}

// ---------------- 5. encoder: BN1 statistics ----------------
__global__ __launch_bounds__(128) void bn1_stats(const float* __restrict__ neigh,
                                                 const float* __restrict__ w,
                                                 const float* __restrict__ bias,
                                                 float* __restrict__ psum,
                                                 float* __restrict__ psq) {
  const int c = threadIdx.x, blk = blockIdx.x;   // 256 blocks x 128 ch
  const float wx = w[c * 3 + 0], wy = w[c * 3 + 1], wz = w[c * 3 + 2], bb = bias[c];
  float s = 0.f, s2 = 0.f;
  const float* nr = neigh + (size_t)blk * 256 * 3;
  for (int r = 0; r < 256; ++r) {
    float y = fmaf(nr[r * 3 + 2], wz, fmaf(nr[r * 3 + 1], wy, fmaf(nr[r * 3 + 0], wx, bb)));
    s += y; s2 = fmaf(y, y, s2);
  }
  psum[c * 256 + blk] = s;
  psq[c * 256 + blk]  = s2;
}

// generic P-partial BN reduce: A = g*rsqrt(var+eps), B0 = b - mean*A  (M = 65536)
__global__ __launch_bounds__(256) void bn_reduce(const float* __restrict__ psum,
                                                 const float* __restrict__ psq,
                                                 const float* __restrict__ g,
                                                 const float* __restrict__ b,
                                                 float* __restrict__ A, float* __restrict__ B0,
                                                 int P) {
  __shared__ double rs[256], rq[256];
  const int c = blockIdx.x, t = threadIdx.x;
  double s = 0.0, q = 0.0;
  for (int i = t; i < P; i += 256) {
    s += (double)psum[(size_t)c * P + i];
    q += (double)psq[(size_t)c * P + i];
  }
  rs[t] = s; rq[t] = q;
  __syncthreads();
  for (int o = 128; o > 0; o >>= 1) {
    if (t < o) { rs[t] += rs[t + o]; rq[t] += rq[t + o]; }
    __syncthreads();
  }
  if (t == 0) {
    const double M = 65536.0;
    double m = rs[0] / M;
    double v = rq[0] / M - m * m;
    if (v < 0) v = 0;
    float a = g[c] * rsqrtf((float)v + LN_EPS);
    A[c] = a;
    B0[c] = b[c] - (float)m * a;
  }
}

// ---------------- 6. flat encoder stages ----------------
// f1 = relu(bn1(neigh @ ec1w^T)) -> bf16 [65536][128]
__global__ __launch_bounds__(256) void enc_f1(const float* __restrict__ neigh,
                                              const float* __restrict__ ec1w, const float* __restrict__ ec1b,
                                              const float* __restrict__ A1, const float* __restrict__ B01,
                                              unsigned short* __restrict__ f1bf) {
  __shared__ float ns[96];
  const int bg = blockIdx.x, t = threadIdx.x;
  if (t < 96) ns[t] = neigh[(size_t)bg * 96 + t];
  __syncthreads();
  for (int e = t; e < 32 * 128; e += 256) {
    const int r = e >> 7, c = e & 127;
    float y = fmaf(ns[r * 3 + 2], ec1w[c * 3 + 2],
             fmaf(ns[r * 3 + 1], ec1w[c * 3 + 1],
             fmaf(ns[r * 3 + 0], ec1w[c * 3 + 0], ec1b[c])));
    y = fmaxf(fmaf(y, A1[c], B01[c]), 0.f);
    f1bf[(size_t)bg * 4096 + e] = f2bf(y);
  }
}

// ---------------- 7. encoder A-stationary GEMM (stage 64 A-rows in LDS, sweep full N) ----
// EPI 0 (mm2): +bias, write C [N], per-group colmax -> gmaxOut (bf16)
// EPI 1 (mm3): +bias +sg[group], write C, column sum/sumsq partials (over bf16 values)
// EPI 2 (mm4): bn2-apply on A-load (relu(a*A2+B02) in bf16), no C, colmax+sc2b -> tokens
template <int K, int NTILE, int EPI>
__global__ __launch_bounds__(256) void enc_gemm(const unsigned short* __restrict__ A,
                                                const unsigned short* __restrict__ W,
                                                const float* __restrict__ bias,
                                                const float* __restrict__ sgbuf,
                                                const float* __restrict__ A2,
                                                const float* __restrict__ B02,
                                                unsigned short* __restrict__ C,
                                                unsigned short* __restrict__ gmaxOut,
                                                float* __restrict__ psum,
                                                float* __restrict__ psq,
                                                const float* __restrict__ sc2b,
                                                float* __restrict__ tokens) {
  constexpr int LDA = K + 8;   // shorts; +16B pad -> 2-way LDS bank aliasing (free)
  __shared__ unsigned short At[64 * LDA];
  const int blk = blockIdx.x, t = threadIdx.x;
  const int m0 = blk * 64;
  // ---- stage A (once) ----
  for (int idx = t; idx < 64 * (K / 8); idx += 256) {
    const int row = idx / (K / 8), off = idx % (K / 8);
    short8v v = *(const short8v*)(A + (size_t)(m0 + row) * K + off * 8);
    if (EPI == 2) {
      float a2v[8], b0v[8];
      *(float4*)(a2v)     = *(const float4*)(A2 + off * 8);
      *(float4*)(a2v + 4) = *(const float4*)(A2 + off * 8 + 4);
      *(float4*)(b0v)     = *(const float4*)(B02 + off * 8);
      *(float4*)(b0v + 4) = *(const float4*)(B02 + off * 8 + 4);
#pragma unroll
      for (int j = 0; j < 8; ++j)
        v[j] = (short)f2bf(fmaxf(fmaf(bf2f((unsigned short)v[j]), a2v[j], b0v[j]), 0.f));
    }
    *(short8v*)(At + row * LDA + off * 8) = v;
  }
  __syncthreads();
  const int lane = t & 63, wid = t >> 6;
  const int wr = wid >> 1, wc = wid & 1;
  const int lr = lane & 15, kg = lane >> 4;
  const int group = 2 * blk + wr;      // each wave's 32 rows = one group
  const unsigned short* a0 = At + (wr * 32 + lr) * LDA + kg * 8;
  const unsigned short* a1 = a0 + 16 * LDA;
  for (int nt = 0; nt < NTILE / 64; ++nt) {
    const int n0 = nt * 64 + wc * 32;
    const unsigned short* b0 = W + (size_t)(n0 + lr) * K + kg * 8;
    const unsigned short* b1 = b0 + (size_t)16 * K;
    f32x4 acc00 = {0.f, 0.f, 0.f, 0.f}, acc01 = acc00, acc10 = acc00, acc11 = acc00;
#pragma unroll
    for (int k0 = 0; k0 < K; k0 += 32) {
      const short8v av0 = *(const short8v*)(a0 + k0);
      const short8v av1 = *(const short8v*)(a1 + k0);
      const short8v bv0 = *(const short8v*)(b0 + k0);
      const short8v bv1 = *(const short8v*)(b1 + k0);
      acc00 = __builtin_amdgcn_mfma_f32_16x16x32_bf16(av0, bv0, acc00, 0, 0, 0);
      acc01 = __builtin_amdgcn_mfma_f32_16x16x32_bf16(av0, bv1, acc01, 0, 0, 0);
      acc10 = __builtin_amdgcn_mfma_f32_16x16x32_bf16(av1, bv0, acc10, 0, 0, 0);
      acc11 = __builtin_amdgcn_mfma_f32_16x16x32_bf16(av1, bv1, acc11, 0, 0, 0);
    }
    // ---- epilogue ----
#pragma unroll
    for (int j = 0; j < 2; ++j) {
      const int n = n0 + j * 16 + lr;
      float red0 = (EPI == 1) ? 0.f : -3.0e38f;   // sum or max
      float red1 = 0.f;                            // sumsq
      float base = 0.f;
      if (EPI == 0) base = bias[n];
      if (EPI == 1) base = bias[n] + sgbuf[(size_t)group * NTILE + n];
#pragma unroll
      for (int i = 0; i < 2; ++i) {
        const f32x4 a = (i == 0) ? (j == 0 ? acc00 : acc01) : (j == 0 ? acc10 : acc11);
#pragma unroll
        for (int r = 0; r < 4; ++r) {
          const int m = m0 + wr * 32 + i * 16 + kg * 4 + r;
          const float v = a[r] + base;
          if (EPI == 0) {
            C[(size_t)m * NTILE + n] = f2bf(v);
            red0 = fmaxf(red0, v);
          } else if (EPI == 1) {
            const unsigned short us = f2bf(v);
            C[(size_t)m * NTILE + n] = us;
            const float vv = bf2f(us);
            red0 += vv; red1 = fmaf(vv, vv, red1);
          } else {
            red0 = fmaxf(red0, v);
          }
        }
      }
      // reduce over kg (rows within the group): lanes lr, lr+16, lr+32, lr+48
      if (EPI == 1) {
        red0 += __shfl_xor(red0, 16, 64); red0 += __shfl_xor(red0, 32, 64);
        red1 += __shfl_xor(red1, 16, 64); red1 += __shfl_xor(red1, 32, 64);
        if (kg == 0) {
          psum[(size_t)n * 2048 + blk * 2 + wr] = red0;
          psq[(size_t)n * 2048 + blk * 2 + wr]  = red1;
        }
      } else {
        red0 = fmaxf(red0, __shfl_xor(red0, 16, 64));
        red0 = fmaxf(red0, __shfl_xor(red0, 32, 64));
        if (kg == 0) {
          if (EPI == 0) gmaxOut[(size_t)group * NTILE + n] = f2bf(red0);
          else          tokens[(size_t)group * NTILE + n] = red0 + sc2b[n];
        }
      }
    }
  }
}

// ---------------- 8. positional embedding + h init (merged) ----------------
__global__ void pos_hinit(const float* __restrict__ cord, const float* __restrict__ tokens,
                          const float* __restrict__ sos,
                          float* __restrict__ pos, float* __restrict__ h) {
  const int tok = blockIdx.x, t = threadIdx.x;   // 384 threads
  const int c = t >> 7;
  const int rem = t & 127;
  const int i = rem >> 1;
  const int isc = rem & 1;
  const float coord = cord[tok * 3 + c];
  const float ex = 2.0f * (float)i / 128.0f;
  const float inv = 1.0f / powf(10000.0f, ex);
  const float ang = coord * inv;
  pos[(size_t)tok * NC + t] = isc ? cosf(ang) : sinf(ang);
  const int b = tok >> 7, g = tok & 127;
  h[(size_t)tok * NC + t] = (g == 0) ? sos[t] : tokens[((size_t)b * NG + (g - 1)) * NC + t];
}

// ---------------- weight fp32 -> bf16 conversion (all segments, one kernel) ----------------
__global__ void cvt_all(const float* __restrict__ qkvw, const float* __restrict__ outw,
                        const float* __restrict__ m1w, const float* __restrict__ m2w,
                        const float* __restrict__ ec2w, const float* __restrict__ sc1w,
                        const float* __restrict__ sc2w,
                        unsigned short* __restrict__ wqkv, unsigned short* __restrict__ wout,
                        unsigned short* __restrict__ wm1, unsigned short* __restrict__ wm2,
                        unsigned short* __restrict__ ec2, unsigned short* __restrict__ w3a,
                        unsigned short* __restrict__ w3b, unsigned short* __restrict__ sc2) {
  constexpr int S0 = NL * 3 * NC * NC;          // 5308416
  constexpr int O0 = S0;
  constexpr int O1 = O0 + NL * NC * NC;         // +1769472
  constexpr int O2 = O1 + NL * NHID * NC;       // +7077888
  constexpr int O3 = O2 + NL * NC * NHID;       // +7077888
  constexpr int O4 = O3 + 256 * 128;
  constexpr int O5 = O4 + 512 * 512;
  constexpr int TOT = O5 + 384 * 512;
  for (int i = blockIdx.x * blockDim.x + threadIdx.x; i < TOT; i += gridDim.x * blockDim.x) {
    if (i < O0)      wqkv[i] = f2bf(qkvw[i]);
    else if (i < O1) wout[i - O0] = f2bf(outw[i - O0]);
    else if (i < O2) wm1[i - O1] = f2bf(m1w[i - O1]);
    else if (i < O3) wm2[i - O2] = f2bf(m2w[i - O2]);
    else if (i < O4) ec2[i - O3] = f2bf(ec2w[i - O3]);
    else if (i < O5) {
      const int ii = i - O4, c = ii >> 9, k = ii & 511;
      const unsigned short v = f2bf(sc1w[ii]);
      if (k < 256) w3a[c * 256 + k] = v;
      else         w3b[c * 256 + (k - 256)] = v;
    } else sc2[i - O5] = f2bf(sc2w[i - O5]);
  }
}

// ---------------- 9. layernorm (shuffle-reduce; optionally add first; y fp32 or bf16) ------
template <bool BF16OUT>
__global__ __launch_bounds__(128) void ln_kernel(const float* __restrict__ in,
                                                 const float* __restrict__ add,
                                                 const float* __restrict__ g,
                                                 const float* __restrict__ b,
                                                 void* __restrict__ y,
                                                 float* __restrict__ xout) {
  __shared__ float sm[4];
  const int row = blockIdx.x, t = threadIdx.x, w = t >> 6;
  const float* ip = in + (size_t)row * NC;
  float v0 = ip[t], v1 = ip[t + 128], v2 = ip[t + 256];
  if (add) {
    const float* ap = add + (size_t)row * NC;
    v0 += ap[t]; v1 += ap[t + 128]; v2 += ap[t + 256];
  }
  float s = v0 + v1 + v2;
#pragma unroll
  for (int m = 1; m < 64; m <<= 1) s += __shfl_xor(s, m, 64);
  if ((t & 63) == 0) sm[w] = s;
  __syncthreads();
  const float mean = (sm[0] + sm[1]) / (float)NC;
  const float d0 = v0 - mean, d1 = v1 - mean, d2 = v2 - mean;
  float sq = d0 * d0 + d1 * d1 + d2 * d2;
#pragma unroll
  for (int m = 1; m < 64; m <<= 1) sq += __shfl_xor(sq, m, 64);
  if ((t & 63) == 0) sm[2 + w] = sq;
  __syncthreads();
  const float rs = rsqrtf((sm[2] + sm[3]) / (float)NC + LN_EPS);
  const float y0 = d0 * rs * g[t] + b[t];
  const float y1 = d1 * rs * g[t + 128] + b[t + 128];
  const float y2 = d2 * rs * g[t + 256] + b[t + 256];
  if (BF16OUT) {
    unsigned short* yp = (unsigned short*)y + (size_t)row * NC;
    yp[t] = f2bf(y0); yp[t + 128] = f2bf(y1); yp[t + 256] = f2bf(y2);
  } else {
    float* yp = (float*)y + (size_t)row * NC;
    yp[t] = y0; yp[t + 128] = y1; yp[t + 256] = y2;
  }
  if (xout) {
    float* xp = xout + (size_t)row * NC;
    xp[t] = v0; xp[t + 128] = v1; xp[t + 256] = v2;
  }
}

// ---------------- 10. bf16 MFMA GEMM: C = act(A @ W^T + bias) (+res) ----------------
// RESMODE: 0=none, 1=+R[m*N+n]
template <int ACT, int RESMODE, bool OUT_BF, int K>
__global__ __launch_bounds__(256) void gemm_mfma(const unsigned short* __restrict__ A,
                                                 const unsigned short* __restrict__ W,
                                                 const float* __restrict__ bias,
                                                 const float* __restrict__ R,
                                                 void* __restrict__ Cv,
                                                 int N) {
  const int t = threadIdx.x;
  const int lane = t & 63, wid = t >> 6;
  const int wr = wid >> 1, wc = wid & 1;
  const int m0 = blockIdx.y * 64 + wr * 32;
  const int n0 = blockIdx.x * 64 + wc * 32;
  const int lr = lane & 15, kg = lane >> 4;
  const unsigned short* a0p = A + (size_t)(m0 + lr) * K + kg * 8;
  const unsigned short* a1p = a0p + (size_t)16 * K;
  const unsigned short* b0p = W + (size_t)(n0 + lr) * K + kg * 8;
  const unsigned short* b1p = b0p + (size_t)16 * K;
  f32x4 acc00 = {0.f, 0.f, 0.f, 0.f}, acc01 = acc00, acc10 = acc00, acc11 = acc00;
#pragma unroll 2
  for (int k0 = 0; k0 < K; k0 += 32) {
    const short8v av0 = *(const short8v*)(a0p + k0);
    const short8v av1 = *(const short8v*)(a1p + k0);
    const short8v bv0 = *(const short8v*)(b0p + k0);
    const short8v bv1 = *(const short8v*)(b1p + k0);
    acc00 = __builtin_amdgcn_mfma_f32_16x16x32_bf16(av0, bv0, acc00, 0, 0, 0);
    acc01 = __builtin_amdgcn_mfma_f32_16x16x32_bf16(av0, bv1, acc01, 0, 0, 0);
    acc10 = __builtin_amdgcn_mfma_f32_16x16x32_bf16(av1, bv0, acc10, 0, 0, 0);
    acc11 = __builtin_amdgcn_mfma_f32_16x16x32_bf16(av1, bv1, acc11, 0, 0, 0);
  }
#pragma unroll
  for (int i = 0; i < 2; ++i) {
#pragma unroll
    for (int j = 0; j < 2; ++j) {
      const f32x4 a = (i == 0) ? (j == 0 ? acc00 : acc01) : (j == 0 ? acc10 : acc11);
      const int n = n0 + j * 16 + lr;
      const float bn = bias ? bias[n] : 0.f;
#pragma unroll
      for (int r = 0; r < 4; ++r) {
        const int m = m0 + i * 16 + kg * 4 + r;
        float v = a[r] + bn;
        if (ACT == 1) v = 0.5f * v * (1.0f + erff(v * 0.70710678118654752f));
        if (RESMODE == 1) v += R[(size_t)m * N + n];
        if (OUT_BF) ((unsigned short*)Cv)[(size_t)m * N + n] = f2bf(v);
        else        ((float*)Cv)[(size_t)m * N + n] = v;
      }
    }
  }
}

// ---------------- 11. fused attention via MFMA: scores + softmax + PV ----------------
// one block per (b, h, 64-row half); 4 waves, wave w owns 16 q-rows.
__global__ __launch_bounds__(256) void attn_fused(const unsigned short* __restrict__ qkv,
                                                  unsigned short* __restrict__ obuf) {
  __shared__ __align__(16) unsigned short qs[64 * 72];    // Q [64][64] pad 8
  __shared__ __align__(16) unsigned short ks[128 * 72];   // K [128][64] pad 8
  __shared__ __align__(16) unsigned short vt[64 * 136];   // V^T [64][128] pad 8
  __shared__ __align__(16) unsigned short ps[64 * 136];   // P [64][128] pad 8
  const int blk = blockIdx.x, t = threadIdx.x;
  const int qt = blk & 1;
  const int h = (blk >> 1) % NH;
  const int b = blk / (2 * NH);
  const size_t qbase = ((size_t)(b * NG + qt * 64)) * (3 * NC) + h * NDH;
  const size_t kbase = ((size_t)(b * NG)) * (3 * NC) + NC + h * NDH;
  const size_t vbase = kbase + NC;
#pragma unroll
  for (int it = 0; it < 2; ++it) {   // Q: 512 8-short tasks
    const int idx = t + it * 256;
    const int r = idx >> 3, c0 = (idx & 7) * 8;
    *(short8v*)(qs + r * 72 + c0) = *(const short8v*)(qkv + qbase + (size_t)r * (3 * NC) + c0);
  }
#pragma unroll
  for (int it = 0; it < 4; ++it) {   // K: 1024 tasks
    const int idx = t + it * 256;
    const int r = idx >> 3, c0 = (idx & 7) * 8;
    *(short8v*)(ks + r * 72 + c0) = *(const short8v*)(qkv + kbase + (size_t)r * (3 * NC) + c0);
  }
#pragma unroll
  for (int it = 0; it < 4; ++it) {   // V transposed
    const int idx = t + it * 256;
    const int r = idx >> 3, c0 = (idx & 7) * 8;
    const short8v v = *(const short8v*)(qkv + vbase + (size_t)r * (3 * NC) + c0);
#pragma unroll
    for (int j = 0; j < 8; ++j) vt[(c0 + j) * 136 + r] = (unsigned short)v[j];
  }
  __syncthreads();
  const int lane = t & 63, w = t >> 6;
  const int lr = lane & 15, kg = lane >> 4;
  // ---- QK^T: wave w computes rows [w*16, w*16+16) x all 128 cols ----
  f32x4 sc[8] = {};
  {
    const short8v av0 = *(const short8v*)(qs + (w * 16 + lr) * 72 + kg * 8);
    const short8v av1 = *(const short8v*)(qs + (w * 16 + lr) * 72 + 32 + kg * 8);
#pragma unroll
    for (int j = 0; j < 8; ++j) {
      const short8v bv0 = *(const short8v*)(ks + (j * 16 + lr) * 72 + kg * 8);
      const short8v bv1 = *(const short8v*)(ks + (j * 16 + lr) * 72 + 32 + kg * 8);
      sc[j] = __builtin_amdgcn_mfma_f32_16x16x32_bf16(av0, bv0, sc[j], 0, 0, 0);
      sc[j] = __builtin_amdgcn_mfma_f32_16x16x32_bf16(av1, bv1, sc[j], 0, 0, 0);
    }
  }
  // ---- softmax (rows of this wave live in-wave: col=j*16+lr, row=kg*4+r) ----
#pragma unroll
  for (int r = 0; r < 4; ++r) {
    const int rowg = qt * 64 + w * 16 + kg * 4 + r;
    float pj[8];
    float mx = -3.0e38f;
#pragma unroll
    for (int j = 0; j < 8; ++j) {
      const int col = j * 16 + lr;
      const float s = (col <= rowg) ? sc[j][r] * 0.125f : -1e9f;
      pj[j] = s;
      mx = fmaxf(mx, s);
    }
#pragma unroll
    for (int m = 1; m < 16; m <<= 1) mx = fmaxf(mx, __shfl_xor(mx, m, 64));
    float sum = 0.f;
#pragma unroll
    for (int j = 0; j < 8; ++j) { pj[j] = expf(pj[j] - mx); sum += pj[j]; }
#pragma unroll
    for (int m = 1; m < 16; m <<= 1) sum += __shfl_xor(sum, m, 64);
#pragma unroll
    for (int j = 0; j < 8; ++j)
      ps[(w * 16 + kg * 4 + r) * 136 + j * 16 + lr] = f2bf(pj[j] / sum);
  }
  __syncthreads();
  // ---- PV: rows [w*16, w*16+16) x 64 dims, K=128 ----
  f32x4 oc[4] = {};
#pragma unroll
  for (int k = 0; k < 4; ++k) {
    const short8v av = *(const short8v*)(ps + (w * 16 + lr) * 136 + k * 32 + kg * 8);
#pragma unroll
    for (int dj = 0; dj < 4; ++dj) {
      const short8v bv = *(const short8v*)(vt + (dj * 16 + lr) * 136 + k * 32 + kg * 8);
      oc[dj] = __builtin_amdgcn_mfma_f32_16x16x32_bf16(av, bv, oc[dj], 0, 0, 0);
    }
  }
#pragma unroll
  for (int dj = 0; dj < 4; ++dj) {
#pragma unroll
    for (int r = 0; r < 4; ++r) {
      const int m = qt * 64 + w * 16 + kg * 4 + r;
      obuf[((size_t)(b * NG + m)) * NC + h * NDH + dj * 16 + lr] = f2bf(oc[dj][r]);
    }
  }
}

// ---------------- launch ----------------
extern "C" void kernel_launch(void* const* d_in, const int* in_sizes, int n_in,
                              void* d_out, int out_size, void* d_ws, size_t ws_size,
                              hipStream_t stream) {
  (void)in_sizes; (void)n_in; (void)out_size; (void)ws_size;
  const float* xyz  = (const float*)d_in[0];
  const float* ec1w = (const float*)d_in[1];
  const float* ec1b = (const float*)d_in[2];
  const float* bn1g = (const float*)d_in[3];
  const float* bn1b = (const float*)d_in[4];
  const float* ec2w = (const float*)d_in[5];
  const float* ec2b = (const float*)d_in[6];
  const float* sc1w = (const float*)d_in[7];
  const float* sc1b = (const float*)d_in[8];
  const float* bn2g = (const float*)d_in[9];
  const float* bn2b = (const float*)d_in[10];
  const float* sc2w = (const float*)d_in[11];
  const float* sc2b = (const float*)d_in[12];
  const float* sos  = (const float*)d_in[13];
  const float* ln1g = (const float*)d_in[14];
  const float* ln1b = (const float*)d_in[15];
  const float* qkvw = (const float*)d_in[16];
  const float* qkvb = (const float*)d_in[17];
  const float* outw = (const float*)d_in[18];
  const float* outb = (const float*)d_in[19];
  const float* ln2g = (const float*)d_in[20];
  const float* ln2b = (const float*)d_in[21];
  const float* m1w  = (const float*)d_in[22];
  const float* m1b  = (const float*)d_in[23];
  const float* m2w  = (const float*)d_in[24];
  const float* m2b  = (const float*)d_in[25];
  const float* lnfg = (const float*)d_in[26];
  const float* lnfb = (const float*)d_in[27];
  float* out = (float*)d_out;

  char* p = (char*)d_ws;
  auto carve = [&](size_t bytes) -> void* {
    void* q = (void*)p;
    p += (bytes + 255) & ~(size_t)255;
    return q;
  };
  int*   cent   = (int*)carve((size_t)NB * NG * 4);
  float* center = (float*)carve((size_t)NB * NG * 3 * 4);
  int*   knn    = (int*)carve((size_t)NB * NG * NK * 4);
  int*   order  = (int*)carve((size_t)NB * NG * 4);
  float* neigh  = (float*)carve((size_t)NB * NG * NK * 3 * 4);
  float* cord   = (float*)carve((size_t)NB * NG * 3 * 4);
  float* psum1  = (float*)carve((size_t)128 * 256 * 4);
  float* psq1   = (float*)carve((size_t)128 * 256 * 4);
  float* A1     = (float*)carve(128 * 4);
  float* B01    = (float*)carve(128 * 4);
  float* psum2  = (float*)carve((size_t)512 * 2048 * 4);
  float* psq2   = (float*)carve((size_t)512 * 2048 * 4);
  float* A2     = (float*)carve(512 * 4);
  float* B02    = (float*)carve(512 * 4);
  float* tokens = (float*)carve((size_t)NB * NG * NC * 4);
  float* posb   = (float*)carve((size_t)NB * NG * NC * 4);
  float* hbuf   = (float*)carve((size_t)NB * NG * NC * 4);
  float* xbuf   = (float*)carve((size_t)NB * NG * NC * 4);
  unsigned short* ybf    = (unsigned short*)carve((size_t)NB * NG * NC * 2);
  unsigned short* qkv_bf = (unsigned short*)carve((size_t)NB * NG * 3 * NC * 2);
  unsigned short* obf    = (unsigned short*)carve((size_t)NB * NG * NC * 2);
  unsigned short* mh_bf  = (unsigned short*)carve((size_t)NB * NG * NHID * 2);
  unsigned short* wqkv_bf = (unsigned short*)carve((size_t)NL * 3 * NC * NC * 2);
  unsigned short* wout_bf = (unsigned short*)carve((size_t)NL * NC * NC * 2);
  unsigned short* wm1_bf  = (unsigned short*)carve((size_t)NL * NHID * NC * 2);
  unsigned short* wm2_bf  = (unsigned short*)carve((size_t)NL * NC * NHID * 2);
  // encoder bf16 weights
  unsigned short* ec2w_bf = (unsigned short*)carve((size_t)256 * 128 * 2);
  unsigned short* w3a_bf  = (unsigned short*)carve((size_t)512 * 256 * 2);
  unsigned short* w3b_bf  = (unsigned short*)carve((size_t)512 * 256 * 2);
  unsigned short* sc2w_bf = (unsigned short*)carve((size_t)384 * 512 * 2);
  // encoder activations (flat)
  unsigned short* f1bf   = (unsigned short*)carve((size_t)65536 * 128 * 2);  // 16.78 MB
  unsigned short* f2bf_a = (unsigned short*)carve((size_t)65536 * 256 * 2);  // 33.55 MB
  unsigned short* gmaxbf = (unsigned short*)carve((size_t)2048 * 256 * 2);
  float*          sgbuf  = (float*)carve((size_t)2048 * 512 * 4);
  unsigned short* s3bf   = (unsigned short*)carve((size_t)65536 * 512 * 2);  // 67.1 MB

  const int NTOK = NB * NG;  // 2048

  // weight conversion (deterministic, every call; one kernel)
  cvt_all<<<2048, 256, 0, stream>>>(qkvw, outw, m1w, m2w, ec2w, sc1w, sc2w,
                                    wqkv_bf, wout_bf, wm1_bf, wm2_bf,
                                    ec2w_bf, w3a_bf, w3b_bf, sc2w_bf);

  fps_kernel<<<NB, 512, 3 * NPTS * 4, stream>>>(xyz, cent);
  knn_kernel<<<NTOK, 256, 0, stream>>>(xyz, cent, center, knn);
  order_kernel<<<NB, 128, 0, stream>>>(center, order);
  gather_neigh<<<NTOK, 32, 0, stream>>>(xyz, knn, order, center, neigh, cord);

  // ---- encoder (flat MFMA pipeline, A-stationary, fused reductions) ----
  bn1_stats<<<256, 128, 0, stream>>>(neigh, ec1w, ec1b, psum1, psq1);
  bn_reduce<<<128, 256, 0, stream>>>(psum1, psq1, bn1g, bn1b, A1, B01, 256);
  enc_f1<<<NTOK, 256, 0, stream>>>(neigh, ec1w, ec1b, A1, B01, f1bf);
  enc_gemm<128, 256, 0><<<1024, 256, 0, stream>>>(
      f1bf, ec2w_bf, ec2b, nullptr, nullptr, nullptr,
      f2bf_a, gmaxbf, nullptr, nullptr, nullptr, nullptr);
  gemm_mfma<0, 0, false, 256><<<dim3(8, 32), 256, 0, stream>>>(
      gmaxbf, w3a_bf, nullptr, nullptr, sgbuf, 512);
  enc_gemm<256, 512, 1><<<1024, 256, 0, stream>>>(
      f2bf_a, w3b_bf, sc1b, sgbuf, nullptr, nullptr,
      s3bf, nullptr, psum2, psq2, nullptr, nullptr);
  bn_reduce<<<512, 256, 0, stream>>>(psum2, psq2, bn2g, bn2b, A2, B02, 2048);
  enc_gemm<512, 384, 2><<<1024, 256, 0, stream>>>(
      s3bf, sc2w_bf, nullptr, nullptr, A2, B02,
      nullptr, nullptr, nullptr, nullptr, sc2b, tokens);

  pos_hinit<<<NTOK, NC, 0, stream>>>(cord, tokens, sos, posb, hbuf);

  for (int l = 0; l < NL; ++l) {
    ln_kernel<true><<<NTOK, 128, 0, stream>>>(hbuf, posb, ln1g + l * NC, ln1b + l * NC, ybf, xbuf);
    gemm_mfma<0, 0, true, 384><<<dim3(18, 32), 256, 0, stream>>>(
        ybf, wqkv_bf + (size_t)l * 3 * NC * NC, qkvb + (size_t)l * 3 * NC, nullptr, qkv_bf,
        3 * NC);
    attn_fused<<<NB * NH * 2, 256, 0, stream>>>(qkv_bf, obf);
    gemm_mfma<0, 1, false, 384><<<dim3(6, 32), 256, 0, stream>>>(
        obf, wout_bf + (size_t)l * NC * NC, outb + (size_t)l * NC, xbuf, hbuf, NC);
    ln_kernel<true><<<NTOK, 128, 0, stream>>>(hbuf, nullptr, ln2g + l * NC, ln2b + l * NC, ybf, nullptr);
    gemm_mfma<1, 0, true, 384><<<dim3(24, 32), 256, 0, stream>>>(
        ybf, wm1_bf + (size_t)l * NHID * NC, m1b + (size_t)l * NHID, nullptr, mh_bf, NHID);
    gemm_mfma<0, 1, false, 1536><<<dim3(6, 32), 256, 0, stream>>>(
        mh_bf, wm2_bf + (size_t)l * NC * NHID, m2b + (size_t)l * NC, hbuf, hbuf, NC);
  }
  ln_kernel<false><<<NTOK, 128, 0, stream>>>(hbuf, nullptr, lnfg, lnfb, out, nullptr);
}

// Round 18
// 1596.969 us; speedup vs baseline: 1.0640x; 1.0231x over previous
//
#include <hip/hip_runtime.h>
#include <math.h>

#define DEVFN __device__ __forceinline__

constexpr int NB   = 16;     // batch
constexpr int NPTS = 8192;   // N points
constexpr int NG   = 128;    // groups
constexpr int NK   = 32;     // knn
constexpr int NC   = 384;    // model dim
constexpr int NH   = 6;      // heads
constexpr int NL   = 12;     // layers
constexpr int NHID = 1536;   // mlp hidden
constexpr int NDH  = 64;     // head dim
constexpr float LN_EPS = 1e-5f;

typedef __attribute__((ext_vector_type(8))) short short8v;
typedef __attribute__((ext_vector_type(4))) float f32x4;
typedef unsigned long long u64;

// fp32 ops without fma contraction, to track numpy's rounding in the
// index-selection stages (FPS / kNN / path ordering).
DEVFN float sq3(float x, float y, float z) {
  return __fadd_rn(__fadd_rn(__fmul_rn(x, x), __fmul_rn(y, y)), __fmul_rn(z, z));
}
DEVFN float dot3(float ax, float ay, float az, float bx, float by, float bz) {
  return __fadd_rn(__fadd_rn(__fmul_rn(ax, bx), __fmul_rn(ay, by)), __fmul_rn(az, bz));
}
DEVFN unsigned short f2bf(float f) {   // RTNE fp32 -> bf16
  unsigned u = __float_as_uint(f);
  return (unsigned short)((u + 0x7fffu + ((u >> 16) & 1u)) >> 16);
}
DEVFN float bf2f(unsigned short u) { return __uint_as_float(((unsigned)u) << 16); }

// ---------------- 1. FPS (blocks 0..15) + weight cvt (blocks 16+) fused ----------------
// fps: one block per batch, 512 thr, 96KB dynamic LDS; cvt: independent streaming.
__global__ __launch_bounds__(512) void fps_cvt(const float* __restrict__ xyz,
                                               int* __restrict__ cent,
                                               const float* __restrict__ qkvw, const float* __restrict__ outw,
                                               const float* __restrict__ m1w, const float* __restrict__ m2w,
                                               const float* __restrict__ ec2w, const float* __restrict__ sc1w,
                                               const float* __restrict__ sc2w,
                                               unsigned short* __restrict__ wqkv, unsigned short* __restrict__ wout,
                                               unsigned short* __restrict__ wm1, unsigned short* __restrict__ wm2,
                                               unsigned short* __restrict__ ec2, unsigned short* __restrict__ w3a,
                                               unsigned short* __restrict__ w3b, unsigned short* __restrict__ sc2) {
  if (blockIdx.x >= NB) {
    // ---- cvt branch ----
    constexpr int O0 = NL * 3 * NC * NC;
    constexpr int O1 = O0 + NL * NC * NC;
    constexpr int O2 = O1 + NL * NHID * NC;
    constexpr int O3 = O2 + NL * NC * NHID;
    constexpr int O4 = O3 + 256 * 128;
    constexpr int O5 = O4 + 512 * 512;
    constexpr int TOT = O5 + 384 * 512;
    const int stride = (gridDim.x - NB) * 512;
    for (int i = (blockIdx.x - NB) * 512 + threadIdx.x; i < TOT; i += stride) {
      if (i < O0)      wqkv[i] = f2bf(qkvw[i]);
      else if (i < O1) wout[i - O0] = f2bf(outw[i - O0]);
      else if (i < O2) wm1[i - O1] = f2bf(m1w[i - O1]);
      else if (i < O3) wm2[i - O2] = f2bf(m2w[i - O2]);
      else if (i < O4) ec2[i - O3] = f2bf(ec2w[i - O3]);
      else if (i < O5) {
        const int ii = i - O4, c = ii >> 9, k = ii & 511;
        const unsigned short v = f2bf(sc1w[ii]);
        if (k < 256) w3a[c * 256 + k] = v;
        else         w3b[c * 256 + (k - 256)] = v;
      } else sc2[i - O5] = f2bf(sc2w[i - O5]);
    }
    return;
  }
  // ---- fps branch (identical to the standalone fps_kernel) ----
  extern __shared__ float dsm[];
  float* lx = dsm; float* ly = dsm + NPTS; float* lz = dsm + 2 * NPTS;
  __shared__ u64 swk[2][8];
  const int b = blockIdx.x, t = threadIdx.x;
  const float* X = xyz + (size_t)b * NPTS * 3;
  float px[16], py[16], pz[16], dd[16];
#pragma unroll
  for (int k = 0; k < 16; ++k) {
    const int i = t + k * 512;
    px[k] = X[i * 3 + 0]; py[k] = X[i * 3 + 1]; pz[k] = X[i * 3 + 2];
    lx[i] = px[k]; ly[i] = py[k]; lz[i] = pz[k];
    dd[k] = 1e10f;
  }
  __syncthreads();
  int far = 0;
  float fx = lx[0], fy = ly[0], fz = lz[0];
  for (int s = 0; s < NG; ++s) {
    if (t == 0) cent[b * NG + s] = far;
    float bv = -1.0f; int bi = 0;
#pragma unroll
    for (int k = 0; k < 16; ++k) {
      const float dx = __fsub_rn(px[k], fx);
      const float dy = __fsub_rn(py[k], fy);
      const float dz = __fsub_rn(pz[k], fz);
      const float d  = sq3(dx, dy, dz);
      const float nd = fminf(dd[k], d);
      dd[k] = nd;
      if (nd > bv) { bv = nd; bi = t + k * 512; }   // first occurrence = lowest i
    }
    u64 key = (((u64)__float_as_uint(bv)) << 32) | (unsigned)(8191 - bi);
#pragma unroll
    for (int m = 1; m < 64; m <<= 1) {
      const u64 o = __shfl_xor(key, m, 64);
      key = (o > key) ? o : key;
    }
    if ((t & 63) == 0) swk[s & 1][t >> 6] = key;
    __syncthreads();   // parity buffer: one barrier per step is race-free
    u64 fk = swk[s & 1][0];
#pragma unroll
    for (int w = 1; w < 8; ++w) fk = (swk[s & 1][w] > fk) ? swk[s & 1][w] : fk;
    far = 8191 - (int)(fk & 0xffffffffu);
    fx = lx[far]; fy = ly[far]; fz = lz[far];
  }
}

// ---------------- 2. kNN (one block per (b,g) center) ----------------
__global__ __launch_bounds__(256) void knn_kernel(const float* __restrict__ xyz,
                                                  const int* __restrict__ cent,
                                                  float* __restrict__ center,
                                                  int* __restrict__ knn) {
  __shared__ u64 swk[2][4];
  __shared__ float sc[3];
  const int bg = blockIdx.x, t = threadIdx.x;
  const int b = bg >> 7;
  const float* X = xyz + (size_t)b * NPTS * 3;
  if (t == 0) {
    const int ci = cent[bg];
    sc[0] = X[ci * 3 + 0]; sc[1] = X[ci * 3 + 1]; sc[2] = X[ci * 3 + 2];
    center[bg * 3 + 0] = sc[0]; center[bg * 3 + 1] = sc[1]; center[bg * 3 + 2] = sc[2];
  }
  __syncthreads();
  const float cx = sc[0], cy = sc[1], cz = sc[2];
  const float ra = sq3(cx, cy, cz);
  float d[32];
#pragma unroll
  for (int k = 0; k < 32; ++k) {
    const int i = t + k * 256;
    const float x = X[i * 3 + 0], y = X[i * 3 + 1], z = X[i * 3 + 2];
    const float rb = sq3(x, y, z);
    const float dt = dot3(cx, cy, cz, x, y, z);
    d[k] = fmaxf(__fsub_rn(__fadd_rn(ra, rb), __fmul_rn(2.0f, dt)), 0.0f);
  }
  float lv = 3.0e38f; int li = 0;
#pragma unroll
  for (int k = 0; k < 32; ++k) { if (d[k] < lv) { lv = d[k]; li = k; } }
  for (int k = 0; k < NK; ++k) {
    u64 key = (((u64)__float_as_uint(lv)) << 32) | (unsigned)(t + li * 256);
#pragma unroll
    for (int m = 1; m < 64; m <<= 1) {
      const u64 o = __shfl_xor(key, m, 64);
      key = (o < key) ? o : key;
    }
    if ((t & 63) == 0) swk[k & 1][t >> 6] = key;
    __syncthreads();
    u64 fk = swk[k & 1][0];
#pragma unroll
    for (int w = 1; w < 4; ++w) fk = (swk[k & 1][w] < fk) ? swk[k & 1][w] : fk;
    const int fi = (int)(fk & 0xffffffffu);
    if (t == 0) knn[(size_t)bg * NK + k] = fi;
    if ((fi & 255) == t) {
      const int kk = fi >> 8;
#pragma unroll
      for (int j = 0; j < 32; ++j) if (j == kk) d[j] = 3.0e38f;   // compile-time indices
      lv = 3.0e38f; li = 0;
#pragma unroll
      for (int j = 0; j < 32; ++j) { if (d[j] < lv) { lv = d[j]; li = j; } }
    }
  }
}

// ---------------- 3. greedy nearest path over centers (one block per batch) ----------------
__global__ __launch_bounds__(128) void order_kernel(const float* __restrict__ center,
                                                    int* __restrict__ order) {
  __shared__ float cx[NG], cy[NG], cz[NG];
  __shared__ u64 swk[2][2];
  const int b = blockIdx.x, t = threadIdx.x;
  cx[t] = center[((size_t)b * NG + t) * 3 + 0];
  cy[t] = center[((size_t)b * NG + t) * 3 + 1];
  cz[t] = center[((size_t)b * NG + t) * 3 + 2];
  bool vis = (t == 0);
  if (t == 0) order[b * NG] = 0;
  __syncthreads();
  int last = 0;
  for (int s = 1; s < NG; ++s) {
    float dv;
    const float lx = cx[last], ly = cy[last], lz = cz[last];
    if (vis) {
      dv = 3.0e38f;
    } else {
      const float ra = sq3(lx, ly, lz), rb = sq3(cx[t], cy[t], cz[t]);
      const float dd = __fsub_rn(__fadd_rn(ra, rb),
                                 __fmul_rn(2.0f, dot3(lx, ly, lz, cx[t], cy[t], cz[t])));
      dv = fmaxf(dd, 0.0f);
    }
    u64 key = (((u64)__float_as_uint(dv)) << 32) | (unsigned)t;
#pragma unroll
    for (int m = 1; m < 64; m <<= 1) {
      const u64 o = __shfl_xor(key, m, 64);
      key = (o < key) ? o : key;
    }
    if ((t & 63) == 0) swk[s & 1][t >> 6] = key;
    __syncthreads();
    const u64 fk = (swk[s & 1][1] < swk[s & 1][0]) ? swk[s & 1][1] : swk[s & 1][0];
    last = (int)(fk & 0xffffffffu);
    if (t == last) vis = true;
    if (t == 0) order[b * NG + s] = last;
  }
}

// ---------------- 4. gather ordered neighborhoods ----------------
__global__ void gather_neigh(const float* __restrict__ xyz, const int* __restrict__ knn,
                             const int* __restrict__ order, const float* __restrict__ center,
                             float* __restrict__ neigh, float* __restrict__ cord) {
  const int bg = blockIdx.x, t = threadIdx.x;  // 32 threads
  const int b = bg >> 7;
  const int src = order[bg];
  const int sbg = (b << 7) + src;
  const float c0 = center[sbg * 3 + 0], c1 = center[sbg * 3 + 1], c2 = center[sbg * 3 + 2];
  if (t < 3) cord[bg * 3 + t] = center[sbg * 3 + t];
  const int idx = knn[(size_t)sbg * NK + t];
  const float* P = xyz + ((size_t)b * NPTS + idx) * 3;
  float* o = neigh + ((size_t)bg * NK + t) * 3;
  o[0] = __fsub_rn(P[0], c0);
  o[1] = __fsub_rn(P[1], c1);
  o[2] = __fsub_rn(P[2], c2);
}

// ---------------- 5. encoder: BN1 statistics ----------------
__global__ __launch_bounds__(128) void bn1_stats(const float* __restrict__ neigh,
                                                 const float* __restrict__ w,
                                                 const float* __restrict__ bias,
                                                 float* __restrict__ psum,
                                                 float* __restrict__ psq) {
  const int c = threadIdx.x, blk = blockIdx.x;   // 256 blocks x 128 ch
  const float wx = w[c * 3 + 0], wy = w[c * 3 + 1], wz = w[c * 3 + 2], bb = bias[c];
  float s = 0.f, s2 = 0.f;
  const float* nr = neigh + (size_t)blk * 256 * 3;
  for (int r = 0; r < 256; ++r) {
    float y = fmaf(nr[r * 3 + 2], wz, fmaf(nr[r * 3 + 1], wy, fmaf(nr[r * 3 + 0], wx, bb)));
    s += y; s2 = fmaf(y, y, s2);
  }
  psum[c * 256 + blk] = s;
  psq[c * 256 + blk]  = s2;
}

// generic P-partial BN reduce: A = g*rsqrt(var+eps), B0 = b - mean*A  (M = 65536)
__global__ __launch_bounds__(256) void bn_reduce(const float* __restrict__ psum,
                                                 const float* __restrict__ psq,
                                                 const float* __restrict__ g,
                                                 const float* __restrict__ b,
                                                 float* __restrict__ A, float* __restrict__ B0,
                                                 int P) {
  __shared__ double rs[256], rq[256];
  const int c = blockIdx.x, t = threadIdx.x;
  double s = 0.0, q = 0.0;
  for (int i = t; i < P; i += 256) {
    s += (double)psum[(size_t)c * P + i];
    q += (double)psq[(size_t)c * P + i];
  }
  rs[t] = s; rq[t] = q;
  __syncthreads();
  for (int o = 128; o > 0; o >>= 1) {
    if (t < o) { rs[t] += rs[t + o]; rq[t] += rq[t + o]; }
    __syncthreads();
  }
  if (t == 0) {
    const double M = 65536.0;
    double m = rs[0] / M;
    double v = rq[0] / M - m * m;
    if (v < 0) v = 0;
    float a = g[c] * rsqrtf((float)v + LN_EPS);
    A[c] = a;
    B0[c] = b[c] - (float)m * a;
  }
}

// ---------------- 6. flat encoder stages ----------------
// f1 = relu(bn1(neigh @ ec1w^T)) -> bf16 [65536][128]
__global__ __launch_bounds__(256) void enc_f1(const float* __restrict__ neigh,
                                              const float* __restrict__ ec1w, const float* __restrict__ ec1b,
                                              const float* __restrict__ A1, const float* __restrict__ B01,
                                              unsigned short* __restrict__ f1bf) {
  __shared__ float ns[96];
  const int bg = blockIdx.x, t = threadIdx.x;
  if (t < 96) ns[t] = neigh[(size_t)bg * 96 + t];
  __syncthreads();
  for (int e = t; e < 32 * 128; e += 256) {
    const int r = e >> 7, c = e & 127;
    float y = fmaf(ns[r * 3 + 2], ec1w[c * 3 + 2],
             fmaf(ns[r * 3 + 1], ec1w[c * 3 + 1],
             fmaf(ns[r * 3 + 0], ec1w[c * 3 + 0], ec1b[c])));
    y = fmaxf(fmaf(y, A1[c], B01[c]), 0.f);
    f1bf[(size_t)bg * 4096 + e] = f2bf(y);
  }
}

// ---------------- 7. encoder A-stationary GEMM (stage 64 A-rows in LDS, sweep full N) ----
// EPI 0 (mm2): +bias, write C [N], per-group colmax -> gmaxOut (bf16)
// EPI 1 (mm3): +bias +sg[group], write C, column sum/sumsq partials (over bf16 values)
// EPI 2 (mm4): bn2-apply on A-load (relu(a*A2+B02) in bf16), no C, colmax+sc2b -> tokens
template <int K, int NTILE, int EPI>
__global__ __launch_bounds__(256) void enc_gemm(const unsigned short* __restrict__ A,
                                                const unsigned short* __restrict__ W,
                                                const float* __restrict__ bias,
                                                const float* __restrict__ sgbuf,
                                                const float* __restrict__ A2,
                                                const float* __restrict__ B02,
                                                unsigned short* __restrict__ C,
                                                unsigned short* __restrict__ gmaxOut,
                                                float* __restrict__ psum,
                                                float* __restrict__ psq,
                                                const float* __restrict__ sc2b,
                                                float* __restrict__ tokens) {
  constexpr int LDA = K + 8;   // shorts; +16B pad -> 2-way LDS bank aliasing (free)
  __shared__ unsigned short At[64 * LDA];
  const int blk = blockIdx.x, t = threadIdx.x;
  const int m0 = blk * 64;
  // ---- stage A (once) ----
  for (int idx = t; idx < 64 * (K / 8); idx += 256) {
    const int row = idx / (K / 8), off = idx % (K / 8);
    short8v v = *(const short8v*)(A + (size_t)(m0 + row) * K + off * 8);
    if (EPI == 2) {
      float a2v[8], b0v[8];
      *(float4*)(a2v)     = *(const float4*)(A2 + off * 8);
      *(float4*)(a2v + 4) = *(const float4*)(A2 + off * 8 + 4);
      *(float4*)(b0v)     = *(const float4*)(B02 + off * 8);
      *(float4*)(b0v + 4) = *(const float4*)(B02 + off * 8 + 4);
#pragma unroll
      for (int j = 0; j < 8; ++j)
        v[j] = (short)f2bf(fmaxf(fmaf(bf2f((unsigned short)v[j]), a2v[j], b0v[j]), 0.f));
    }
    *(short8v*)(At + row * LDA + off * 8) = v;
  }
  __syncthreads();
  const int lane = t & 63, wid = t >> 6;
  const int wr = wid >> 1, wc = wid & 1;
  const int lr = lane & 15, kg = lane >> 4;
  const int group = 2 * blk + wr;      // each wave's 32 rows = one group
  const unsigned short* a0 = At + (wr * 32 + lr) * LDA + kg * 8;
  const unsigned short* a1 = a0 + 16 * LDA;
  for (int nt = 0; nt < NTILE / 64; ++nt) {
    const int n0 = nt * 64 + wc * 32;
    const unsigned short* b0 = W + (size_t)(n0 + lr) * K + kg * 8;
    const unsigned short* b1 = b0 + (size_t)16 * K;
    f32x4 acc00 = {0.f, 0.f, 0.f, 0.f}, acc01 = acc00, acc10 = acc00, acc11 = acc00;
#pragma unroll
    for (int k0 = 0; k0 < K; k0 += 32) {
      const short8v av0 = *(const short8v*)(a0 + k0);
      const short8v av1 = *(const short8v*)(a1 + k0);
      const short8v bv0 = *(const short8v*)(b0 + k0);
      const short8v bv1 = *(const short8v*)(b1 + k0);
      acc00 = __builtin_amdgcn_mfma_f32_16x16x32_bf16(av0, bv0, acc00, 0, 0, 0);
      acc01 = __builtin_amdgcn_mfma_f32_16x16x32_bf16(av0, bv1, acc01, 0, 0, 0);
      acc10 = __builtin_amdgcn_mfma_f32_16x16x32_bf16(av1, bv0, acc10, 0, 0, 0);
      acc11 = __builtin_amdgcn_mfma_f32_16x16x32_bf16(av1, bv1, acc11, 0, 0, 0);
    }
    // ---- epilogue ----
#pragma unroll
    for (int j = 0; j < 2; ++j) {
      const int n = n0 + j * 16 + lr;
      float red0 = (EPI == 1) ? 0.f : -3.0e38f;   // sum or max
      float red1 = 0.f;                            // sumsq
      float base = 0.f;
      if (EPI == 0) base = bias[n];
      if (EPI == 1) base = bias[n] + sgbuf[(size_t)group * NTILE + n];
#pragma unroll
      for (int i = 0; i < 2; ++i) {
        const f32x4 a = (i == 0) ? (j == 0 ? acc00 : acc01) : (j == 0 ? acc10 : acc11);
#pragma unroll
        for (int r = 0; r < 4; ++r) {
          const int m = m0 + wr * 32 + i * 16 + kg * 4 + r;
          const float v = a[r] + base;
          if (EPI == 0) {
            C[(size_t)m * NTILE + n] = f2bf(v);
            red0 = fmaxf(red0, v);
          } else if (EPI == 1) {
            const unsigned short us = f2bf(v);
            C[(size_t)m * NTILE + n] = us;
            const float vv = bf2f(us);
            red0 += vv; red1 = fmaf(vv, vv, red1);
          } else {
            red0 = fmaxf(red0, v);
          }
        }
      }
      // reduce over kg (rows within the group): lanes lr, lr+16, lr+32, lr+48
      if (EPI == 1) {
        red0 += __shfl_xor(red0, 16, 64); red0 += __shfl_xor(red0, 32, 64);
        red1 += __shfl_xor(red1, 16, 64); red1 += __shfl_xor(red1, 32, 64);
        if (kg == 0) {
          psum[(size_t)n * 2048 + blk * 2 + wr] = red0;
          psq[(size_t)n * 2048 + blk * 2 + wr]  = red1;
        }
      } else {
        red0 = fmaxf(red0, __shfl_xor(red0, 16, 64));
        red0 = fmaxf(red0, __shfl_xor(red0, 32, 64));
        if (kg == 0) {
          if (EPI == 0) gmaxOut[(size_t)group * NTILE + n] = f2bf(red0);
          else          tokens[(size_t)group * NTILE + n] = red0 + sc2b[n];
        }
      }
    }
  }
}

// ---------------- 8. positional embedding + h init (merged) ----------------
__global__ void pos_hinit(const float* __restrict__ cord, const float* __restrict__ tokens,
                          const float* __restrict__ sos,
                          float* __restrict__ pos, float* __restrict__ h) {
  const int tok = blockIdx.x, t = threadIdx.x;   // 384 threads
  const int c = t >> 7;
  const int rem = t & 127;
  const int i = rem >> 1;
  const int isc = rem & 1;
  const float coord = cord[tok * 3 + c];
  const float ex = 2.0f * (float)i / 128.0f;
  const float inv = 1.0f / powf(10000.0f, ex);
  const float ang = coord * inv;
  pos[(size_t)tok * NC + t] = isc ? cosf(ang) : sinf(ang);
  const int b = tok >> 7, g = tok & 127;
  h[(size_t)tok * NC + t] = (g == 0) ? sos[t] : tokens[((size_t)b * NG + (g - 1)) * NC + t];
}

// ---------------- 9. layernorm (shuffle-reduce; optionally add first; y fp32 or bf16) ------
template <bool BF16OUT>
__global__ __launch_bounds__(128) void ln_kernel(const float* __restrict__ in,
                                                 const float* __restrict__ add,
                                                 const float* __restrict__ g,
                                                 const float* __restrict__ b,
                                                 void* __restrict__ y,
                                                 float* __restrict__ xout) {
  __shared__ float sm[4];
  const int row = blockIdx.x, t = threadIdx.x, w = t >> 6;
  const float* ip = in + (size_t)row * NC;
  float v0 = ip[t], v1 = ip[t + 128], v2 = ip[t + 256];
  if (add) {
    const float* ap = add + (size_t)row * NC;
    v0 += ap[t]; v1 += ap[t + 128]; v2 += ap[t + 256];
  }
  float s = v0 + v1 + v2;
#pragma unroll
  for (int m = 1; m < 64; m <<= 1) s += __shfl_xor(s, m, 64);
  if ((t & 63) == 0) sm[w] = s;
  __syncthreads();
  const float mean = (sm[0] + sm[1]) / (float)NC;
  const float d0 = v0 - mean, d1 = v1 - mean, d2 = v2 - mean;
  float sq = d0 * d0 + d1 * d1 + d2 * d2;
#pragma unroll
  for (int m = 1; m < 64; m <<= 1) sq += __shfl_xor(sq, m, 64);
  if ((t & 63) == 0) sm[2 + w] = sq;
  __syncthreads();
  const float rs = rsqrtf((sm[2] + sm[3]) / (float)NC + LN_EPS);
  const float y0 = d0 * rs * g[t] + b[t];
  const float y1 = d1 * rs * g[t + 128] + b[t + 128];
  const float y2 = d2 * rs * g[t + 256] + b[t + 256];
  if (BF16OUT) {
    unsigned short* yp = (unsigned short*)y + (size_t)row * NC;
    yp[t] = f2bf(y0); yp[t + 128] = f2bf(y1); yp[t + 256] = f2bf(y2);
  } else {
    float* yp = (float*)y + (size_t)row * NC;
    yp[t] = y0; yp[t + 128] = y1; yp[t + 256] = y2;
  }
  if (xout) {
    float* xp = xout + (size_t)row * NC;
    xp[t] = v0; xp[t + 128] = v1; xp[t + 256] = v2;
  }
}

// ---------------- 10. bf16 MFMA GEMM: C = act(A @ W^T + bias) (+res) ----------------
// RESMODE: 0=none, 1=+R[m*N+n]
template <int ACT, int RESMODE, bool OUT_BF, int K>
__global__ __launch_bounds__(256) void gemm_mfma(const unsigned short* __restrict__ A,
                                                 const unsigned short* __restrict__ W,
                                                 const float* __restrict__ bias,
                                                 const float* __restrict__ R,
                                                 void* __restrict__ Cv,
                                                 int N) {
  const int t = threadIdx.x;
  const int lane = t & 63, wid = t >> 6;
  const int wr = wid >> 1, wc = wid & 1;
  const int m0 = blockIdx.y * 64 + wr * 32;
  const int n0 = blockIdx.x * 64 + wc * 32;
  const int lr = lane & 15, kg = lane >> 4;
  const unsigned short* a0p = A + (size_t)(m0 + lr) * K + kg * 8;
  const unsigned short* a1p = a0p + (size_t)16 * K;
  const unsigned short* b0p = W + (size_t)(n0 + lr) * K + kg * 8;
  const unsigned short* b1p = b0p + (size_t)16 * K;
  f32x4 acc00 = {0.f, 0.f, 0.f, 0.f}, acc01 = acc00, acc10 = acc00, acc11 = acc00;
#pragma unroll 2
  for (int k0 = 0; k0 < K; k0 += 32) {
    const short8v av0 = *(const short8v*)(a0p + k0);
    const short8v av1 = *(const short8v*)(a1p + k0);
    const short8v bv0 = *(const short8v*)(b0p + k0);
    const short8v bv1 = *(const short8v*)(b1p + k0);
    acc00 = __builtin_amdgcn_mfma_f32_16x16x32_bf16(av0, bv0, acc00, 0, 0, 0);
    acc01 = __builtin_amdgcn_mfma_f32_16x16x32_bf16(av0, bv1, acc01, 0, 0, 0);
    acc10 = __builtin_amdgcn_mfma_f32_16x16x32_bf16(av1, bv0, acc10, 0, 0, 0);
    acc11 = __builtin_amdgcn_mfma_f32_16x16x32_bf16(av1, bv1, acc11, 0, 0, 0);
  }
#pragma unroll
  for (int i = 0; i < 2; ++i) {
#pragma unroll
    for (int j = 0; j < 2; ++j) {
      const f32x4 a = (i == 0) ? (j == 0 ? acc00 : acc01) : (j == 0 ? acc10 : acc11);
      const int n = n0 + j * 16 + lr;
      const float bn = bias ? bias[n] : 0.f;
#pragma unroll
      for (int r = 0; r < 4; ++r) {
        const int m = m0 + i * 16 + kg * 4 + r;
        float v = a[r] + bn;
        if (ACT == 1) v = 0.5f * v * (1.0f + erff(v * 0.70710678118654752f));
        if (RESMODE == 1) v += R[(size_t)m * N + n];
        if (OUT_BF) ((unsigned short*)Cv)[(size_t)m * N + n] = f2bf(v);
        else        ((float*)Cv)[(size_t)m * N + n] = v;
      }
    }
  }
}

// ---------------- 11. fused attention via MFMA: scores + softmax + PV ----------------
// one block per (b, h, 64-row half); 4 waves, wave w owns 16 q-rows.
__global__ __launch_bounds__(256) void attn_fused(const unsigned short* __restrict__ qkv,
                                                  unsigned short* __restrict__ obuf) {
  __shared__ __align__(16) unsigned short qs[64 * 72];    // Q [64][64] pad 8
  __shared__ __align__(16) unsigned short ks[128 * 72];   // K [128][64] pad 8
  __shared__ __align__(16) unsigned short vt[64 * 136];   // V^T [64][128] pad 8
  __shared__ __align__(16) unsigned short ps[64 * 136];   // P [64][128] pad 8
  const int blk = blockIdx.x, t = threadIdx.x;
  const int qt = blk & 1;
  const int h = (blk >> 1) % NH;
  const int b = blk / (2 * NH);
  const size_t qbase = ((size_t)(b * NG + qt * 64)) * (3 * NC) + h * NDH;
  const size_t kbase = ((size_t)(b * NG)) * (3 * NC) + NC + h * NDH;
  const size_t vbase = kbase + NC;
#pragma unroll
  for (int it = 0; it < 2; ++it) {   // Q: 512 8-short tasks
    const int idx = t + it * 256;
    const int r = idx >> 3, c0 = (idx & 7) * 8;
    *(short8v*)(qs + r * 72 + c0) = *(const short8v*)(qkv + qbase + (size_t)r * (3 * NC) + c0);
  }
#pragma unroll
  for (int it = 0; it < 4; ++it) {   // K: 1024 tasks
    const int idx = t + it * 256;
    const int r = idx >> 3, c0 = (idx & 7) * 8;
    *(short8v*)(ks + r * 72 + c0) = *(const short8v*)(qkv + kbase + (size_t)r * (3 * NC) + c0);
  }
#pragma unroll
  for (int it = 0; it < 4; ++it) {   // V transposed
    const int idx = t + it * 256;
    const int r = idx >> 3, c0 = (idx & 7) * 8;
    const short8v v = *(const short8v*)(qkv + vbase + (size_t)r * (3 * NC) + c0);
#pragma unroll
    for (int j = 0; j < 8; ++j) vt[(c0 + j) * 136 + r] = (unsigned short)v[j];
  }
  __syncthreads();
  const int lane = t & 63, w = t >> 6;
  const int lr = lane & 15, kg = lane >> 4;
  // ---- QK^T: wave w computes rows [w*16, w*16+16) x all 128 cols ----
  f32x4 sc[8] = {};
  {
    const short8v av0 = *(const short8v*)(qs + (w * 16 + lr) * 72 + kg * 8);
    const short8v av1 = *(const short8v*)(qs + (w * 16 + lr) * 72 + 32 + kg * 8);
#pragma unroll
    for (int j = 0; j < 8; ++j) {
      const short8v bv0 = *(const short8v*)(ks + (j * 16 + lr) * 72 + kg * 8);
      const short8v bv1 = *(const short8v*)(ks + (j * 16 + lr) * 72 + 32 + kg * 8);
      sc[j] = __builtin_amdgcn_mfma_f32_16x16x32_bf16(av0, bv0, sc[j], 0, 0, 0);
      sc[j] = __builtin_amdgcn_mfma_f32_16x16x32_bf16(av1, bv1, sc[j], 0, 0, 0);
    }
  }
  // ---- softmax (rows of this wave live in-wave: col=j*16+lr, row=kg*4+r) ----
#pragma unroll
  for (int r = 0; r < 4; ++r) {
    const int rowg = qt * 64 + w * 16 + kg * 4 + r;
    float pj[8];
    float mx = -3.0e38f;
#pragma unroll
    for (int j = 0; j < 8; ++j) {
      const int col = j * 16 + lr;
      const float s = (col <= rowg) ? sc[j][r] * 0.125f : -1e9f;
      pj[j] = s;
      mx = fmaxf(mx, s);
    }
#pragma unroll
    for (int m = 1; m < 16; m <<= 1) mx = fmaxf(mx, __shfl_xor(mx, m, 64));
    float sum = 0.f;
#pragma unroll
    for (int j = 0; j < 8; ++j) { pj[j] = expf(pj[j] - mx); sum += pj[j]; }
#pragma unroll
    for (int m = 1; m < 16; m <<= 1) sum += __shfl_xor(sum, m, 64);
#pragma unroll
    for (int j = 0; j < 8; ++j)
      ps[(w * 16 + kg * 4 + r) * 136 + j * 16 + lr] = f2bf(pj[j] / sum);
  }
  __syncthreads();
  // ---- PV: rows [w*16, w*16+16) x 64 dims, K=128 ----
  f32x4 oc[4] = {};
#pragma unroll
  for (int k = 0; k < 4; ++k) {
    const short8v av = *(const short8v*)(ps + (w * 16 + lr) * 136 + k * 32 + kg * 8);
#pragma unroll
    for (int dj = 0; dj < 4; ++dj) {
      const short8v bv = *(const short8v*)(vt + (dj * 16 + lr) * 136 + k * 32 + kg * 8);
      oc[dj] = __builtin_amdgcn_mfma_f32_16x16x32_bf16(av, bv, oc[dj], 0, 0, 0);
    }
  }
#pragma unroll
  for (int dj = 0; dj < 4; ++dj) {
#pragma unroll
    for (int r = 0; r < 4; ++r) {
      const int m = qt * 64 + w * 16 + kg * 4 + r;
      obuf[((size_t)(b * NG + m)) * NC + h * NDH + dj * 16 + lr] = f2bf(oc[dj][r]);
    }
  }
}

// ---------------- launch ----------------
extern "C" void kernel_launch(void* const* d_in, const int* in_sizes, int n_in,
                              void* d_out, int out_size, void* d_ws, size_t ws_size,
                              hipStream_t stream) {
  (void)in_sizes; (void)n_in; (void)out_size; (void)ws_size;
  const float* xyz  = (const float*)d_in[0];
  const float* ec1w = (const float*)d_in[1];
  const float* ec1b = (const float*)d_in[2];
  const float* bn1g = (const float*)d_in[3];
  const float* bn1b = (const float*)d_in[4];
  const float* ec2w = (const float*)d_in[5];
  const float* ec2b = (const float*)d_in[6];
  const float* sc1w = (const float*)d_in[7];
  const float* sc1b = (const float*)d_in[8];
  const float* bn2g = (const float*)d_in[9];
  const float* bn2b = (const float*)d_in[10];
  const float* sc2w = (const float*)d_in[11];
  const float* sc2b = (const float*)d_in[12];
  const float* sos  = (const float*)d_in[13];
  const float* ln1g = (const float*)d_in[14];
  const float* ln1b = (const float*)d_in[15];
  const float* qkvw = (const float*)d_in[16];
  const float* qkvb = (const float*)d_in[17];
  const float* outw = (const float*)d_in[18];
  const float* outb = (const float*)d_in[19];
  const float* ln2g = (const float*)d_in[20];
  const float* ln2b = (const float*)d_in[21];
  const float* m1w  = (const float*)d_in[22];
  const float* m1b  = (const float*)d_in[23];
  const float* m2w  = (const float*)d_in[24];
  const float* m2b  = (const float*)d_in[25];
  const float* lnfg = (const float*)d_in[26];
  const float* lnfb = (const float*)d_in[27];
  float* out = (float*)d_out;

  char* p = (char*)d_ws;
  auto carve = [&](size_t bytes) -> void* {
    void* q = (void*)p;
    p += (bytes + 255) & ~(size_t)255;
    return q;
  };
  int*   cent   = (int*)carve((size_t)NB * NG * 4);
  float* center = (float*)carve((size_t)NB * NG * 3 * 4);
  int*   knn    = (int*)carve((size_t)NB * NG * NK * 4);
  int*   order  = (int*)carve((size_t)NB * NG * 4);
  float* neigh  = (float*)carve((size_t)NB * NG * NK * 3 * 4);
  float* cord   = (float*)carve((size_t)NB * NG * 3 * 4);
  float* psum1  = (float*)carve((size_t)128 * 256 * 4);
  float* psq1   = (float*)carve((size_t)128 * 256 * 4);
  float* A1     = (float*)carve(128 * 4);
  float* B01    = (float*)carve(128 * 4);
  float* psum2  = (float*)carve((size_t)512 * 2048 * 4);
  float* psq2   = (float*)carve((size_t)512 * 2048 * 4);
  float* A2     = (float*)carve(512 * 4);
  float* B02    = (float*)carve(512 * 4);
  float* tokens = (float*)carve((size_t)NB * NG * NC * 4);
  float* posb   = (float*)carve((size_t)NB * NG * NC * 4);
  float* hbuf   = (float*)carve((size_t)NB * NG * NC * 4);
  float* xbuf   = (float*)carve((size_t)NB * NG * NC * 4);
  unsigned short* ybf    = (unsigned short*)carve((size_t)NB * NG * NC * 2);
  unsigned short* qkv_bf = (unsigned short*)carve((size_t)NB * NG * 3 * NC * 2);
  unsigned short* obf    = (unsigned short*)carve((size_t)NB * NG * NC * 2);
  unsigned short* mh_bf  = (unsigned short*)carve((size_t)NB * NG * NHID * 2);
  unsigned short* wqkv_bf = (unsigned short*)carve((size_t)NL * 3 * NC * NC * 2);
  unsigned short* wout_bf = (unsigned short*)carve((size_t)NL * NC * NC * 2);
  unsigned short* wm1_bf  = (unsigned short*)carve((size_t)NL * NHID * NC * 2);
  unsigned short* wm2_bf  = (unsigned short*)carve((size_t)NL * NC * NHID * 2);
  // encoder bf16 weights
  unsigned short* ec2w_bf = (unsigned short*)carve((size_t)256 * 128 * 2);
  unsigned short* w3a_bf  = (unsigned short*)carve((size_t)512 * 256 * 2);
  unsigned short* w3b_bf  = (unsigned short*)carve((size_t)512 * 256 * 2);
  unsigned short* sc2w_bf = (unsigned short*)carve((size_t)384 * 512 * 2);
  // encoder activations (flat)
  unsigned short* f1bf   = (unsigned short*)carve((size_t)65536 * 128 * 2);  // 16.78 MB
  unsigned short* f2bf_a = (unsigned short*)carve((size_t)65536 * 256 * 2);  // 33.55 MB
  unsigned short* gmaxbf = (unsigned short*)carve((size_t)2048 * 256 * 2);
  float*          sgbuf  = (float*)carve((size_t)2048 * 512 * 4);
  unsigned short* s3bf   = (unsigned short*)carve((size_t)65536 * 512 * 2);  // 67.1 MB

  const int NTOK = NB * NG;  // 2048

  // fused: FPS (blocks 0..15, 96KB LDS) + weight bf16 conversion (blocks 16+)
  fps_cvt<<<NB + 1024, 512, 3 * NPTS * 4, stream>>>(
      xyz, cent, qkvw, outw, m1w, m2w, ec2w, sc1w, sc2w,
      wqkv_bf, wout_bf, wm1_bf, wm2_bf, ec2w_bf, w3a_bf, w3b_bf, sc2w_bf);
  knn_kernel<<<NTOK, 256, 0, stream>>>(xyz, cent, center, knn);
  order_kernel<<<NB, 128, 0, stream>>>(center, order);
  gather_neigh<<<NTOK, 32, 0, stream>>>(xyz, knn, order, center, neigh, cord);

  // ---- encoder (flat MFMA pipeline, A-stationary, fused reductions) ----
  bn1_stats<<<256, 128, 0, stream>>>(neigh, ec1w, ec1b, psum1, psq1);
  bn_reduce<<<128, 256, 0, stream>>>(psum1, psq1, bn1g, bn1b, A1, B01, 256);
  enc_f1<<<NTOK, 256, 0, stream>>>(neigh, ec1w, ec1b, A1, B01, f1bf);
  enc_gemm<128, 256, 0><<<1024, 256, 0, stream>>>(
      f1bf, ec2w_bf, ec2b, nullptr, nullptr, nullptr,
      f2bf_a, gmaxbf, nullptr, nullptr, nullptr, nullptr);
  gemm_mfma<0, 0, false, 256><<<dim3(8, 32), 256, 0, stream>>>(
      gmaxbf, w3a_bf, nullptr, nullptr, sgbuf, 512);
  enc_gemm<256, 512, 1><<<1024, 256, 0, stream>>>(
      f2bf_a, w3b_bf, sc1b, sgbuf, nullptr, nullptr,
      s3bf, nullptr, psum2, psq2, nullptr, nullptr);
  bn_reduce<<<512, 256, 0, stream>>>(psum2, psq2, bn2g, bn2b, A2, B02, 2048);
  enc_gemm<512, 384, 2><<<1024, 256, 0, stream>>>(
      s3bf, sc2w_bf, nullptr, nullptr, A2, B02,
      nullptr, nullptr, nullptr, nullptr, sc2b, tokens);

  pos_hinit<<<NTOK, NC, 0, stream>>>(cord, tokens, sos, posb, hbuf);

  for (int l = 0; l < NL; ++l) {
    ln_kernel<true><<<NTOK, 128, 0, stream>>>(hbuf, posb, ln1g + l * NC, ln1b + l * NC, ybf, xbuf);
    gemm_mfma<0, 0, true, 384><<<dim3(18, 32), 256, 0, stream>>>(
        ybf, wqkv_bf + (size_t)l * 3 * NC * NC, qkvb + (size_t)l * 3 * NC, nullptr, qkv_bf,
        3 * NC);
    attn_fused<<<NB * NH * 2, 256, 0, stream>>>(qkv_bf, obf);
    gemm_mfma<0, 1, false, 384><<<dim3(6, 32), 256, 0, stream>>>(
        obf, wout_bf + (size_t)l * NC * NC, outb + (size_t)l * NC, xbuf, hbuf, NC);
    ln_kernel<true><<<NTOK, 128, 0, stream>>>(hbuf, nullptr, ln2g + l * NC, ln2b + l * NC, ybf, nullptr);
    gemm_mfma<1, 0, true, 384><<<dim3(24, 32), 256, 0, stream>>>(
        ybf, wm1_bf + (size_t)l * NHID * NC, m1b + (size_t)l * NHID, nullptr, mh_bf, NHID);
    gemm_mfma<0, 1, false, 1536><<<dim3(6, 32), 256, 0, stream>>>(
        mh_bf, wm2_bf + (size_t)l * NC * NHID, m2b + (size_t)l * NC, hbuf, hbuf, NC);
  }
  ln_kernel<false><<<NTOK, 128, 0, stream>>>(hbuf, nullptr, lnfg, lnfb, out, nullptr);
}